// Round 14
// baseline (592.350 us; speedup 1.0000x reference)
//
#include <hip/hip_runtime.h>
#include <stdint.h>
#include <stddef.h>

#define BATCH 32
#define TLEN 256
#define DIM 512
#define PHE 2048
#define VOC 40000
#define VOCP 40960
#define DFF 2148
#define DFFP2 2304
#define BT 8192
#define KC 50
#define KP 10
#define CHUNK 8192
#define NCHUNK 5
#define LNEPS 1e-6f
#define BIGF 1e30f

typedef unsigned short u16;
typedef __attribute__((ext_vector_type(8))) short short8;
typedef __attribute__((ext_vector_type(8))) unsigned short ushort8;
typedef __attribute__((ext_vector_type(4))) float floatx4;

__device__ inline u16 f2bf(float f) {
  union { float f; unsigned int u; } v; v.f = f;
  unsigned int u = v.u;
  return (u16)((u + 0x7fffu + ((u >> 16) & 1u)) >> 16);
}
__device__ inline float bf2f(u16 u) {
  union { unsigned int u; float f; } c; c.u = ((unsigned int)u) << 16;
  return c.f;
}

// monotone float<->uint transforms
__device__ inline unsigned int f2mono(float f) {
  union { float f; unsigned int u; } c; c.f = f;
  return (c.u & 0x80000000u) ? ~c.u : (c.u | 0x80000000u);
}
__device__ inline float mono2f(unsigned int u) {
  union { unsigned int u; float f; } c;
  c.u = (u & 0x80000000u) ? (u & 0x7FFFFFFFu) : ~u;
  return c.f;
}
__device__ inline unsigned int mono16(u16 u) {
  return (u & 0x8000u) ? (u16)~u : (u16)(u | 0x8000u);
}
__device__ inline float mono2f16(unsigned int k) {
  unsigned int ub = (k & 0x8000u) ? (k & 0x7FFFu) : ((~k) & 0xFFFFu);
  union { unsigned int u; float f; } c; c.u = ub << 16;
  return c.f;
}

// async global->LDS, 16 bytes per lane; LDS dest is wave-uniform base + lane*16B
__device__ inline void load_lds16(const void* g, void* l) {
  __builtin_amdgcn_global_load_lds(
      (const __attribute__((address_space(1))) unsigned int*)g,
      (__attribute__((address_space(3))) unsigned int*)l, 16, 0, 0);
}

// ---------------- reduction helpers ----------------
__device__ inline float waveRedSum(float v) {
  #pragma unroll
  for (int off = 32; off > 0; off >>= 1) v += __shfl_down(v, off);
  return v;
}
__device__ inline float waveRedMax(float v) {
  #pragma unroll
  for (int off = 32; off > 0; off >>= 1) v = fmaxf(v, __shfl_down(v, off));
  return v;
}
__device__ inline float blockRedSum(float v) {
  __shared__ float sm[8];
  int lane = threadIdx.x & 63, w = threadIdx.x >> 6, nw = blockDim.x >> 6;
  v = waveRedSum(v);
  __syncthreads();
  if (lane == 0) sm[w] = v;
  __syncthreads();
  float r = 0.f;
  for (int i = 0; i < nw; ++i) r += sm[i];
  return r;
}
__device__ inline float blockRedMax(float v) {
  __shared__ float sm2[8];
  int lane = threadIdx.x & 63, w = threadIdx.x >> 6, nw = blockDim.x >> 6;
  v = waveRedMax(v);
  __syncthreads();
  if (lane == 0) sm2[w] = v;
  __syncthreads();
  float r = -BIGF;
  for (int i = 0; i < nw; ++i) r = fmaxf(r, sm2[i]);
  return r;
}
__device__ inline double blockRedSumD(double v) {
  __shared__ double red[256];
  int tid = threadIdx.x;
  __syncthreads();
  red[tid] = v;
  __syncthreads();
  for (int s = 128; s > 0; s >>= 1) {
    if (tid < s) red[tid] += red[tid + s];
    __syncthreads();
  }
  return red[0];
}

// dominance-test histogram add (deterministic integer adds)
__device__ inline void hist_add2(int* hist, int digit, bool pred) {
  int lane = threadIdx.x & 63;
  unsigned long long act = __ballot(pred);
  if (!act) return;
  int src = __ffsll((long long)act) - 1;
  int ld = __shfl(digit, src);
  unsigned long long m = __ballot(pred && digit == ld);
  if (__popcll(m) >= 32) {
    if (lane == src) atomicAdd(&hist[ld], (int)__popcll(m));
    if ((act & ~m) & (1ull << lane)) atomicAdd(&hist[digit], 1);
  } else {
    if (pred) atomicAdd(&hist[digit], 1);
  }
}

// ---------------- small utility kernels ----------------
__global__ void k_sentinel(float* out) { out[0] = -12345.0f; }

// slim prologue: ONLY what L0's gemm needs — phe rows + emb chunk-0 rows
// (cvt + sumsq, fully coalesced). Everything else is absorbed as aux roles
// in the k_dpc pipeline launches.
__global__ void __launch_bounds__(256) k_prep_a(
    const float* __restrict__ phe, u16* __restrict__ phe_bf, float* __restrict__ r_p,
    const float* __restrict__ emb, u16* __restrict__ emb_bf, float* __restrict__ r_c)
{
  int bid = (int)blockIdx.x, tid = threadIdx.x;
  const float* src; u16* dst; float* rout;
  if (bid < PHE) {
    src = phe + (size_t)bid * DIM; dst = phe_bf + (size_t)bid * DIM; rout = r_p + bid;
  } else {
    int row = bid - PHE;
    src = emb + (size_t)row * DIM; dst = emb_bf + (size_t)row * DIM; rout = r_c + row;
  }
  float a = src[tid], b = src[tid + 256];
  dst[tid] = f2bf(a); dst[tid + 256] = f2bf(b);
  float s = blockRedSum(a * a + b * b);
  if (tid == 0) *rout = s;
}

#define EPI_STORE 0
#define EPI_DPP   1
#define EPI_FFN1  3
#define EPI_FFN2  4

// XCD-aware bijective block swizzle (m204)
__device__ inline void xcd_block(int BM, int BN, int& m0, int& n0) {
  int nwg = gridDim.x * gridDim.y;
  int orig = blockIdx.y * gridDim.x + blockIdx.x;
  int q = nwg >> 3, r = nwg & 7;
  int xcd = orig & 7, i0 = orig >> 3;
  int wgid = (xcd < r ? xcd * (q + 1) : r * (q + 1) + (xcd - r) * q) + i0;
  m0 = (wgid / gridDim.x) * BM;
  n0 = (wgid % gridDim.x) * BN;
}

template<int EPI>
__device__ inline void epi_write(int rr, int col, float c,
    float* outF, u16* outU, int ldc, const float* rp,
    const float* bias, int nepi) {
  if (EPI == EPI_STORE) {
    outF[(size_t)rr * ldc + col] = c;
  } else if (EPI == EPI_DPP) {
    outF[(size_t)rr * ldc + col] = rp[rr] + rp[col] - 2.f * c;
  } else if (EPI == EPI_FFN1) {
    float h = (col < nepi) ? fmaxf(c + bias[col], 0.f) : 0.f;
    outU[(size_t)rr * ldc + col] = f2bf(h);
  } else if (EPI == EPI_FFN2) {
    outF[(size_t)rr * ldc + col] = c + bias[col];
  }
}

// ---------------- DPC select body (shared by k_dpc / k_dpc_log) -----------
__device__ __forceinline__ void dpc_select(
    char* smem, int si, const u16* __restrict__ dr, int schunk,
    float* __restrict__ top)
{
  int row = si >> 1, half = si & 1;
  const u16* src = dr + (size_t)row * CHUNK + half * 4096;
  int* hist = (int*)smem;
  int* cum  = hist + 1024;
  int* wred = cum + 256;
  int* selb = wred + 8;
  int tid = threadIdx.x, lane = tid & 63, w4 = tid >> 6;
  int hbase = w4 << 8;

  unsigned int kv[16];
  #pragma unroll
  for (int j2 = 0; j2 < 2; ++j2) {
    ushort8 qv = *(const ushort8*)(src + j2 * 2048 + tid * 8);
    #pragma unroll
    for (int e = 0; e < 8; ++e) kv[j2 * 8 + e] = mono16((u16)qv[e]);
  }

  int hbmin = 255, hbmax = 0;
  #pragma unroll
  for (int j = 0; j < 16; ++j) {
    int hb = (int)(kv[j] >> 8);
    hbmin = min(hbmin, hb); hbmax = max(hbmax, hb);
  }
  #pragma unroll
  for (int off = 32; off > 0; off >>= 1) {
    hbmin = min(hbmin, __shfl_down(hbmin, off));
    hbmax = max(hbmax, __shfl_down(hbmax, off));
  }
  if (lane == 0) { wred[w4] = hbmin; wred[4 + w4] = hbmax; }
  __syncthreads();
  int bmin = min(min(wred[0], wred[1]), min(wred[2], wred[3]));
  int bmax = max(max(wred[4], wred[5]), max(wred[6], wred[7]));
  __syncthreads();

  unsigned int prefix;
  int kk = KC;
  if (bmin == bmax) {
    prefix = (unsigned int)bmin;
  } else {
    hist[tid] = 0; hist[tid + 256] = 0; hist[tid + 512] = 0; hist[tid + 768] = 0;
    __syncthreads();
    #pragma unroll
    for (int j = 0; j < 16; ++j) hist_add2(hist + hbase, (int)(kv[j] >> 8), true);
    __syncthreads();
    int x = hist[tid] + hist[tid + 256] + hist[tid + 512] + hist[tid + 768];
    #pragma unroll
    for (int off = 1; off < 64; off <<= 1) { int y = __shfl_up(x, off); if (lane >= off) x += y; }
    if (lane == 63) wred[w4] = x;
    __syncthreads();
    #pragma unroll
    for (int i = 0; i < 4; ++i) if (i < w4) x += wred[i];
    cum[tid] = x;
    __syncthreads();
    int prev = (tid == 0) ? 0 : cum[tid - 1];
    if (prev < kk && kk <= cum[tid]) { selb[0] = tid; selb[1] = kk - prev; }
    __syncthreads();
    prefix = (unsigned int)selb[0];
    kk = selb[1];
    __syncthreads();
  }

  hist[tid] = 0; hist[tid + 256] = 0; hist[tid + 512] = 0; hist[tid + 768] = 0;
  __syncthreads();
  #pragma unroll
  for (int j = 0; j < 16; ++j)
    hist_add2(hist + hbase, (int)(kv[j] & 255u), (kv[j] >> 8) == prefix);
  __syncthreads();
  int x = hist[tid] + hist[tid + 256] + hist[tid + 512] + hist[tid + 768];
  #pragma unroll
  for (int off = 1; off < 64; off <<= 1) { int y = __shfl_up(x, off); if (lane >= off) x += y; }
  if (lane == 63) wred[w4] = x;
  __syncthreads();
  #pragma unroll
  for (int i = 0; i < 4; ++i) if (i < w4) x += wred[i];
  cum[tid] = x;
  __syncthreads();
  int prev = (tid == 0) ? 0 : cum[tid - 1];
  if (prev < kk && kk <= cum[tid]) { selb[0] = tid; selb[1] = kk - prev; }
  __syncthreads();
  unsigned int key = (prefix << 8) | (unsigned int)selb[0];
  float thr = mono2f16(key);
  float* o50 = top + (size_t)row * (NCHUNK * 2 * KC) + (schunk * 2 + half) * KC;
  __syncthreads();

  int cless = 0;
  #pragma unroll
  for (int j = 0; j < 16; ++j) if (kv[j] < key) cless++;
  int xc = cless;
  #pragma unroll
  for (int off = 1; off < 64; off <<= 1) { int y = __shfl_up(xc, off); if (lane >= off) xc += y; }
  if (lane == 63) wred[w4] = xc;
  __syncthreads();
  #pragma unroll
  for (int i = 0; i < 4; ++i) if (i < w4) xc += wred[i];
  int o = xc - cless;
  #pragma unroll
  for (int j = 0; j < 16; ++j)
    if (kv[j] < key) o50[o++] = mono2f16(kv[j]);
  cum[tid] = xc;
  __syncthreads();
  int total_less = cum[255];
  for (int i = total_less + tid; i < KC; i += 256) o50[i] = thr;
}

// ---------------- fused DPC: GEMM(c) || select(c-1) || aux prep ------------
// Roles contiguous: [gemm 1024][select nsel][emb-cvt ncvt][vis][pheT][w1T][w2T]
// Aux branches reuse carved smem (no extra static __shared__) to keep
// LDS at exactly 32768 (5 blocks/CU).
__global__ void __launch_bounds__(256, 2) k_dpc(
    const u16* __restrict__ phe_bf, const u16* emb_bf,
    int gchunk, int ngemm, u16* __restrict__ dw,
    const u16* __restrict__ dr, int schunk, float* __restrict__ top,
    const float* __restrict__ rp, const float* __restrict__ rc, int nsel,
    int ncvt, int cvtbase, const float* __restrict__ embf, u16* emb_bf_w,
    float* __restrict__ r_c_w,
    int nvis, const float* __restrict__ visitf, u16* __restrict__ visit_bf,
    int npht, const float* __restrict__ phef, u16* __restrict__ pheT_bf,
    int nw1, const float* __restrict__ w1, u16* __restrict__ w1T_bf,
    int nw2, const float* __restrict__ w2, u16* __restrict__ w2T_bf)
{
  __shared__ __align__(16) char smem[32768];
  int bid = (int)blockIdx.x;
  int tid = threadIdx.x;
  if (bid < ngemm) {
    u16* As = (u16*)smem;
    u16* Bs = (u16*)(smem + 16384);
    int lane = tid & 63, w = tid >> 6;
    int wm = w >> 1, wn = w & 1;
    int nwg = ngemm, orig = bid;
    int q = nwg >> 3, r = nwg & 7;
    int xcd = orig & 7, i0 = orig >> 3;
    int wgid = (xcd < r ? xcd * (q + 1) : r * (q + 1) + (xcd - r) * q) + i0;
    int m0 = (wgid >> 6) << 7;
    int n0 = (wgid & 63) << 7;
    const u16* Bm = emb_bf + (size_t)gchunk * CHUNK * DIM;
    const float* rcc = rc + gchunk * CHUNK;
    int bvalid = VOC - gchunk * CHUNK; if (bvalid > CHUNK) bvalid = CHUNK;

    floatx4 acc[4][4];
    #pragma unroll
    for (int i = 0; i < 4; ++i)
      #pragma unroll
      for (int j = 0; j < 4; ++j)
        acc[i][j] = (floatx4){0.f, 0.f, 0.f, 0.f};

    int hi = lane >> 4, rsw = lane & 7;
    for (int kt = 0; kt < DIM / 64; ++kt) {
      int k0 = kt * 64;
      #pragma unroll
      for (int p = 0; p < 4; ++p) {
        int c = p * 256 + tid;
        int row = c >> 3;
        int src16 = (c & 7) ^ (row & 7);
        load_lds16(phe_bf + (size_t)(m0 + row) * DIM + k0 + src16 * 8,
                   &As[p * 2048 + w * 512]);
      }
      #pragma unroll
      for (int p = 0; p < 4; ++p) {
        int c = p * 256 + tid;
        int row = c >> 3;
        int src16 = (c & 7) ^ (row & 7);
        load_lds16(Bm + (size_t)(n0 + row) * DIM + k0 + src16 * 8,
                   &Bs[p * 2048 + w * 512]);
      }
      __syncthreads();
      #pragma unroll
      for (int ks = 0; ks < 2; ++ks) {
        int chk = ((ks << 2) | hi) ^ rsw;
        short8 a[4], b[4];
        #pragma unroll
        for (int i = 0; i < 4; ++i)
          a[i] = *(const short8*)&As[(wm * 64 + i * 16 + (lane & 15)) * 64 + chk * 8];
        #pragma unroll
        for (int j = 0; j < 4; ++j)
          b[j] = *(const short8*)&Bs[(wn * 64 + j * 16 + (lane & 15)) * 64 + chk * 8];
        #pragma unroll
        for (int i = 0; i < 4; ++i)
          #pragma unroll
          for (int j = 0; j < 4; ++j)
            acc[i][j] = __builtin_amdgcn_mfma_f32_16x16x32_bf16(a[i], b[j], acc[i][j], 0, 0, 0);
      }
      __syncthreads();
    }
    #pragma unroll
    for (int i = 0; i < 4; ++i) {
      #pragma unroll
      for (int j = 0; j < 4; ++j) {
        floatx4 v = acc[i][j];
        int col = n0 + wn * 64 + j * 16 + (lane & 15);
        int rb = m0 + wm * 64 + i * 16 + ((lane >> 4) << 2);
        #pragma unroll
        for (int qq = 0; qq < 4; ++qq) {
          int rr = rb + qq;
          float d = (col < bvalid) ? sqrtf(fmaxf(rp[rr] + rcc[col] - 2.f * v[qq], 0.f)) : BIGF;
          dw[(size_t)rr * CHUNK + col] = f2bf(d);
        }
      }
    }
    return;
  }
  bid -= ngemm;
  if (bid < nsel) {
    if (schunk >= 0) dpc_select(smem, bid, dr, schunk, top);
    return;
  }
  bid -= nsel;
  if (bid < ncvt) {
    // emb row cvt + sumsq (for the NEXT chunk), reduction via carved smem
    int row = cvtbase + bid;
    const float* src = embf + (size_t)row * DIM;
    u16* dst = emb_bf_w + (size_t)row * DIM;
    float a = src[tid], b = src[tid + 256];
    dst[tid] = f2bf(a); dst[tid + 256] = f2bf(b);
    float s = waveRedSum(a * a + b * b);
    float* red = (float*)smem;
    if ((tid & 63) == 0) red[tid >> 6] = s;
    __syncthreads();
    if (tid == 0) r_c_w[row] = red[0] + red[1] + red[2] + red[3];
    return;
  }
  bid -= ncvt;
  if (bid < nvis) {
    int base = bid * 2048 + tid;
    #pragma unroll
    for (int e = 0; e < 8; ++e) {
      int i = base + e * 256;
      visit_bf[i] = f2bf(visitf[i]);
    }
    return;
  }
  bid -= nvis;
  if (bid < npht) {
    int i = bid * 256 + tid;          // dst [DIM][PHE]
    int r = i >> 11, c = i & 2047;
    pheT_bf[i] = f2bf(phef[(size_t)c * DIM + r]);
    return;
  }
  bid -= npht;
  if (bid < nw1) {
    int i = bid * 256 + tid;          // dst [DFFP2][DIM], src w1 [DIM][DFF]
    int r = i >> 9, c = i & 511;
    float v = (r < DFF) ? w1[(size_t)c * DFF + r] : 0.f;
    w1T_bf[i] = f2bf(v);
    return;
  }
  bid -= nw1;
  if (bid < nw2) {
    int i = bid * 256 + tid;          // dst [DIM][DFFP2], src w2 [DFF][DIM]
    int r = i / DFFP2, c = i % DFFP2;
    float v = (c < DFF) ? w2[(size_t)c * DIM + r] : 0.f;
    w2T_bf[i] = f2bf(v);
    return;
  }
}

// ---------------- logits GEMM (bf16 store) || tail select -----------------
__global__ void __launch_bounds__(256, 2) k_dpc_log(
    const u16* __restrict__ visit_bf, const u16* __restrict__ phe_bf,
    int ngemm, u16* __restrict__ logit_bf,
    const u16* __restrict__ dr, int schunk, float* __restrict__ top)
{
  __shared__ __align__(16) char smem[32768];
  int bid = (int)blockIdx.x;
  if (bid < ngemm) {
    u16* As = (u16*)smem;
    u16* Bs = (u16*)(smem + 16384);
    int tid = threadIdx.x, lane = tid & 63, w = tid >> 6;
    int wm = w >> 1, wn = w & 1;
    int nwg = ngemm, orig = bid;
    int q = nwg >> 3, r = nwg & 7;
    int xcd = orig & 7, i0 = orig >> 3;
    int wgid = (xcd < r ? xcd * (q + 1) : r * (q + 1) + (xcd - r) * q) + i0;
    int m0 = (wgid >> 4) << 7;        // gridx = PHE/128 = 16
    int n0 = (wgid & 15) << 7;

    floatx4 acc[4][4];
    #pragma unroll
    for (int i = 0; i < 4; ++i)
      #pragma unroll
      for (int j = 0; j < 4; ++j)
        acc[i][j] = (floatx4){0.f, 0.f, 0.f, 0.f};

    int hi = lane >> 4, rsw = lane & 7;
    for (int kt = 0; kt < DIM / 64; ++kt) {
      int k0 = kt * 64;
      #pragma unroll
      for (int p = 0; p < 4; ++p) {
        int c = p * 256 + tid;
        int row = c >> 3;
        int src16 = (c & 7) ^ (row & 7);
        load_lds16(visit_bf + (size_t)(m0 + row) * DIM + k0 + src16 * 8,
                   &As[p * 2048 + w * 512]);
      }
      #pragma unroll
      for (int p = 0; p < 4; ++p) {
        int c = p * 256 + tid;
        int row = c >> 3;
        int src16 = (c & 7) ^ (row & 7);
        load_lds16(phe_bf + (size_t)(n0 + row) * DIM + k0 + src16 * 8,
                   &Bs[p * 2048 + w * 512]);
      }
      __syncthreads();
      #pragma unroll
      for (int ks = 0; ks < 2; ++ks) {
        int chk = ((ks << 2) | hi) ^ rsw;
        short8 a[4], b[4];
        #pragma unroll
        for (int i = 0; i < 4; ++i)
          a[i] = *(const short8*)&As[(wm * 64 + i * 16 + (lane & 15)) * 64 + chk * 8];
        #pragma unroll
        for (int j = 0; j < 4; ++j)
          b[j] = *(const short8*)&Bs[(wn * 64 + j * 16 + (lane & 15)) * 64 + chk * 8];
        #pragma unroll
        for (int i = 0; i < 4; ++i)
          #pragma unroll
          for (int j = 0; j < 4; ++j)
            acc[i][j] = __builtin_amdgcn_mfma_f32_16x16x32_bf16(a[i], b[j], acc[i][j], 0, 0, 0);
      }
      __syncthreads();
    }
    #pragma unroll
    for (int i = 0; i < 4; ++i) {
      #pragma unroll
      for (int j = 0; j < 4; ++j) {
        floatx4 v = acc[i][j];
        int col = n0 + wn * 64 + j * 16 + (lane & 15);
        int rb = m0 + wm * 64 + i * 16 + ((lane >> 4) << 2);
        #pragma unroll
        for (int qq = 0; qq < 4; ++qq)
          logit_bf[(size_t)(rb + qq) * PHE + col] = f2bf(v[qq]);
      }
    }
  } else {
    if (schunk < 0) return;
    dpc_select(smem, bid - ngemm, dr, schunk, top);
  }
}

// ---------------- GEMM (NT), 2-phase double-buffered, BK=64 ----------------
template<int EPI, int BM, int BN, int NTH, int WR, int WC>
__global__ void __launch_bounds__(NTH, 2) k_gemm2(
    const u16* __restrict__ A, int lda,
    const u16* __restrict__ Bm, int ldb, int K,
    float* __restrict__ outF, u16* __restrict__ outU, int ldc,
    const float* __restrict__ rp, const float* __restrict__ bias, int nepi)
{
  constexpr int BK = 64;
  constexpr int MR = BM / WR / 16;
  constexpr int NR = BN / WC / 16;
  constexpr int LD_A = BM * BK / (NTH * 8);
  constexpr int LD_B = BN * BK / (NTH * 8);
  __shared__ __align__(16) u16 As[2][BM * BK];
  __shared__ __align__(16) u16 Bs[2][BN * BK];
  int tid = threadIdx.x, lane = tid & 63, w = tid >> 6;
  int wm = w / WC, wn = w % WC;
  int m0, n0;
  xcd_block(BM, BN, m0, n0);

  floatx4 acc[MR][NR];
  #pragma unroll
  for (int i = 0; i < MR; ++i)
    #pragma unroll
    for (int j = 0; j < NR; ++j)
      acc[i][j] = (floatx4){0.f, 0.f, 0.f, 0.f};

  auto stage = [&](int buf, int k0) {
    #pragma unroll
    for (int p = 0; p < LD_A; ++p) {
      int c = p * NTH + tid;
      int row = c >> 3;
      int src16 = (c & 7) ^ (row & 7);
      load_lds16(A + (size_t)(m0 + row) * lda + k0 + src16 * 8,
                 &As[buf][p * NTH * 8 + w * 512]);
    }
    #pragma unroll
    for (int p = 0; p < LD_B; ++p) {
      int c = p * NTH + tid;
      int row = c >> 3;
      int src16 = (c & 7) ^ (row & 7);
      load_lds16(Bm + (size_t)(n0 + row) * ldb + k0 + src16 * 8,
                 &Bs[buf][p * NTH * 8 + w * 512]);
    }
  };

  int nt = K / BK;
  stage(0, 0);
  __syncthreads();
  int cur = 0;
  int hi = lane >> 4;
  int rsw = lane & 7;
  for (int kt = 0; kt < nt; ++kt) {
    if (kt + 1 < nt) stage(cur ^ 1, (kt + 1) * BK);
    #pragma unroll
    for (int ks = 0; ks < 2; ++ks) {
      int chk = ((ks << 2) | hi) ^ rsw;
      short8 a[MR], b[NR];
      #pragma unroll
      for (int i = 0; i < MR; ++i)
        a[i] = *(const short8*)&As[cur][(wm * (BM / WR) + i * 16 + (lane & 15)) * BK + chk * 8];
      #pragma unroll
      for (int j = 0; j < NR; ++j)
        b[j] = *(const short8*)&Bs[cur][(wn * (BN / WC) + j * 16 + (lane & 15)) * BK + chk * 8];
      #pragma unroll
      for (int i = 0; i < MR; ++i)
        #pragma unroll
        for (int j = 0; j < NR; ++j)
          acc[i][j] = __builtin_amdgcn_mfma_f32_16x16x32_bf16(a[i], b[j], acc[i][j], 0, 0, 0);
    }
    __syncthreads();
    cur ^= 1;
  }

  #pragma unroll
  for (int i = 0; i < MR; ++i) {
    #pragma unroll
    for (int j = 0; j < NR; ++j) {
      floatx4 v = acc[i][j];
      int col = n0 + wn * (BN / WC) + j * 16 + (lane & 15);
      int rb = m0 + wm * (BM / WR) + i * 16 + ((lane >> 4) << 2);
      #pragma unroll
      for (int qq = 0; qq < 4; ++qq)
        epi_write<EPI>(rb + qq, col, v[qq], outF, outU, ldc, rp, bias, nepi);
    }
  }
}

// ---------------- GEMM (NT), single-buffer, 128x128, 4 blocks/CU -----------
template<int EPI>
__global__ void __launch_bounds__(256, 4) k_gemm2s(
    const u16* __restrict__ A, int lda,
    const u16* __restrict__ Bm, int ldb, int K,
    float* __restrict__ outF, u16* __restrict__ outU, int ldc,
    const float* __restrict__ rp, const float* __restrict__ bias, int nepi)
{
  constexpr int BM = 128, BN = 128, BK = 64, NTH = 256;
  constexpr int MR = 4, NR = 4;
  __shared__ __align__(16) u16 As[BM * BK];
  __shared__ __align__(16) u16 Bs[BN * BK];
  int tid = threadIdx.x, lane = tid & 63, w = tid >> 6;
  int wm = w >> 1, wn = w & 1;
  int m0, n0;
  xcd_block(BM, BN, m0, n0);

  floatx4 acc[MR][NR];
  #pragma unroll
  for (int i = 0; i < MR; ++i)
    #pragma unroll
    for (int j = 0; j < NR; ++j)
      acc[i][j] = (floatx4){0.f, 0.f, 0.f, 0.f};

  int hi = lane >> 4;
  int rsw = lane & 7;
  int nt = K / BK;
  for (int kt = 0; kt < nt; ++kt) {
    int k0 = kt * BK;
    #pragma unroll
    for (int p = 0; p < 4; ++p) {
      int c = p * NTH + tid;
      int row = c >> 3;
      int src16 = (c & 7) ^ (row & 7);
      load_lds16(A + (size_t)(m0 + row) * lda + k0 + src16 * 8,
                 &As[p * NTH * 8 + w * 512]);
    }
    #pragma unroll
    for (int p = 0; p < 4; ++p) {
      int c = p * NTH + tid;
      int row = c >> 3;
      int src16 = (c & 7) ^ (row & 7);
      load_lds16(Bm + (size_t)(n0 + row) * ldb + k0 + src16 * 8,
                 &Bs[p * NTH * 8 + w * 512]);
    }
    __syncthreads();
    #pragma unroll
    for (int ks = 0; ks < 2; ++ks) {
      int chk = ((ks << 2) | hi) ^ rsw;
      short8 a[MR], b[NR];
      #pragma unroll
      for (int i = 0; i < MR; ++i)
        a[i] = *(const short8*)&As[(wm * 64 + i * 16 + (lane & 15)) * BK + chk * 8];
      #pragma unroll
      for (int j = 0; j < NR; ++j)
        b[j] = *(const short8*)&Bs[(wn * 64 + j * 16 + (lane & 15)) * BK + chk * 8];
      #pragma unroll
      for (int i = 0; i < MR; ++i)
        #pragma unroll
        for (int j = 0; j < NR; ++j)
          acc[i][j] = __builtin_amdgcn_mfma_f32_16x16x32_bf16(a[i], b[j], acc[i][j], 0, 0, 0);
    }
    __syncthreads();
  }

  #pragma unroll
  for (int i = 0; i < MR; ++i) {
    #pragma unroll
    for (int j = 0; j < NR; ++j) {
      floatx4 v = acc[i][j];
      int col = n0 + wn * 64 + j * 16 + (lane & 15);
      int rb = m0 + wm * 64 + i * 16 + ((lane >> 4) << 2);
      #pragma unroll
      for (int qq = 0; qq < 4; ++qq)
        epi_write<EPI>(rb + qq, col, v[qq], outF, outU, ldc, rp, bias, nepi);
    }
  }
}

// ---------------- softmax + entropy (bf16 logits in-place) ----------------
__global__ void __launch_bounds__(256) k_softmax(
    u16* __restrict__ probs_bf, const int* __restrict__ mask,
    float* __restrict__ probs, float* __restrict__ entropy)
{
  int row = blockIdx.x;
  int tid = threadIdx.x;
  u16* pb = probs_bf + (size_t)row * PHE;
  float* pp = probs + (size_t)row * PHE;
  if (mask[row] != 0) {
    const float u = 1.0f / (float)PHE;
    const u16 ub = f2bf(u);
    for (int i = tid; i < PHE; i += 256) { pp[i] = u; pb[i] = ub; }
    if (tid == 0) entropy[row] = 0.f;
    return;
  }
  float l[8];
  float mx = -BIGF;
  #pragma unroll
  for (int j = 0; j < 8; ++j) { l[j] = bf2f(pb[tid + j * 256]); mx = fmaxf(mx, l[j]); }
  mx = blockRedMax(mx);
  float s = 0.f;
  #pragma unroll
  for (int j = 0; j < 8; ++j) { l[j] = __expf(l[j] - mx); s += l[j]; }
  s = blockRedSum(s);
  float inv = 1.0f / s;
  float ent = 0.f;
  #pragma unroll
  for (int j = 0; j < 8; ++j) {
    float p = l[j] * inv;
    pp[tid + j * 256] = p;
    pb[tid + j * 256] = f2bf(p);
    ent += p * __logf(p);
  }
  ent = blockRedSum(ent);
  if (tid == 0) entropy[row] = -ent;
}

// ---------------- add + layernorm ----------------
__global__ void __launch_bounds__(256) k_ln(
    const float* __restrict__ xa, const float* __restrict__ xb,
    const float* __restrict__ g, const float* __restrict__ bb,
    float* __restrict__ outF, u16* __restrict__ outBf)
{
  int row = blockIdx.x;
  int tid = threadIdx.x;
  const float* pa = xa + (size_t)row * DIM;
  const float* pb = xb + (size_t)row * DIM;
  float x0 = pa[tid] + pb[tid];
  float x1 = pa[tid + 256] + pb[tid + 256];
  float mu = blockRedSum(x0 + x1) * (1.0f / DIM);
  float d0 = x0 - mu, d1 = x1 - mu;
  float var = blockRedSum(d0 * d0 + d1 * d1) * (1.0f / DIM);
  float rs = 1.0f / sqrtf(var + LNEPS);
  float y0 = d0 * rs * g[tid] + bb[tid];
  float y1 = d1 * rs * g[tid + 256] + bb[tid + 256];
  if (outF) {
    outF[(size_t)row * DIM + tid] = y0;
    outF[(size_t)row * DIM + tid + 256] = y1;
  }
  if (outBf) {
    outBf[(size_t)row * DIM + tid] = f2bf(y0);
    outBf[(size_t)row * DIM + tid + 256] = f2bf(y1);
  }
}

// ---------------- radix smallest-k per row, f32 keys ----------------
template<int NPER>
__global__ void __launch_bounds__(256) k_rsel(
    const float* __restrict__ in, int ldin, int ncols, int k, int mode,
    float* __restrict__ out)
{
  __shared__ int hist[1024];
  __shared__ int cum[256];
  __shared__ int wsum[4];
  __shared__ int sel_bucket, sel_rank;
  int row = blockIdx.x;
  int tid = threadIdx.x;
  int lane = tid & 63, w = tid >> 6;
  int hbase = w << 8;
  const float* src = in + (size_t)row * ldin;

  unsigned int v[NPER];
  #pragma unroll
  for (int j = 0; j < NPER; ++j) {
    int idx = tid + j * 256;
    v[j] = (idx < ncols) ? f2mono(src[idx]) : 0xFFFFFFFFu;
  }

  unsigned int prefix = 0, pmask = 0;
  int kk = k;
  for (int shift = 24; shift >= 0; shift -= 8) {
    hist[tid] = 0; hist[tid + 256] = 0; hist[tid + 512] = 0; hist[tid + 768] = 0;
    __syncthreads();
    #pragma unroll
    for (int j = 0; j < NPER; ++j)
      hist_add2(hist + hbase, (int)((v[j] >> shift) & 255), (v[j] & pmask) == prefix);
    __syncthreads();
    int x = hist[tid] + hist[tid + 256] + hist[tid + 512] + hist[tid + 768];
    #pragma unroll
    for (int off = 1; off < 64; off <<= 1) {
      int y = __shfl_up(x, off);
      if (lane >= off) x += y;
    }
    if (lane == 63) wsum[w] = x;
    __syncthreads();
    #pragma unroll
    for (int i = 0; i < 4; ++i) if (i < w) x += wsum[i];
    cum[tid] = x;
    __syncthreads();
    int prev = (tid == 0) ? 0 : cum[tid - 1];
    if (prev < kk && kk <= cum[tid]) { sel_bucket = tid; sel_rank = kk - prev; }
    __syncthreads();
    prefix |= ((unsigned int)sel_bucket) << shift;
    pmask |= 255u << shift;
    kk = sel_rank;
    __syncthreads();
  }

  float thr = mono2f(prefix);
  int need = kk;

  float s = 0.f, se = 0.f, sq = 0.f;
  #pragma unroll
  for (int j = 0; j < NPER; ++j) {
    if (v[j] < prefix) {
      float f = mono2f(v[j]);
      s += f; se += __expf(-f); sq += f * f;
    }
  }
  float ts = blockRedSum(s);
  float tse = blockRedSum(se);
  float tsq = blockRedSum(sq);
  if (tid == 0) {
    float fn = (float)need;
    ts += fn * thr;
    if (mode == 1) {
      out[row] = ts;
    } else {
      tse += fn * __expf(-thr);
      tsq += fn * thr * thr;
      out[(size_t)row * 4] = ts;
      out[(size_t)row * 4 + 1] = tse;
      out[(size_t)row * 4 + 2] = tsq;
    }
  }
}

// ---------------- final scalar reductions ----------------
__global__ void __launch_bounds__(256) k_final(
    const float* __restrict__ row_sum50, const float* __restrict__ pp_part,
    float* __restrict__ out_pcd, float* __restrict__ out_inv,
    float* __restrict__ out_mean, float* __restrict__ out_var)
{
  int tid = threadIdx.x;
  double s50 = 0, sn = 0, se = 0, sq = 0;
  for (int i = tid; i < PHE; i += 256) {
    s50 += (double)row_sum50[i];
    sn += (double)pp_part[(size_t)i * 4];
    se += (double)pp_part[(size_t)i * 4 + 1];
    sq += (double)pp_part[(size_t)i * 4 + 2];
  }
  s50 = blockRedSumD(s50);
  sn = blockRedSumD(sn);
  se = blockRedSumD(se);
  sq = blockRedSumD(sq);
  if (tid == 0) {
    *out_pcd = (float)(s50 / (double)(PHE * KC));
    double mean = sn / (double)(PHE * KP);
    *out_inv = (float)(se / (double)(PHE * KP));
    *out_mean = (float)mean;
    *out_var = (float)(sq / (double)(PHE * KP) - mean * mean);
  }
}

// ---------------- host ----------------
extern "C" void kernel_launch(void* const* d_in, const int* in_sizes, int n_in,
                              void* d_out, int out_size, void* d_ws, size_t ws_size,
                              hipStream_t stream)
{
  const float* visit = (const float*)d_in[0];
  const int*   vmask = (const int*)d_in[1];
  const float* emb   = (const float*)d_in[2];
  const float* phe   = (const float*)d_in[3];
  const float* w1    = (const float*)d_in[4];
  const float* b1    = (const float*)d_in[5];
  const float* w2    = (const float*)d_in[6];
  const float* b2    = (const float*)d_in[7];
  const float* ln1g  = (const float*)d_in[8];
  const float* ln1b  = (const float*)d_in[9];
  const float* ln2g  = (const float*)d_in[10];
  const float* ln2b  = (const float*)d_in[11];

  float* out = (float*)d_out;
  float* out2      = out;
  float* probs     = out + (size_t)BT * DIM;
  float* pcd       = probs + (size_t)BT * PHE;
  float* entropy   = pcd + 1;
  float* inv_loss  = entropy + BT;
  float* dist_mean = inv_loss + 1;
  float* dist_var  = dist_mean + 1;

  char* wsb = (char*)d_ws;
  size_t off = 0;
  auto alloc = [&](size_t bytes) -> char* {
    char* p = wsb + off;
    off = (off + bytes + 255) & ~(size_t)255;
    return p;
  };
  u16* phe_bf   = (u16*)alloc((size_t)PHE * DIM * 2);
  u16* pheT_bf  = (u16*)alloc((size_t)DIM * PHE * 2);
  u16* visit_bf = (u16*)alloc((size_t)BT * DIM * 2);
  u16* w1T_bf   = (u16*)alloc((size_t)DFFP2 * DIM * 2);
  u16* w2T_bf   = (u16*)alloc((size_t)DIM * DFFP2 * 2);
  float* r_p    = (float*)alloc((size_t)PHE * 4);
  float* r_c    = (float*)alloc((size_t)VOC * 4);
  char* big1    = alloc((size_t)67108864);            // 2x bf16 d-chunk ping-pong
  char* big2    = alloc((size_t)VOCP * DIM * 2);      // emb_bf padded -> h_bf [BT][DFFP2]
  float* top50c = (float*)alloc((size_t)PHE * NCHUNK * 2 * KC * 4);
  char* big3    = alloc((size_t)PHE * PHE * 4);       // d_pp f32 -> ctx_f [BT][DIM]
  u16* probs_bf = (u16*)alloc((size_t)BT * PHE * 2);  // logits bf16 -> probs (in-place)
  float* out1_f = (float*)alloc((size_t)BT * DIM * 4);
  u16* out1_bf  = (u16*)alloc((size_t)BT * DIM * 2);
  float* ffn_f  = (float*)alloc((size_t)BT * DIM * 4);
  float* row_sum50 = (float*)alloc((size_t)PHE * 4);
  float* pp_part   = (float*)alloc((size_t)PHE * 4 * 4);

  u16* dchunk0  = (u16*)big1;
  u16* dchunk1  = (u16*)(big1 + 33554432);
  u16* emb_bf   = (u16*)big2;
  u16* h_bf     = (u16*)big2;
  float* d_pp   = (float*)big3;
  float* ctx_f  = (float*)big3;

  if (ws_size < off) { k_sentinel<<<1, 1, 0, stream>>>(out); return; }

  // slim prologue: phe rows + emb chunk-0 rows only
  k_prep_a<<<PHE + CHUNK, 256, 0, stream>>>(phe, phe_bf, r_p, emb, emb_bf, r_c);

  // DPC pipeline: L_c = gemm(c) || select(c-1) || aux prep (emb-cvt c+1, and
  // on L0 also visit cvt + pheT + w1T + w2T). L5 = logits-gemm || select(c4).
  for (int c = 0; c < NCHUNK; ++c) {
    int s = c - 1;
    int nsel = (s >= 0) ? PHE * 2 : 0;
    int cvtc = c + 1;
    int ncvt = (cvtc < NCHUNK) ? ((VOC - cvtc * CHUNK < CHUNK) ? VOC - cvtc * CHUNK : CHUNK) : 0;
    int nvis = (c == 0) ? 2048 : 0;
    int npht = (c == 0) ? (DIM * PHE / 256) : 0;      // 4096
    int nw1  = (c == 0) ? (DFFP2 * DIM / 256) : 0;    // 4608
    int nw2  = (c == 0) ? (DIM * DFFP2 / 256) : 0;    // 4608
    u16* dw = (c & 1) ? dchunk1 : dchunk0;
    const u16* dr = (s >= 0) ? ((s & 1) ? dchunk1 : dchunk0) : nullptr;
    k_dpc<<<1024 + nsel + ncvt + nvis + npht + nw1 + nw2, 256, 0, stream>>>(
        phe_bf, emb_bf, c, 1024, dw, dr, s, top50c, r_p, r_c, nsel,
        ncvt, cvtc * CHUNK, emb, emb_bf, r_c,
        nvis, visit, visit_bf,
        npht, phe, pheT_bf,
        nw1, w1, w1T_bf,
        nw2, w2, w2T_bf);
  }
  k_dpc_log<<<1024 + PHE * 2, 256, 0, stream>>>(
      visit_bf, phe_bf, 1024, probs_bf,
      (NCHUNK - 1) & 1 ? dchunk1 : dchunk0, NCHUNK - 1, top50c);
  k_rsel<2><<<PHE, 256, 0, stream>>>(top50c, NCHUNK * 2 * KC, NCHUNK * 2 * KC, KC, 1, row_sum50);

  // phenotype-phenotype squared distances + smallest-10 stats
  k_gemm2<EPI_DPP, 128, 128, 256, 2, 2><<<dim3(PHE / 128, PHE / 128), 256, 0, stream>>>(
      phe_bf, DIM, phe_bf, DIM, DIM, d_pp, nullptr, PHE, r_p, nullptr, 0);
  k_rsel<8><<<PHE, 256, 0, stream>>>(d_pp, PHE, PHE, KP, 2, pp_part);

  // softmax (in-place bf16 logits) -> ctx
  k_softmax<<<BT, 256, 0, stream>>>(probs_bf, vmask, probs, entropy);
  k_gemm2<EPI_STORE, 64, 128, 256, 2, 2><<<dim3(DIM / 128, BT / 64), 256, 0, stream>>>(
      probs_bf, PHE, pheT_bf, PHE, PHE, ctx_f, nullptr, DIM, nullptr, nullptr, 0);

  // LN1, FFN, LN2
  k_ln<<<BT, 256, 0, stream>>>(visit, ctx_f, ln1g, ln1b, out1_f, out1_bf);
  k_gemm2s<EPI_FFN1><<<dim3(DFFP2 / 128, BT / 128), 256, 0, stream>>>(
      out1_bf, DIM, w1T_bf, DIM, DIM, nullptr, h_bf, DFFP2, nullptr, b1, DFF);
  k_gemm2<EPI_FFN2, 64, 128, 256, 2, 2><<<dim3(DIM / 128, BT / 64), 256, 0, stream>>>(
      h_bf, DFFP2, w2T_bf, DFFP2, DFFP2, ffn_f, nullptr, DIM, nullptr, b2, 0);
  k_ln<<<BT, 256, 0, stream>>>(out1_f, ffn_f, ln2g, ln2b, out2, nullptr);

  // scalars
  k_final<<<1, 256, 0, stream>>>(row_sum50, pp_part, pcd, inv_loss, dist_mean, dist_var);
}

// Round 15
// 564.859 us; speedup vs baseline: 1.0487x; 1.0487x over previous
//
#include <hip/hip_runtime.h>
#include <stdint.h>
#include <stddef.h>

#define BATCH 32
#define TLEN 256
#define DIM 512
#define PHE 2048
#define VOC 40000
#define VOCP 40960
#define DFF 2148
#define DFFP2 2304
#define BT 8192
#define KC 50
#define KP 10
#define CHUNK 8192
#define NCHUNK 5
#define LNEPS 1e-6f
#define BIGF 1e30f

typedef unsigned short u16;
typedef __attribute__((ext_vector_type(8))) short short8;
typedef __attribute__((ext_vector_type(8))) unsigned short ushort8;
typedef __attribute__((ext_vector_type(4))) float floatx4;

__device__ inline u16 f2bf(float f) {
  union { float f; unsigned int u; } v; v.f = f;
  unsigned int u = v.u;
  return (u16)((u + 0x7fffu + ((u >> 16) & 1u)) >> 16);
}
__device__ inline float bf2f(u16 u) {
  union { unsigned int u; float f; } c; c.u = ((unsigned int)u) << 16;
  return c.f;
}

// monotone float<->uint transforms
__device__ inline unsigned int f2mono(float f) {
  union { float f; unsigned int u; } c; c.f = f;
  return (c.u & 0x80000000u) ? ~c.u : (c.u | 0x80000000u);
}
__device__ inline float mono2f(unsigned int u) {
  union { unsigned int u; float f; } c;
  c.u = (u & 0x80000000u) ? (u & 0x7FFFFFFFu) : ~u;
  return c.f;
}
__device__ inline unsigned int mono16(u16 u) {
  return (u & 0x8000u) ? (u16)~u : (u16)(u | 0x8000u);
}
__device__ inline float mono2f16(unsigned int k) {
  unsigned int ub = (k & 0x8000u) ? (k & 0x7FFFu) : ((~k) & 0xFFFFu);
  union { unsigned int u; float f; } c; c.u = ub << 16;
  return c.f;
}

// async global->LDS, 16 bytes per lane; LDS dest is wave-uniform base + lane*16B
__device__ inline void load_lds16(const void* g, void* l) {
  __builtin_amdgcn_global_load_lds(
      (const __attribute__((address_space(1))) unsigned int*)g,
      (__attribute__((address_space(3))) unsigned int*)l, 16, 0, 0);
}

// ---------------- reduction helpers ----------------
__device__ inline float waveRedSum(float v) {
  #pragma unroll
  for (int off = 32; off > 0; off >>= 1) v += __shfl_down(v, off);
  return v;
}
__device__ inline float waveRedMax(float v) {
  #pragma unroll
  for (int off = 32; off > 0; off >>= 1) v = fmaxf(v, __shfl_down(v, off));
  return v;
}
__device__ inline float blockRedSum(float v) {
  __shared__ float sm[8];
  int lane = threadIdx.x & 63, w = threadIdx.x >> 6, nw = blockDim.x >> 6;
  v = waveRedSum(v);
  __syncthreads();
  if (lane == 0) sm[w] = v;
  __syncthreads();
  float r = 0.f;
  for (int i = 0; i < nw; ++i) r += sm[i];
  return r;
}
__device__ inline float blockRedMax(float v) {
  __shared__ float sm2[8];
  int lane = threadIdx.x & 63, w = threadIdx.x >> 6, nw = blockDim.x >> 6;
  v = waveRedMax(v);
  __syncthreads();
  if (lane == 0) sm2[w] = v;
  __syncthreads();
  float r = -BIGF;
  for (int i = 0; i < nw; ++i) r = fmaxf(r, sm2[i]);
  return r;
}
__device__ inline double blockRedSumD(double v) {
  __shared__ double red[256];
  int tid = threadIdx.x;
  __syncthreads();
  red[tid] = v;
  __syncthreads();
  for (int s = 128; s > 0; s >>= 1) {
    if (tid < s) red[tid] += red[tid + s];
    __syncthreads();
  }
  return red[0];
}

// dominance-test histogram add (deterministic integer adds)
__device__ inline void hist_add2(int* hist, int digit, bool pred) {
  int lane = threadIdx.x & 63;
  unsigned long long act = __ballot(pred);
  if (!act) return;
  int src = __ffsll((long long)act) - 1;
  int ld = __shfl(digit, src);
  unsigned long long m = __ballot(pred && digit == ld);
  if (__popcll(m) >= 32) {
    if (lane == src) atomicAdd(&hist[ld], (int)__popcll(m));
    if ((act & ~m) & (1ull << lane)) atomicAdd(&hist[digit], 1);
  } else {
    if (pred) atomicAdd(&hist[digit], 1);
  }
}

// ---------------- small utility kernels ----------------
__global__ void k_sentinel(float* out) { out[0] = -12345.0f; }

// fused prep with LDS-tiled COALESCED transposes.
// roles: [0,VOC+PHE) row cvt+sumsq | vis 2048 | pheT 1024 tiles |
//        w1T 1152 tiles | w2T 1152 tiles. tile = 32x32, padded smem.
#define PREP_VIS 2048
#define PREP_PHT 1024
#define PREP_W1  1152
#define PREP_W2  1152
__global__ void __launch_bounds__(256) k_prep(
    const float* __restrict__ emb, u16* __restrict__ emb_bf, float* __restrict__ r_c,
    const float* __restrict__ phe, u16* __restrict__ phe_bf, float* __restrict__ r_p,
    const float* __restrict__ visit, u16* __restrict__ visit_bf,
    u16* __restrict__ pheT_bf,
    const float* __restrict__ w1, u16* __restrict__ w1T_bf,
    const float* __restrict__ w2, u16* __restrict__ w2T_bf)
{
  __shared__ float tile[32][33];
  int bid = (int)blockIdx.x, tid = threadIdx.x;
  if (bid < VOC + PHE) {
    const float* src = (bid < VOC) ? emb + (size_t)bid * DIM
                                   : phe + (size_t)(bid - VOC) * DIM;
    u16* dst = (bid < VOC) ? emb_bf + (size_t)bid * DIM
                           : phe_bf + (size_t)(bid - VOC) * DIM;
    float a = src[tid], b = src[tid + 256];
    dst[tid] = f2bf(a); dst[tid + 256] = f2bf(b);
    float s = blockRedSum(a * a + b * b);
    if (tid == 0) {
      if (bid < VOC) r_c[bid] = s; else r_p[bid - VOC] = s;
    }
    return;
  }
  int b2 = bid - (VOC + PHE);
  int rr = tid >> 5, cc = tid & 31;
  if (b2 < PREP_VIS) {
    int base = b2 * 2048 + tid;
    #pragma unroll
    for (int e = 0; e < 8; ++e) {
      int i = base + e * 256;
      visit_bf[i] = f2bf(visit[i]);
    }
    return;
  }
  b2 -= PREP_VIS;
  if (b2 < PREP_PHT) {
    // pheT[j][i] = phe[i][j]; tile: src rows i0.., cols j0..
    int i0 = (b2 >> 4) << 5, j0 = (b2 & 15) << 5;
    #pragma unroll
    for (int p = 0; p < 4; ++p)
      tile[p * 8 + rr][cc] = phe[(size_t)(i0 + p * 8 + rr) * DIM + j0 + cc];
    __syncthreads();
    #pragma unroll
    for (int p = 0; p < 4; ++p)
      pheT_bf[(size_t)(j0 + p * 8 + rr) * PHE + i0 + cc] = f2bf(tile[cc][p * 8 + rr]);
    return;
  }
  b2 -= PREP_PHT;
  if (b2 < PREP_W1) {
    // w1T[r][c] = (r<DFF) ? w1[c][r] : 0 ; dst [DFFP2][DIM], src [DIM][DFF]
    int r0 = (b2 >> 4) << 5, c0 = (b2 & 15) << 5;
    #pragma unroll
    for (int p = 0; p < 4; ++p) {
      int i = p * 8 + rr;                 // c-offset
      tile[i][cc] = (r0 + cc < DFF) ? w1[(size_t)(c0 + i) * DFF + r0 + cc] : 0.f;
    }
    __syncthreads();
    #pragma unroll
    for (int p = 0; p < 4; ++p) {
      int a = p * 8 + rr;                 // r-offset
      w1T_bf[(size_t)(r0 + a) * DIM + c0 + cc] = f2bf(tile[cc][a]);
    }
    return;
  }
  b2 -= PREP_W1;
  {
    // w2T[r][c] = (c<DFF) ? w2[c][r] : 0 ; dst [DIM][DFFP2], src [DFF][DIM]
    int r0 = (b2 / 72) << 5, c0 = (b2 % 72) << 5;
    #pragma unroll
    for (int p = 0; p < 4; ++p) {
      int i = p * 8 + rr;                 // c-offset
      tile[i][cc] = (c0 + i < DFF) ? w2[(size_t)(c0 + i) * DIM + r0 + cc] : 0.f;
    }
    __syncthreads();
    #pragma unroll
    for (int p = 0; p < 4; ++p) {
      int a = p * 8 + rr;                 // r-offset
      w2T_bf[(size_t)(r0 + a) * DFFP2 + c0 + cc] = f2bf(tile[cc][a]);
    }
    return;
  }
}

#define EPI_STORE 0
#define EPI_DPP   1
#define EPI_FFN1  3
#define EPI_FFN2  4

// XCD-aware bijective block swizzle (m204)
__device__ inline void xcd_block(int BM, int BN, int& m0, int& n0) {
  int nwg = gridDim.x * gridDim.y;
  int orig = blockIdx.y * gridDim.x + blockIdx.x;
  int q = nwg >> 3, r = nwg & 7;
  int xcd = orig & 7, i0 = orig >> 3;
  int wgid = (xcd < r ? xcd * (q + 1) : r * (q + 1) + (xcd - r) * q) + i0;
  m0 = (wgid / gridDim.x) * BM;
  n0 = (wgid % gridDim.x) * BN;
}

template<int EPI>
__device__ inline void epi_write(int rr, int col, float c,
    float* outF, u16* outU, int ldc, const float* rp,
    const float* bias, int nepi) {
  if (EPI == EPI_STORE) {
    outF[(size_t)rr * ldc + col] = c;
  } else if (EPI == EPI_DPP) {
    outF[(size_t)rr * ldc + col] = rp[rr] + rp[col] - 2.f * c;
  } else if (EPI == EPI_FFN1) {
    float h = (col < nepi) ? fmaxf(c + bias[col], 0.f) : 0.f;
    outU[(size_t)rr * ldc + col] = f2bf(h);
  } else if (EPI == EPI_FFN2) {
    outF[(size_t)rr * ldc + col] = c + bias[col];
  }
}

// ---------------- DPC select body (shared by k_dpc / k_dpc_log) -----------
__device__ __forceinline__ void dpc_select(
    char* smem, int si, const u16* __restrict__ dr, int schunk,
    float* __restrict__ top)
{
  int row = si >> 1, half = si & 1;
  const u16* src = dr + (size_t)row * CHUNK + half * 4096;
  int* hist = (int*)smem;
  int* cum  = hist + 1024;
  int* wred = cum + 256;
  int* selb = wred + 8;
  int tid = threadIdx.x, lane = tid & 63, w4 = tid >> 6;
  int hbase = w4 << 8;

  unsigned int kv[16];
  #pragma unroll
  for (int j2 = 0; j2 < 2; ++j2) {
    ushort8 qv = *(const ushort8*)(src + j2 * 2048 + tid * 8);
    #pragma unroll
    for (int e = 0; e < 8; ++e) kv[j2 * 8 + e] = mono16((u16)qv[e]);
  }

  int hbmin = 255, hbmax = 0;
  #pragma unroll
  for (int j = 0; j < 16; ++j) {
    int hb = (int)(kv[j] >> 8);
    hbmin = min(hbmin, hb); hbmax = max(hbmax, hb);
  }
  #pragma unroll
  for (int off = 32; off > 0; off >>= 1) {
    hbmin = min(hbmin, __shfl_down(hbmin, off));
    hbmax = max(hbmax, __shfl_down(hbmax, off));
  }
  if (lane == 0) { wred[w4] = hbmin; wred[4 + w4] = hbmax; }
  __syncthreads();
  int bmin = min(min(wred[0], wred[1]), min(wred[2], wred[3]));
  int bmax = max(max(wred[4], wred[5]), max(wred[6], wred[7]));
  __syncthreads();

  unsigned int prefix;
  int kk = KC;
  if (bmin == bmax) {
    prefix = (unsigned int)bmin;
  } else {
    hist[tid] = 0; hist[tid + 256] = 0; hist[tid + 512] = 0; hist[tid + 768] = 0;
    __syncthreads();
    #pragma unroll
    for (int j = 0; j < 16; ++j) hist_add2(hist + hbase, (int)(kv[j] >> 8), true);
    __syncthreads();
    int x = hist[tid] + hist[tid + 256] + hist[tid + 512] + hist[tid + 768];
    #pragma unroll
    for (int off = 1; off < 64; off <<= 1) { int y = __shfl_up(x, off); if (lane >= off) x += y; }
    if (lane == 63) wred[w4] = x;
    __syncthreads();
    #pragma unroll
    for (int i = 0; i < 4; ++i) if (i < w4) x += wred[i];
    cum[tid] = x;
    __syncthreads();
    int prev = (tid == 0) ? 0 : cum[tid - 1];
    if (prev < kk && kk <= cum[tid]) { selb[0] = tid; selb[1] = kk - prev; }
    __syncthreads();
    prefix = (unsigned int)selb[0];
    kk = selb[1];
    __syncthreads();
  }

  hist[tid] = 0; hist[tid + 256] = 0; hist[tid + 512] = 0; hist[tid + 768] = 0;
  __syncthreads();
  #pragma unroll
  for (int j = 0; j < 16; ++j)
    hist_add2(hist + hbase, (int)(kv[j] & 255u), (kv[j] >> 8) == prefix);
  __syncthreads();
  int x = hist[tid] + hist[tid + 256] + hist[tid + 512] + hist[tid + 768];
  #pragma unroll
  for (int off = 1; off < 64; off <<= 1) { int y = __shfl_up(x, off); if (lane >= off) x += y; }
  if (lane == 63) wred[w4] = x;
  __syncthreads();
  #pragma unroll
  for (int i = 0; i < 4; ++i) if (i < w4) x += wred[i];
  cum[tid] = x;
  __syncthreads();
  int prev = (tid == 0) ? 0 : cum[tid - 1];
  if (prev < kk && kk <= cum[tid]) { selb[0] = tid; selb[1] = kk - prev; }
  __syncthreads();
  unsigned int key = (prefix << 8) | (unsigned int)selb[0];
  float thr = mono2f16(key);
  float* o50 = top + (size_t)row * (NCHUNK * 2 * KC) + (schunk * 2 + half) * KC;
  __syncthreads();

  int cless = 0;
  #pragma unroll
  for (int j = 0; j < 16; ++j) if (kv[j] < key) cless++;
  int xc = cless;
  #pragma unroll
  for (int off = 1; off < 64; off <<= 1) { int y = __shfl_up(xc, off); if (lane >= off) xc += y; }
  if (lane == 63) wred[w4] = xc;
  __syncthreads();
  #pragma unroll
  for (int i = 0; i < 4; ++i) if (i < w4) xc += wred[i];
  int o = xc - cless;
  #pragma unroll
  for (int j = 0; j < 16; ++j)
    if (kv[j] < key) o50[o++] = mono2f16(kv[j]);
  cum[tid] = xc;
  __syncthreads();
  int total_less = cum[255];
  for (int i = total_less + tid; i < KC; i += 256) o50[i] = thr;
}

// ---------------- fused DPC: GEMM(chunk g) || select(chunk s) --------------
__global__ void __launch_bounds__(256, 2) k_dpc(
    const u16* __restrict__ phe_bf, const u16* __restrict__ emb_bf,
    int gchunk, int ngemm, u16* __restrict__ dw,
    const u16* __restrict__ dr, int schunk, float* __restrict__ top,
    const float* __restrict__ rp, const float* __restrict__ rc)
{
  __shared__ __align__(16) char smem[32768];
  int bid = (int)blockIdx.x;
  if (bid < ngemm) {
    u16* As = (u16*)smem;
    u16* Bs = (u16*)(smem + 16384);
    int tid = threadIdx.x, lane = tid & 63, w = tid >> 6;
    int wm = w >> 1, wn = w & 1;
    int nwg = ngemm, orig = bid;
    int q = nwg >> 3, r = nwg & 7;
    int xcd = orig & 7, i0 = orig >> 3;
    int wgid = (xcd < r ? xcd * (q + 1) : r * (q + 1) + (xcd - r) * q) + i0;
    int m0 = (wgid >> 6) << 7;
    int n0 = (wgid & 63) << 7;
    const u16* Bm = emb_bf + (size_t)gchunk * CHUNK * DIM;
    const float* rcc = rc + gchunk * CHUNK;
    int bvalid = VOC - gchunk * CHUNK; if (bvalid > CHUNK) bvalid = CHUNK;

    floatx4 acc[4][4];
    #pragma unroll
    for (int i = 0; i < 4; ++i)
      #pragma unroll
      for (int j = 0; j < 4; ++j)
        acc[i][j] = (floatx4){0.f, 0.f, 0.f, 0.f};

    int hi = lane >> 4, rsw = lane & 7;
    for (int kt = 0; kt < DIM / 64; ++kt) {
      int k0 = kt * 64;
      #pragma unroll
      for (int p = 0; p < 4; ++p) {
        int c = p * 256 + tid;
        int row = c >> 3;
        int src16 = (c & 7) ^ (row & 7);
        load_lds16(phe_bf + (size_t)(m0 + row) * DIM + k0 + src16 * 8,
                   &As[p * 2048 + w * 512]);
      }
      #pragma unroll
      for (int p = 0; p < 4; ++p) {
        int c = p * 256 + tid;
        int row = c >> 3;
        int src16 = (c & 7) ^ (row & 7);
        load_lds16(Bm + (size_t)(n0 + row) * DIM + k0 + src16 * 8,
                   &Bs[p * 2048 + w * 512]);
      }
      __syncthreads();
      #pragma unroll
      for (int ks = 0; ks < 2; ++ks) {
        int chk = ((ks << 2) | hi) ^ rsw;
        short8 a[4], b[4];
        #pragma unroll
        for (int i = 0; i < 4; ++i)
          a[i] = *(const short8*)&As[(wm * 64 + i * 16 + (lane & 15)) * 64 + chk * 8];
        #pragma unroll
        for (int j = 0; j < 4; ++j)
          b[j] = *(const short8*)&Bs[(wn * 64 + j * 16 + (lane & 15)) * 64 + chk * 8];
        #pragma unroll
        for (int i = 0; i < 4; ++i)
          #pragma unroll
          for (int j = 0; j < 4; ++j)
            acc[i][j] = __builtin_amdgcn_mfma_f32_16x16x32_bf16(a[i], b[j], acc[i][j], 0, 0, 0);
      }
      __syncthreads();
    }
    #pragma unroll
    for (int i = 0; i < 4; ++i) {
      #pragma unroll
      for (int j = 0; j < 4; ++j) {
        floatx4 v = acc[i][j];
        int col = n0 + wn * 64 + j * 16 + (lane & 15);
        int rb = m0 + wm * 64 + i * 16 + ((lane >> 4) << 2);
        #pragma unroll
        for (int qq = 0; qq < 4; ++qq) {
          int rr = rb + qq;
          float d = (col < bvalid) ? sqrtf(fmaxf(rp[rr] + rcc[col] - 2.f * v[qq], 0.f)) : BIGF;
          dw[(size_t)rr * CHUNK + col] = f2bf(d);
        }
      }
    }
  } else {
    if (schunk < 0) return;
    dpc_select(smem, bid - ngemm, dr, schunk, top);
  }
}

// ---------------- logits GEMM (bf16 store) || tail select -----------------
__global__ void __launch_bounds__(256, 2) k_dpc_log(
    const u16* __restrict__ visit_bf, const u16* __restrict__ phe_bf,
    int ngemm, u16* __restrict__ logit_bf,
    const u16* __restrict__ dr, int schunk, float* __restrict__ top)
{
  __shared__ __align__(16) char smem[32768];
  int bid = (int)blockIdx.x;
  if (bid < ngemm) {
    u16* As = (u16*)smem;
    u16* Bs = (u16*)(smem + 16384);
    int tid = threadIdx.x, lane = tid & 63, w = tid >> 6;
    int wm = w >> 1, wn = w & 1;
    int nwg = ngemm, orig = bid;
    int q = nwg >> 3, r = nwg & 7;
    int xcd = orig & 7, i0 = orig >> 3;
    int wgid = (xcd < r ? xcd * (q + 1) : r * (q + 1) + (xcd - r) * q) + i0;
    int m0 = (wgid >> 4) << 7;        // gridx = PHE/128 = 16
    int n0 = (wgid & 15) << 7;

    floatx4 acc[4][4];
    #pragma unroll
    for (int i = 0; i < 4; ++i)
      #pragma unroll
      for (int j = 0; j < 4; ++j)
        acc[i][j] = (floatx4){0.f, 0.f, 0.f, 0.f};

    int hi = lane >> 4, rsw = lane & 7;
    for (int kt = 0; kt < DIM / 64; ++kt) {
      int k0 = kt * 64;
      #pragma unroll
      for (int p = 0; p < 4; ++p) {
        int c = p * 256 + tid;
        int row = c >> 3;
        int src16 = (c & 7) ^ (row & 7);
        load_lds16(visit_bf + (size_t)(m0 + row) * DIM + k0 + src16 * 8,
                   &As[p * 2048 + w * 512]);
      }
      #pragma unroll
      for (int p = 0; p < 4; ++p) {
        int c = p * 256 + tid;
        int row = c >> 3;
        int src16 = (c & 7) ^ (row & 7);
        load_lds16(phe_bf + (size_t)(n0 + row) * DIM + k0 + src16 * 8,
                   &Bs[p * 2048 + w * 512]);
      }
      __syncthreads();
      #pragma unroll
      for (int ks = 0; ks < 2; ++ks) {
        int chk = ((ks << 2) | hi) ^ rsw;
        short8 a[4], b[4];
        #pragma unroll
        for (int i = 0; i < 4; ++i)
          a[i] = *(const short8*)&As[(wm * 64 + i * 16 + (lane & 15)) * 64 + chk * 8];
        #pragma unroll
        for (int j = 0; j < 4; ++j)
          b[j] = *(const short8*)&Bs[(wn * 64 + j * 16 + (lane & 15)) * 64 + chk * 8];
        #pragma unroll
        for (int i = 0; i < 4; ++i)
          #pragma unroll
          for (int j = 0; j < 4; ++j)
            acc[i][j] = __builtin_amdgcn_mfma_f32_16x16x32_bf16(a[i], b[j], acc[i][j], 0, 0, 0);
      }
      __syncthreads();
    }
    #pragma unroll
    for (int i = 0; i < 4; ++i) {
      #pragma unroll
      for (int j = 0; j < 4; ++j) {
        floatx4 v = acc[i][j];
        int col = n0 + wn * 64 + j * 16 + (lane & 15);
        int rb = m0 + wm * 64 + i * 16 + ((lane >> 4) << 2);
        #pragma unroll
        for (int qq = 0; qq < 4; ++qq)
          logit_bf[(size_t)(rb + qq) * PHE + col] = f2bf(v[qq]);
      }
    }
  } else {
    if (schunk < 0) return;
    dpc_select(smem, bid - ngemm, dr, schunk, top);
  }
}

// ---------------- GEMM (NT), 2-phase double-buffered, BK=64 ----------------
template<int EPI, int BM, int BN, int NTH, int WR, int WC>
__global__ void __launch_bounds__(NTH, 2) k_gemm2(
    const u16* __restrict__ A, int lda,
    const u16* __restrict__ Bm, int ldb, int K,
    float* __restrict__ outF, u16* __restrict__ outU, int ldc,
    const float* __restrict__ rp, const float* __restrict__ bias, int nepi)
{
  constexpr int BK = 64;
  constexpr int MR = BM / WR / 16;
  constexpr int NR = BN / WC / 16;
  constexpr int LD_A = BM * BK / (NTH * 8);
  constexpr int LD_B = BN * BK / (NTH * 8);
  __shared__ __align__(16) u16 As[2][BM * BK];
  __shared__ __align__(16) u16 Bs[2][BN * BK];
  int tid = threadIdx.x, lane = tid & 63, w = tid >> 6;
  int wm = w / WC, wn = w % WC;
  int m0, n0;
  xcd_block(BM, BN, m0, n0);

  floatx4 acc[MR][NR];
  #pragma unroll
  for (int i = 0; i < MR; ++i)
    #pragma unroll
    for (int j = 0; j < NR; ++j)
      acc[i][j] = (floatx4){0.f, 0.f, 0.f, 0.f};

  auto stage = [&](int buf, int k0) {
    #pragma unroll
    for (int p = 0; p < LD_A; ++p) {
      int c = p * NTH + tid;
      int row = c >> 3;
      int src16 = (c & 7) ^ (row & 7);
      load_lds16(A + (size_t)(m0 + row) * lda + k0 + src16 * 8,
                 &As[buf][p * NTH * 8 + w * 512]);
    }
    #pragma unroll
    for (int p = 0; p < LD_B; ++p) {
      int c = p * NTH + tid;
      int row = c >> 3;
      int src16 = (c & 7) ^ (row & 7);
      load_lds16(Bm + (size_t)(n0 + row) * ldb + k0 + src16 * 8,
                 &Bs[buf][p * NTH * 8 + w * 512]);
    }
  };

  int nt = K / BK;
  stage(0, 0);
  __syncthreads();
  int cur = 0;
  int hi = lane >> 4;
  int rsw = lane & 7;
  for (int kt = 0; kt < nt; ++kt) {
    if (kt + 1 < nt) stage(cur ^ 1, (kt + 1) * BK);
    #pragma unroll
    for (int ks = 0; ks < 2; ++ks) {
      int chk = ((ks << 2) | hi) ^ rsw;
      short8 a[MR], b[NR];
      #pragma unroll
      for (int i = 0; i < MR; ++i)
        a[i] = *(const short8*)&As[cur][(wm * (BM / WR) + i * 16 + (lane & 15)) * BK + chk * 8];
      #pragma unroll
      for (int j = 0; j < NR; ++j)
        b[j] = *(const short8*)&Bs[cur][(wn * (BN / WC) + j * 16 + (lane & 15)) * BK + chk * 8];
      #pragma unroll
      for (int i = 0; i < MR; ++i)
        #pragma unroll
        for (int j = 0; j < NR; ++j)
          acc[i][j] = __builtin_amdgcn_mfma_f32_16x16x32_bf16(a[i], b[j], acc[i][j], 0, 0, 0);
    }
    __syncthreads();
    cur ^= 1;
  }

  #pragma unroll
  for (int i = 0; i < MR; ++i) {
    #pragma unroll
    for (int j = 0; j < NR; ++j) {
      floatx4 v = acc[i][j];
      int col = n0 + wn * (BN / WC) + j * 16 + (lane & 15);
      int rb = m0 + wm * (BM / WR) + i * 16 + ((lane >> 4) << 2);
      #pragma unroll
      for (int qq = 0; qq < 4; ++qq)
        epi_write<EPI>(rb + qq, col, v[qq], outF, outU, ldc, rp, bias, nepi);
    }
  }
}

// ---------------- GEMM (NT), single-buffer, 128x128, 4 blocks/CU -----------
template<int EPI>
__global__ void __launch_bounds__(256, 4) k_gemm2s(
    const u16* __restrict__ A, int lda,
    const u16* __restrict__ Bm, int ldb, int K,
    float* __restrict__ outF, u16* __restrict__ outU, int ldc,
    const float* __restrict__ rp, const float* __restrict__ bias, int nepi)
{
  constexpr int BM = 128, BN = 128, BK = 64, NTH = 256;
  constexpr int MR = 4, NR = 4;
  __shared__ __align__(16) u16 As[BM * BK];
  __shared__ __align__(16) u16 Bs[BN * BK];
  int tid = threadIdx.x, lane = tid & 63, w = tid >> 6;
  int wm = w >> 1, wn = w & 1;
  int m0, n0;
  xcd_block(BM, BN, m0, n0);

  floatx4 acc[MR][NR];
  #pragma unroll
  for (int i = 0; i < MR; ++i)
    #pragma unroll
    for (int j = 0; j < NR; ++j)
      acc[i][j] = (floatx4){0.f, 0.f, 0.f, 0.f};

  int hi = lane >> 4;
  int rsw = lane & 7;
  int nt = K / BK;
  for (int kt = 0; kt < nt; ++kt) {
    int k0 = kt * BK;
    #pragma unroll
    for (int p = 0; p < 4; ++p) {
      int c = p * NTH + tid;
      int row = c >> 3;
      int src16 = (c & 7) ^ (row & 7);
      load_lds16(A + (size_t)(m0 + row) * lda + k0 + src16 * 8,
                 &As[p * NTH * 8 + w * 512]);
    }
    #pragma unroll
    for (int p = 0; p < 4; ++p) {
      int c = p * NTH + tid;
      int row = c >> 3;
      int src16 = (c & 7) ^ (row & 7);
      load_lds16(Bm + (size_t)(n0 + row) * ldb + k0 + src16 * 8,
                 &Bs[p * NTH * 8 + w * 512]);
    }
    __syncthreads();
    #pragma unroll
    for (int ks = 0; ks < 2; ++ks) {
      int chk = ((ks << 2) | hi) ^ rsw;
      short8 a[MR], b[NR];
      #pragma unroll
      for (int i = 0; i < MR; ++i)
        a[i] = *(const short8*)&As[(wm * 64 + i * 16 + (lane & 15)) * BK + chk * 8];
      #pragma unroll
      for (int j = 0; j < NR; ++j)
        b[j] = *(const short8*)&Bs[(wn * 64 + j * 16 + (lane & 15)) * BK + chk * 8];
      #pragma unroll
      for (int i = 0; i < MR; ++i)
        #pragma unroll
        for (int j = 0; j < NR; ++j)
          acc[i][j] = __builtin_amdgcn_mfma_f32_16x16x32_bf16(a[i], b[j], acc[i][j], 0, 0, 0);
    }
    __syncthreads();
  }

  #pragma unroll
  for (int i = 0; i < MR; ++i) {
    #pragma unroll
    for (int j = 0; j < NR; ++j) {
      floatx4 v = acc[i][j];
      int col = n0 + wn * 64 + j * 16 + (lane & 15);
      int rb = m0 + wm * 64 + i * 16 + ((lane >> 4) << 2);
      #pragma unroll
      for (int qq = 0; qq < 4; ++qq)
        epi_write<EPI>(rb + qq, col, v[qq], outF, outU, ldc, rp, bias, nepi);
    }
  }
}

// ---------------- softmax + entropy (bf16 logits in-place) ----------------
__global__ void __launch_bounds__(256) k_softmax(
    u16* __restrict__ probs_bf, const int* __restrict__ mask,
    float* __restrict__ probs, float* __restrict__ entropy)
{
  int row = blockIdx.x;
  int tid = threadIdx.x;
  u16* pb = probs_bf + (size_t)row * PHE;
  float* pp = probs + (size_t)row * PHE;
  if (mask[row] != 0) {
    const float u = 1.0f / (float)PHE;
    const u16 ub = f2bf(u);
    for (int i = tid; i < PHE; i += 256) { pp[i] = u; pb[i] = ub; }
    if (tid == 0) entropy[row] = 0.f;
    return;
  }
  float l[8];
  float mx = -BIGF;
  #pragma unroll
  for (int j = 0; j < 8; ++j) { l[j] = bf2f(pb[tid + j * 256]); mx = fmaxf(mx, l[j]); }
  mx = blockRedMax(mx);
  float s = 0.f;
  #pragma unroll
  for (int j = 0; j < 8; ++j) { l[j] = __expf(l[j] - mx); s += l[j]; }
  s = blockRedSum(s);
  float inv = 1.0f / s;
  float ent = 0.f;
  #pragma unroll
  for (int j = 0; j < 8; ++j) {
    float p = l[j] * inv;
    pp[tid + j * 256] = p;
    pb[tid + j * 256] = f2bf(p);
    ent += p * __logf(p);
  }
  ent = blockRedSum(ent);
  if (tid == 0) entropy[row] = -ent;
}

// ---------------- add + layernorm ----------------
__global__ void __launch_bounds__(256) k_ln(
    const float* __restrict__ xa, const float* __restrict__ xb,
    const float* __restrict__ g, const float* __restrict__ bb,
    float* __restrict__ outF, u16* __restrict__ outBf)
{
  int row = blockIdx.x;
  int tid = threadIdx.x;
  const float* pa = xa + (size_t)row * DIM;
  const float* pb = xb + (size_t)row * DIM;
  float x0 = pa[tid] + pb[tid];
  float x1 = pa[tid + 256] + pb[tid + 256];
  float mu = blockRedSum(x0 + x1) * (1.0f / DIM);
  float d0 = x0 - mu, d1 = x1 - mu;
  float var = blockRedSum(d0 * d0 + d1 * d1) * (1.0f / DIM);
  float rs = 1.0f / sqrtf(var + LNEPS);
  float y0 = d0 * rs * g[tid] + bb[tid];
  float y1 = d1 * rs * g[tid + 256] + bb[tid + 256];
  if (outF) {
    outF[(size_t)row * DIM + tid] = y0;
    outF[(size_t)row * DIM + tid + 256] = y1;
  }
  if (outBf) {
    outBf[(size_t)row * DIM + tid] = f2bf(y0);
    outBf[(size_t)row * DIM + tid + 256] = f2bf(y1);
  }
}

// ---------------- radix smallest-k per row, f32 keys ----------------
template<int NPER>
__global__ void __launch_bounds__(256) k_rsel(
    const float* __restrict__ in, int ldin, int ncols, int k, int mode,
    float* __restrict__ out)
{
  __shared__ int hist[1024];
  __shared__ int cum[256];
  __shared__ int wsum[4];
  __shared__ int sel_bucket, sel_rank;
  int row = blockIdx.x;
  int tid = threadIdx.x;
  int lane = tid & 63, w = tid >> 6;
  int hbase = w << 8;
  const float* src = in + (size_t)row * ldin;

  unsigned int v[NPER];
  #pragma unroll
  for (int j = 0; j < NPER; ++j) {
    int idx = tid + j * 256;
    v[j] = (idx < ncols) ? f2mono(src[idx]) : 0xFFFFFFFFu;
  }

  unsigned int prefix = 0, pmask = 0;
  int kk = k;
  for (int shift = 24; shift >= 0; shift -= 8) {
    hist[tid] = 0; hist[tid + 256] = 0; hist[tid + 512] = 0; hist[tid + 768] = 0;
    __syncthreads();
    #pragma unroll
    for (int j = 0; j < NPER; ++j)
      hist_add2(hist + hbase, (int)((v[j] >> shift) & 255), (v[j] & pmask) == prefix);
    __syncthreads();
    int x = hist[tid] + hist[tid + 256] + hist[tid + 512] + hist[tid + 768];
    #pragma unroll
    for (int off = 1; off < 64; off <<= 1) {
      int y = __shfl_up(x, off);
      if (lane >= off) x += y;
    }
    if (lane == 63) wsum[w] = x;
    __syncthreads();
    #pragma unroll
    for (int i = 0; i < 4; ++i) if (i < w) x += wsum[i];
    cum[tid] = x;
    __syncthreads();
    int prev = (tid == 0) ? 0 : cum[tid - 1];
    if (prev < kk && kk <= cum[tid]) { sel_bucket = tid; sel_rank = kk - prev; }
    __syncthreads();
    prefix |= ((unsigned int)sel_bucket) << shift;
    pmask |= 255u << shift;
    kk = sel_rank;
    __syncthreads();
  }

  float thr = mono2f(prefix);
  int need = kk;

  float s = 0.f, se = 0.f, sq = 0.f;
  #pragma unroll
  for (int j = 0; j < NPER; ++j) {
    if (v[j] < prefix) {
      float f = mono2f(v[j]);
      s += f; se += __expf(-f); sq += f * f;
    }
  }
  float ts = blockRedSum(s);
  float tse = blockRedSum(se);
  float tsq = blockRedSum(sq);
  if (tid == 0) {
    float fn = (float)need;
    ts += fn * thr;
    if (mode == 1) {
      out[row] = ts;
    } else {
      tse += fn * __expf(-thr);
      tsq += fn * thr * thr;
      out[(size_t)row * 4] = ts;
      out[(size_t)row * 4 + 1] = tse;
      out[(size_t)row * 4 + 2] = tsq;
    }
  }
}

// ---------------- final scalar reductions ----------------
__global__ void __launch_bounds__(256) k_final(
    const float* __restrict__ row_sum50, const float* __restrict__ pp_part,
    float* __restrict__ out_pcd, float* __restrict__ out_inv,
    float* __restrict__ out_mean, float* __restrict__ out_var)
{
  int tid = threadIdx.x;
  double s50 = 0, sn = 0, se = 0, sq = 0;
  for (int i = tid; i < PHE; i += 256) {
    s50 += (double)row_sum50[i];
    sn += (double)pp_part[(size_t)i * 4];
    se += (double)pp_part[(size_t)i * 4 + 1];
    sq += (double)pp_part[(size_t)i * 4 + 2];
  }
  s50 = blockRedSumD(s50);
  sn = blockRedSumD(sn);
  se = blockRedSumD(se);
  sq = blockRedSumD(sq);
  if (tid == 0) {
    *out_pcd = (float)(s50 / (double)(PHE * KC));
    double mean = sn / (double)(PHE * KP);
    *out_inv = (float)(se / (double)(PHE * KP));
    *out_mean = (float)mean;
    *out_var = (float)(sq / (double)(PHE * KP) - mean * mean);
  }
}

// ---------------- host ----------------
extern "C" void kernel_launch(void* const* d_in, const int* in_sizes, int n_in,
                              void* d_out, int out_size, void* d_ws, size_t ws_size,
                              hipStream_t stream)
{
  const float* visit = (const float*)d_in[0];
  const int*   vmask = (const int*)d_in[1];
  const float* emb   = (const float*)d_in[2];
  const float* phe   = (const float*)d_in[3];
  const float* w1    = (const float*)d_in[4];
  const float* b1    = (const float*)d_in[5];
  const float* w2    = (const float*)d_in[6];
  const float* b2    = (const float*)d_in[7];
  const float* ln1g  = (const float*)d_in[8];
  const float* ln1b  = (const float*)d_in[9];
  const float* ln2g  = (const float*)d_in[10];
  const float* ln2b  = (const float*)d_in[11];

  float* out = (float*)d_out;
  float* out2      = out;
  float* probs     = out + (size_t)BT * DIM;
  float* pcd       = probs + (size_t)BT * PHE;
  float* entropy   = pcd + 1;
  float* inv_loss  = entropy + BT;
  float* dist_mean = inv_loss + 1;
  float* dist_var  = dist_mean + 1;

  char* wsb = (char*)d_ws;
  size_t off = 0;
  auto alloc = [&](size_t bytes) -> char* {
    char* p = wsb + off;
    off = (off + bytes + 255) & ~(size_t)255;
    return p;
  };
  u16* phe_bf   = (u16*)alloc((size_t)PHE * DIM * 2);
  u16* pheT_bf  = (u16*)alloc((size_t)DIM * PHE * 2);
  u16* visit_bf = (u16*)alloc((size_t)BT * DIM * 2);
  u16* w1T_bf   = (u16*)alloc((size_t)DFFP2 * DIM * 2);
  u16* w2T_bf   = (u16*)alloc((size_t)DIM * DFFP2 * 2);
  float* r_p    = (float*)alloc((size_t)PHE * 4);
  float* r_c    = (float*)alloc((size_t)VOC * 4);
  char* big1    = alloc((size_t)67108864);            // 2x bf16 d-chunk ping-pong
  char* big2    = alloc((size_t)VOCP * DIM * 2);      // emb_bf padded -> h_bf [BT][DFFP2]
  float* top50c = (float*)alloc((size_t)PHE * NCHUNK * 2 * KC * 4);
  char* big3    = alloc((size_t)PHE * PHE * 4);       // d_pp f32 -> ctx_f [BT][DIM]
  u16* probs_bf = (u16*)alloc((size_t)BT * PHE * 2);  // logits bf16 -> probs (in-place)
  float* out1_f = (float*)alloc((size_t)BT * DIM * 4);
  u16* out1_bf  = (u16*)alloc((size_t)BT * DIM * 2);
  float* ffn_f  = (float*)alloc((size_t)BT * DIM * 4);
  float* row_sum50 = (float*)alloc((size_t)PHE * 4);
  float* pp_part   = (float*)alloc((size_t)PHE * 4 * 4);

  u16* dchunk0  = (u16*)big1;
  u16* dchunk1  = (u16*)(big1 + 33554432);
  u16* emb_bf   = (u16*)big2;
  u16* h_bf     = (u16*)big2;
  float* d_pp   = (float*)big3;
  float* ctx_f  = (float*)big3;

  if (ws_size < off) { k_sentinel<<<1, 1, 0, stream>>>(out); return; }

  // fused prep: row cvt+sumsq (emb, phe), visit cvt, 3 TILED transposes
  int nprep = (VOC + PHE) + PREP_VIS + PREP_PHT + PREP_W1 + PREP_W2;
  k_prep<<<nprep, 256, 0, stream>>>(emb, emb_bf, r_c, phe, phe_bf, r_p,
                                    visit, visit_bf, pheT_bf, w1, w1T_bf, w2, w2T_bf);

  // DPC pipeline: L0..L4 = gemm(c) || select(c-1); L5 = logits-gemm || select(c4)
  for (int c = 0; c < NCHUNK; ++c) {
    int s = c - 1;
    int nsel = (s >= 0) ? PHE * 2 : 0;
    u16* dw = (c & 1) ? dchunk1 : dchunk0;
    const u16* dr = (s >= 0) ? ((s & 1) ? dchunk1 : dchunk0) : nullptr;
    k_dpc<<<1024 + nsel, 256, 0, stream>>>(
        phe_bf, emb_bf, c, 1024, dw, dr, s, top50c, r_p, r_c);
  }
  k_dpc_log<<<1024 + PHE * 2, 256, 0, stream>>>(
      visit_bf, phe_bf, 1024, probs_bf,
      (NCHUNK - 1) & 1 ? dchunk1 : dchunk0, NCHUNK - 1, top50c);
  k_rsel<2><<<PHE, 256, 0, stream>>>(top50c, NCHUNK * 2 * KC, NCHUNK * 2 * KC, KC, 1, row_sum50);

  // phenotype-phenotype squared distances + smallest-10 stats
  k_gemm2<EPI_DPP, 128, 128, 256, 2, 2><<<dim3(PHE / 128, PHE / 128), 256, 0, stream>>>(
      phe_bf, DIM, phe_bf, DIM, DIM, d_pp, nullptr, PHE, r_p, nullptr, 0);
  k_rsel<8><<<PHE, 256, 0, stream>>>(d_pp, PHE, PHE, KP, 2, pp_part);

  // softmax (in-place bf16 logits) -> ctx
  k_softmax<<<BT, 256, 0, stream>>>(probs_bf, vmask, probs, entropy);
  k_gemm2<EPI_STORE, 64, 128, 256, 2, 2><<<dim3(DIM / 128, BT / 64), 256, 0, stream>>>(
      probs_bf, PHE, pheT_bf, PHE, PHE, ctx_f, nullptr, DIM, nullptr, nullptr, 0);

  // LN1, FFN, LN2
  k_ln<<<BT, 256, 0, stream>>>(visit, ctx_f, ln1g, ln1b, out1_f, out1_bf);
  k_gemm2s<EPI_FFN1><<<dim3(DFFP2 / 128, BT / 128), 256, 0, stream>>>(
      out1_bf, DIM, w1T_bf, DIM, DIM, nullptr, h_bf, DFFP2, nullptr, b1, DFF);
  k_gemm2<EPI_FFN2, 64, 128, 256, 2, 2><<<dim3(DIM / 128, BT / 64), 256, 0, stream>>>(
      h_bf, DFFP2, w2T_bf, DFFP2, DFFP2, ffn_f, nullptr, DIM, nullptr, b2, 0);
  k_ln<<<BT, 256, 0, stream>>>(out1_f, ffn_f, ln2g, ln2b, out2, nullptr);

  // scalars
  k_final<<<1, 256, 0, stream>>>(row_sum50, pp_part, pcd, inv_loss, dist_mean, dist_var);
}

// Round 16
// 563.003 us; speedup vs baseline: 1.0521x; 1.0033x over previous
//
#include <hip/hip_runtime.h>
#include <stdint.h>
#include <stddef.h>

#define BATCH 32
#define TLEN 256
#define DIM 512
#define PHE 2048
#define VOC 40000
#define VOCP 40960
#define DFF 2148
#define DFFP2 2304
#define BT 8192
#define KC 50
#define KP 10
#define CHUNK 8192
#define NCHUNK 5
#define LNEPS 1e-6f
#define BIGF 1e30f

typedef unsigned short u16;
typedef __attribute__((ext_vector_type(8))) short short8;
typedef __attribute__((ext_vector_type(8))) unsigned short ushort8;
typedef __attribute__((ext_vector_type(4))) float floatx4;

__device__ inline u16 f2bf(float f) {
  union { float f; unsigned int u; } v; v.f = f;
  unsigned int u = v.u;
  return (u16)((u + 0x7fffu + ((u >> 16) & 1u)) >> 16);
}
__device__ inline float bf2f(u16 u) {
  union { unsigned int u; float f; } c; c.u = ((unsigned int)u) << 16;
  return c.f;
}

// monotone float<->uint transforms
__device__ inline unsigned int f2mono(float f) {
  union { float f; unsigned int u; } c; c.f = f;
  return (c.u & 0x80000000u) ? ~c.u : (c.u | 0x80000000u);
}
__device__ inline float mono2f(unsigned int u) {
  union { unsigned int u; float f; } c;
  c.u = (u & 0x80000000u) ? (u & 0x7FFFFFFFu) : ~u;
  return c.f;
}
__device__ inline unsigned int mono16(u16 u) {
  return (u & 0x8000u) ? (u16)~u : (u16)(u | 0x8000u);
}
__device__ inline float mono2f16(unsigned int k) {
  unsigned int ub = (k & 0x8000u) ? (k & 0x7FFFu) : ((~k) & 0xFFFFu);
  union { unsigned int u; float f; } c; c.u = ub << 16;
  return c.f;
}

// async global->LDS, 16 bytes per lane; LDS dest is wave-uniform base + lane*16B
__device__ inline void load_lds16(const void* g, void* l) {
  __builtin_amdgcn_global_load_lds(
      (const __attribute__((address_space(1))) unsigned int*)g,
      (__attribute__((address_space(3))) unsigned int*)l, 16, 0, 0);
}

// ---------------- reduction helpers ----------------
__device__ inline float waveRedSum(float v) {
  #pragma unroll
  for (int off = 32; off > 0; off >>= 1) v += __shfl_down(v, off);
  return v;
}
__device__ inline float waveRedMax(float v) {
  #pragma unroll
  for (int off = 32; off > 0; off >>= 1) v = fmaxf(v, __shfl_down(v, off));
  return v;
}
__device__ inline float blockRedSum(float v) {
  __shared__ float sm[8];
  int lane = threadIdx.x & 63, w = threadIdx.x >> 6, nw = blockDim.x >> 6;
  v = waveRedSum(v);
  __syncthreads();
  if (lane == 0) sm[w] = v;
  __syncthreads();
  float r = 0.f;
  for (int i = 0; i < nw; ++i) r += sm[i];
  return r;
}
__device__ inline float blockRedMax(float v) {
  __shared__ float sm2[8];
  int lane = threadIdx.x & 63, w = threadIdx.x >> 6, nw = blockDim.x >> 6;
  v = waveRedMax(v);
  __syncthreads();
  if (lane == 0) sm2[w] = v;
  __syncthreads();
  float r = -BIGF;
  for (int i = 0; i < nw; ++i) r = fmaxf(r, sm2[i]);
  return r;
}
__device__ inline double blockRedSumD(double v) {
  __shared__ double red[256];
  int tid = threadIdx.x;
  __syncthreads();
  red[tid] = v;
  __syncthreads();
  for (int s = 128; s > 0; s >>= 1) {
    if (tid < s) red[tid] += red[tid + s];
    __syncthreads();
  }
  return red[0];
}

// dominance-test histogram add (deterministic integer adds)
__device__ inline void hist_add2(int* hist, int digit, bool pred) {
  int lane = threadIdx.x & 63;
  unsigned long long act = __ballot(pred);
  if (!act) return;
  int src = __ffsll((long long)act) - 1;
  int ld = __shfl(digit, src);
  unsigned long long m = __ballot(pred && digit == ld);
  if (__popcll(m) >= 32) {
    if (lane == src) atomicAdd(&hist[ld], (int)__popcll(m));
    if ((act & ~m) & (1ull << lane)) atomicAdd(&hist[digit], 1);
  } else {
    if (pred) atomicAdd(&hist[digit], 1);
  }
}

// ---------------- small utility kernels ----------------
__global__ void k_sentinel(float* out) { out[0] = -12345.0f; }

// fused prep with LDS-tiled COALESCED transposes.
#define PREP_VIS 2048
#define PREP_PHT 1024
#define PREP_W1  1152
#define PREP_W2  1152
__global__ void __launch_bounds__(256) k_prep(
    const float* __restrict__ emb, u16* __restrict__ emb_bf, float* __restrict__ r_c,
    const float* __restrict__ phe, u16* __restrict__ phe_bf, float* __restrict__ r_p,
    const float* __restrict__ visit, u16* __restrict__ visit_bf,
    u16* __restrict__ pheT_bf,
    const float* __restrict__ w1, u16* __restrict__ w1T_bf,
    const float* __restrict__ w2, u16* __restrict__ w2T_bf)
{
  __shared__ float tile[32][33];
  int bid = (int)blockIdx.x, tid = threadIdx.x;
  if (bid < VOC + PHE) {
    const float* src = (bid < VOC) ? emb + (size_t)bid * DIM
                                   : phe + (size_t)(bid - VOC) * DIM;
    u16* dst = (bid < VOC) ? emb_bf + (size_t)bid * DIM
                           : phe_bf + (size_t)(bid - VOC) * DIM;
    float a = src[tid], b = src[tid + 256];
    dst[tid] = f2bf(a); dst[tid + 256] = f2bf(b);
    float s = blockRedSum(a * a + b * b);
    if (tid == 0) {
      if (bid < VOC) r_c[bid] = s; else r_p[bid - VOC] = s;
    }
    return;
  }
  int b2 = bid - (VOC + PHE);
  int rr = tid >> 5, cc = tid & 31;
  if (b2 < PREP_VIS) {
    int base = b2 * 2048 + tid;
    #pragma unroll
    for (int e = 0; e < 8; ++e) {
      int i = base + e * 256;
      visit_bf[i] = f2bf(visit[i]);
    }
    return;
  }
  b2 -= PREP_VIS;
  if (b2 < PREP_PHT) {
    int i0 = (b2 >> 4) << 5, j0 = (b2 & 15) << 5;
    #pragma unroll
    for (int p = 0; p < 4; ++p)
      tile[p * 8 + rr][cc] = phe[(size_t)(i0 + p * 8 + rr) * DIM + j0 + cc];
    __syncthreads();
    #pragma unroll
    for (int p = 0; p < 4; ++p)
      pheT_bf[(size_t)(j0 + p * 8 + rr) * PHE + i0 + cc] = f2bf(tile[cc][p * 8 + rr]);
    return;
  }
  b2 -= PREP_PHT;
  if (b2 < PREP_W1) {
    int r0 = (b2 >> 4) << 5, c0 = (b2 & 15) << 5;
    #pragma unroll
    for (int p = 0; p < 4; ++p) {
      int i = p * 8 + rr;
      tile[i][cc] = (r0 + cc < DFF) ? w1[(size_t)(c0 + i) * DFF + r0 + cc] : 0.f;
    }
    __syncthreads();
    #pragma unroll
    for (int p = 0; p < 4; ++p) {
      int a = p * 8 + rr;
      w1T_bf[(size_t)(r0 + a) * DIM + c0 + cc] = f2bf(tile[cc][a]);
    }
    return;
  }
  b2 -= PREP_W1;
  {
    int r0 = (b2 / 72) << 5, c0 = (b2 % 72) << 5;
    #pragma unroll
    for (int p = 0; p < 4; ++p) {
      int i = p * 8 + rr;
      tile[i][cc] = (c0 + i < DFF) ? w2[(size_t)(c0 + i) * DIM + r0 + cc] : 0.f;
    }
    __syncthreads();
    #pragma unroll
    for (int p = 0; p < 4; ++p) {
      int a = p * 8 + rr;
      w2T_bf[(size_t)(r0 + a) * DFFP2 + c0 + cc] = f2bf(tile[cc][a]);
    }
    return;
  }
}

#define EPI_STORE 0
#define EPI_DPP   1
#define EPI_FFN1  3
#define EPI_FFN2  4

// XCD-aware bijective block swizzle (m204)
__device__ inline void xcd_block(int BM, int BN, int& m0, int& n0) {
  int nwg = gridDim.x * gridDim.y;
  int orig = blockIdx.y * gridDim.x + blockIdx.x;
  int q = nwg >> 3, r = nwg & 7;
  int xcd = orig & 7, i0 = orig >> 3;
  int wgid = (xcd < r ? xcd * (q + 1) : r * (q + 1) + (xcd - r) * q) + i0;
  m0 = (wgid / gridDim.x) * BM;
  n0 = (wgid % gridDim.x) * BN;
}

template<int EPI>
__device__ inline void epi_write(int rr, int col, float c,
    float* outF, u16* outU, int ldc, const float* rp,
    const float* bias, int nepi) {
  if (EPI == EPI_STORE) {
    outF[(size_t)rr * ldc + col] = c;
  } else if (EPI == EPI_DPP) {
    outF[(size_t)rr * ldc + col] = rp[rr] + rp[col] - 2.f * c;
  } else if (EPI == EPI_FFN1) {
    float h = (col < nepi) ? fmaxf(c + bias[col], 0.f) : 0.f;
    outU[(size_t)rr * ldc + col] = f2bf(h);
  } else if (EPI == EPI_FFN2) {
    outF[(size_t)rr * ldc + col] = c + bias[col];
  }
}

// ---------------- DPC select body (carve-only smem) -----------------------
__device__ __forceinline__ void dpc_select(
    char* smem, int si, const u16* __restrict__ dr, int schunk,
    float* __restrict__ top)
{
  int row = si >> 1, half = si & 1;
  const u16* src = dr + (size_t)row * CHUNK + half * 4096;
  int* hist = (int*)smem;
  int* cum  = hist + 1024;
  int* wred = cum + 256;
  int* selb = wred + 8;
  int tid = threadIdx.x, lane = tid & 63, w4 = tid >> 6;
  int hbase = w4 << 8;

  unsigned int kv[16];
  #pragma unroll
  for (int j2 = 0; j2 < 2; ++j2) {
    ushort8 qv = *(const ushort8*)(src + j2 * 2048 + tid * 8);
    #pragma unroll
    for (int e = 0; e < 8; ++e) kv[j2 * 8 + e] = mono16((u16)qv[e]);
  }

  int hbmin = 255, hbmax = 0;
  #pragma unroll
  for (int j = 0; j < 16; ++j) {
    int hb = (int)(kv[j] >> 8);
    hbmin = min(hbmin, hb); hbmax = max(hbmax, hb);
  }
  #pragma unroll
  for (int off = 32; off > 0; off >>= 1) {
    hbmin = min(hbmin, __shfl_down(hbmin, off));
    hbmax = max(hbmax, __shfl_down(hbmax, off));
  }
  if (lane == 0) { wred[w4] = hbmin; wred[4 + w4] = hbmax; }
  __syncthreads();
  int bmin = min(min(wred[0], wred[1]), min(wred[2], wred[3]));
  int bmax = max(max(wred[4], wred[5]), max(wred[6], wred[7]));
  __syncthreads();

  unsigned int prefix;
  int kk = KC;
  if (bmin == bmax) {
    prefix = (unsigned int)bmin;
  } else {
    hist[tid] = 0; hist[tid + 256] = 0; hist[tid + 512] = 0; hist[tid + 768] = 0;
    __syncthreads();
    #pragma unroll
    for (int j = 0; j < 16; ++j) hist_add2(hist + hbase, (int)(kv[j] >> 8), true);
    __syncthreads();
    int x = hist[tid] + hist[tid + 256] + hist[tid + 512] + hist[tid + 768];
    #pragma unroll
    for (int off = 1; off < 64; off <<= 1) { int y = __shfl_up(x, off); if (lane >= off) x += y; }
    if (lane == 63) wred[w4] = x;
    __syncthreads();
    #pragma unroll
    for (int i = 0; i < 4; ++i) if (i < w4) x += wred[i];
    cum[tid] = x;
    __syncthreads();
    int prev = (tid == 0) ? 0 : cum[tid - 1];
    if (prev < kk && kk <= cum[tid]) { selb[0] = tid; selb[1] = kk - prev; }
    __syncthreads();
    prefix = (unsigned int)selb[0];
    kk = selb[1];
    __syncthreads();
  }

  hist[tid] = 0; hist[tid + 256] = 0; hist[tid + 512] = 0; hist[tid + 768] = 0;
  __syncthreads();
  #pragma unroll
  for (int j = 0; j < 16; ++j)
    hist_add2(hist + hbase, (int)(kv[j] & 255u), (kv[j] >> 8) == prefix);
  __syncthreads();
  int x = hist[tid] + hist[tid + 256] + hist[tid + 512] + hist[tid + 768];
  #pragma unroll
  for (int off = 1; off < 64; off <<= 1) { int y = __shfl_up(x, off); if (lane >= off) x += y; }
  if (lane == 63) wred[w4] = x;
  __syncthreads();
  #pragma unroll
  for (int i = 0; i < 4; ++i) if (i < w4) x += wred[i];
  cum[tid] = x;
  __syncthreads();
  int prev = (tid == 0) ? 0 : cum[tid - 1];
  if (prev < kk && kk <= cum[tid]) { selb[0] = tid; selb[1] = kk - prev; }
  __syncthreads();
  unsigned int key = (prefix << 8) | (unsigned int)selb[0];
  float thr = mono2f16(key);
  float* o50 = top + (size_t)row * (NCHUNK * 2 * KC) + (schunk * 2 + half) * KC;
  __syncthreads();

  int cless = 0;
  #pragma unroll
  for (int j = 0; j < 16; ++j) if (kv[j] < key) cless++;
  int xc = cless;
  #pragma unroll
  for (int off = 1; off < 64; off <<= 1) { int y = __shfl_up(xc, off); if (lane >= off) xc += y; }
  if (lane == 63) wred[w4] = xc;
  __syncthreads();
  #pragma unroll
  for (int i = 0; i < 4; ++i) if (i < w4) xc += wred[i];
  int o = xc - cless;
  #pragma unroll
  for (int j = 0; j < 16; ++j)
    if (kv[j] < key) o50[o++] = mono2f16(kv[j]);
  cum[tid] = xc;
  __syncthreads();
  int total_less = cum[255];
  for (int i = total_less + tid; i < KC; i += 256) o50[i] = thr;
}

// ---------------- fused DPC: GEMM(c) || [dpp-gemm] || select || [dpp-sel] --
// template params give each launch its OWN instantiation (independent
// regalloc, rule #19). All branches use ONLY the 32768B carve.
template<int NDPPG, int NDPPS>
__global__ void __launch_bounds__(256, 2) k_dpc(
    const u16* __restrict__ phe_bf, const u16* __restrict__ emb_bf,
    int gchunk, int ngemm, u16* __restrict__ dw,
    const u16* __restrict__ dr, int schunk, float* __restrict__ top,
    const float* __restrict__ rp, const float* __restrict__ rc, int nsel,
    float* __restrict__ d_pp, float* __restrict__ pp_part)
{
  __shared__ __align__(16) char smem[32768];
  int bid = (int)blockIdx.x;
  int tid = threadIdx.x;
  if (bid < ngemm) {
    u16* As = (u16*)smem;
    u16* Bs = (u16*)(smem + 16384);
    int lane = tid & 63, w = tid >> 6;
    int wm = w >> 1, wn = w & 1;
    int nwg = ngemm, orig = bid;
    int q = nwg >> 3, r = nwg & 7;
    int xcd = orig & 7, i0 = orig >> 3;
    int wgid = (xcd < r ? xcd * (q + 1) : r * (q + 1) + (xcd - r) * q) + i0;
    int m0 = (wgid >> 6) << 7;
    int n0 = (wgid & 63) << 7;
    const u16* Bm = emb_bf + (size_t)gchunk * CHUNK * DIM;
    const float* rcc = rc + gchunk * CHUNK;
    int bvalid = VOC - gchunk * CHUNK; if (bvalid > CHUNK) bvalid = CHUNK;

    floatx4 acc[4][4];
    #pragma unroll
    for (int i = 0; i < 4; ++i)
      #pragma unroll
      for (int j = 0; j < 4; ++j)
        acc[i][j] = (floatx4){0.f, 0.f, 0.f, 0.f};

    int hi = lane >> 4, rsw = lane & 7;
    for (int kt = 0; kt < DIM / 64; ++kt) {
      int k0 = kt * 64;
      #pragma unroll
      for (int p = 0; p < 4; ++p) {
        int c = p * 256 + tid;
        int row = c >> 3;
        int src16 = (c & 7) ^ (row & 7);
        load_lds16(phe_bf + (size_t)(m0 + row) * DIM + k0 + src16 * 8,
                   &As[p * 2048 + w * 512]);
      }
      #pragma unroll
      for (int p = 0; p < 4; ++p) {
        int c = p * 256 + tid;
        int row = c >> 3;
        int src16 = (c & 7) ^ (row & 7);
        load_lds16(Bm + (size_t)(n0 + row) * DIM + k0 + src16 * 8,
                   &Bs[p * 2048 + w * 512]);
      }
      __syncthreads();
      #pragma unroll
      for (int ks = 0; ks < 2; ++ks) {
        int chk = ((ks << 2) | hi) ^ rsw;
        short8 a[4], b[4];
        #pragma unroll
        for (int i = 0; i < 4; ++i)
          a[i] = *(const short8*)&As[(wm * 64 + i * 16 + (lane & 15)) * 64 + chk * 8];
        #pragma unroll
        for (int j = 0; j < 4; ++j)
          b[j] = *(const short8*)&Bs[(wn * 64 + j * 16 + (lane & 15)) * 64 + chk * 8];
        #pragma unroll
        for (int i = 0; i < 4; ++i)
          #pragma unroll
          for (int j = 0; j < 4; ++j)
            acc[i][j] = __builtin_amdgcn_mfma_f32_16x16x32_bf16(a[i], b[j], acc[i][j], 0, 0, 0);
      }
      __syncthreads();
    }
    #pragma unroll
    for (int i = 0; i < 4; ++i) {
      #pragma unroll
      for (int j = 0; j < 4; ++j) {
        floatx4 v = acc[i][j];
        int col = n0 + wn * 64 + j * 16 + (lane & 15);
        int rb = m0 + wm * 64 + i * 16 + ((lane >> 4) << 2);
        #pragma unroll
        for (int qq = 0; qq < 4; ++qq) {
          int rr = rb + qq;
          float d = (col < bvalid) ? sqrtf(fmaxf(rp[rr] + rcc[col] - 2.f * v[qq], 0.f)) : BIGF;
          dw[(size_t)rr * CHUNK + col] = f2bf(d);
        }
      }
    }
    return;
  }
  bid -= ngemm;
  if (NDPPG > 0) {
    if (bid < NDPPG) {
      // dpp gemm: d_pp[m][n] = rp[m]+rp[n]-2*phe[m].phe[n], 128x128 tiles
      u16* As = (u16*)smem;
      u16* Bs = (u16*)(smem + 16384);
      int lane = tid & 63, w = tid >> 6;
      int wm = w >> 1, wn = w & 1;
      int m0 = (bid >> 4) << 7;
      int n0 = (bid & 15) << 7;

      floatx4 acc[4][4];
      #pragma unroll
      for (int i = 0; i < 4; ++i)
        #pragma unroll
        for (int j = 0; j < 4; ++j)
          acc[i][j] = (floatx4){0.f, 0.f, 0.f, 0.f};

      int hi = lane >> 4, rsw = lane & 7;
      for (int kt = 0; kt < DIM / 64; ++kt) {
        int k0 = kt * 64;
        #pragma unroll
        for (int p = 0; p < 4; ++p) {
          int c = p * 256 + tid;
          int row = c >> 3;
          int src16 = (c & 7) ^ (row & 7);
          load_lds16(phe_bf + (size_t)(m0 + row) * DIM + k0 + src16 * 8,
                     &As[p * 2048 + w * 512]);
        }
        #pragma unroll
        for (int p = 0; p < 4; ++p) {
          int c = p * 256 + tid;
          int row = c >> 3;
          int src16 = (c & 7) ^ (row & 7);
          load_lds16(phe_bf + (size_t)(n0 + row) * DIM + k0 + src16 * 8,
                     &Bs[p * 2048 + w * 512]);
        }
        __syncthreads();
        #pragma unroll
        for (int ks = 0; ks < 2; ++ks) {
          int chk = ((ks << 2) | hi) ^ rsw;
          short8 a[4], b[4];
          #pragma unroll
          for (int i = 0; i < 4; ++i)
            a[i] = *(const short8*)&As[(wm * 64 + i * 16 + (lane & 15)) * 64 + chk * 8];
          #pragma unroll
          for (int j = 0; j < 4; ++j)
            b[j] = *(const short8*)&Bs[(wn * 64 + j * 16 + (lane & 15)) * 64 + chk * 8];
          #pragma unroll
          for (int i = 0; i < 4; ++i)
            #pragma unroll
            for (int j = 0; j < 4; ++j)
              acc[i][j] = __builtin_amdgcn_mfma_f32_16x16x32_bf16(a[i], b[j], acc[i][j], 0, 0, 0);
        }
        __syncthreads();
      }
      #pragma unroll
      for (int i = 0; i < 4; ++i) {
        #pragma unroll
        for (int j = 0; j < 4; ++j) {
          floatx4 v = acc[i][j];
          int col = n0 + wn * 64 + j * 16 + (lane & 15);
          int rb = m0 + wm * 64 + i * 16 + ((lane >> 4) << 2);
          #pragma unroll
          for (int qq = 0; qq < 4; ++qq) {
            int rr = rb + qq;
            d_pp[(size_t)rr * PHE + col] = rp[rr] + rp[col] - 2.f * v[qq];
          }
        }
      }
      return;
    }
    bid -= NDPPG;
  }
  if (bid < nsel) {
    if (schunk >= 0) dpc_select(smem, bid, dr, schunk, top);
    return;
  }
  bid -= nsel;
  if (NDPPS > 0) {
    if (bid >= NDPPS) return;
    // dpp select: smallest-10 stats of d_pp row (2048 f32), carve-only smem
    int row = bid;
    const float* src = d_pp + (size_t)row * PHE;
    int* hist = (int*)smem;
    int* cum  = hist + 1024;
    int* wsum = cum + 256;
    int* selb = wsum + 4;
    float* fred = (float*)(selb + 2);   // 12 floats
    int lane = tid & 63, w4 = tid >> 6;
    int hbase = w4 << 8;

    unsigned int v[8];
    #pragma unroll
    for (int j = 0; j < 8; ++j) v[j] = f2mono(src[tid + j * 256]);

    unsigned int prefix = 0, pmask = 0;
    int kk = KP;
    for (int shift = 24; shift >= 0; shift -= 8) {
      hist[tid] = 0; hist[tid + 256] = 0; hist[tid + 512] = 0; hist[tid + 768] = 0;
      __syncthreads();
      #pragma unroll
      for (int j = 0; j < 8; ++j)
        hist_add2(hist + hbase, (int)((v[j] >> shift) & 255), (v[j] & pmask) == prefix);
      __syncthreads();
      int x = hist[tid] + hist[tid + 256] + hist[tid + 512] + hist[tid + 768];
      #pragma unroll
      for (int off = 1; off < 64; off <<= 1) { int y = __shfl_up(x, off); if (lane >= off) x += y; }
      if (lane == 63) wsum[w4] = x;
      __syncthreads();
      #pragma unroll
      for (int i = 0; i < 4; ++i) if (i < w4) x += wsum[i];
      cum[tid] = x;
      __syncthreads();
      int prev = (tid == 0) ? 0 : cum[tid - 1];
      if (prev < kk && kk <= cum[tid]) { selb[0] = tid; selb[1] = kk - prev; }
      __syncthreads();
      prefix |= ((unsigned int)selb[0]) << shift;
      pmask |= 255u << shift;
      kk = selb[1];
      __syncthreads();
    }

    float thr = mono2f(prefix);
    int need = kk;
    float s = 0.f, se = 0.f, sq = 0.f;
    #pragma unroll
    for (int j = 0; j < 8; ++j) {
      if (v[j] < prefix) {
        float f = mono2f(v[j]);
        s += f; se += __expf(-f); sq += f * f;
      }
    }
    s = waveRedSum(s); se = waveRedSum(se); sq = waveRedSum(sq);
    if (lane == 0) { fred[w4] = s; fred[4 + w4] = se; fred[8 + w4] = sq; }
    __syncthreads();
    if (tid == 0) {
      float ts = fred[0] + fred[1] + fred[2] + fred[3];
      float tse = fred[4] + fred[5] + fred[6] + fred[7];
      float tsq = fred[8] + fred[9] + fred[10] + fred[11];
      float fn = (float)need;
      pp_part[(size_t)row * 4] = ts + fn * thr;
      pp_part[(size_t)row * 4 + 1] = tse + fn * __expf(-thr);
      pp_part[(size_t)row * 4 + 2] = tsq + fn * thr * thr;
    }
    return;
  }
}

// ---------------- logits GEMM (bf16 store) || tail select -----------------
__global__ void __launch_bounds__(256, 2) k_dpc_log(
    const u16* __restrict__ visit_bf, const u16* __restrict__ phe_bf,
    int ngemm, u16* __restrict__ logit_bf,
    const u16* __restrict__ dr, int schunk, float* __restrict__ top)
{
  __shared__ __align__(16) char smem[32768];
  int bid = (int)blockIdx.x;
  if (bid < ngemm) {
    u16* As = (u16*)smem;
    u16* Bs = (u16*)(smem + 16384);
    int tid = threadIdx.x, lane = tid & 63, w = tid >> 6;
    int wm = w >> 1, wn = w & 1;
    int nwg = ngemm, orig = bid;
    int q = nwg >> 3, r = nwg & 7;
    int xcd = orig & 7, i0 = orig >> 3;
    int wgid = (xcd < r ? xcd * (q + 1) : r * (q + 1) + (xcd - r) * q) + i0;
    int m0 = (wgid >> 4) << 7;        // gridx = PHE/128 = 16
    int n0 = (wgid & 15) << 7;

    floatx4 acc[4][4];
    #pragma unroll
    for (int i = 0; i < 4; ++i)
      #pragma unroll
      for (int j = 0; j < 4; ++j)
        acc[i][j] = (floatx4){0.f, 0.f, 0.f, 0.f};

    int hi = lane >> 4, rsw = lane & 7;
    for (int kt = 0; kt < DIM / 64; ++kt) {
      int k0 = kt * 64;
      #pragma unroll
      for (int p = 0; p < 4; ++p) {
        int c = p * 256 + tid;
        int row = c >> 3;
        int src16 = (c & 7) ^ (row & 7);
        load_lds16(visit_bf + (size_t)(m0 + row) * DIM + k0 + src16 * 8,
                   &As[p * 2048 + w * 512]);
      }
      #pragma unroll
      for (int p = 0; p < 4; ++p) {
        int c = p * 256 + tid;
        int row = c >> 3;
        int src16 = (c & 7) ^ (row & 7);
        load_lds16(phe_bf + (size_t)(n0 + row) * DIM + k0 + src16 * 8,
                   &Bs[p * 2048 + w * 512]);
      }
      __syncthreads();
      #pragma unroll
      for (int ks = 0; ks < 2; ++ks) {
        int chk = ((ks << 2) | hi) ^ rsw;
        short8 a[4], b[4];
        #pragma unroll
        for (int i = 0; i < 4; ++i)
          a[i] = *(const short8*)&As[(wm * 64 + i * 16 + (lane & 15)) * 64 + chk * 8];
        #pragma unroll
        for (int j = 0; j < 4; ++j)
          b[j] = *(const short8*)&Bs[(wn * 64 + j * 16 + (lane & 15)) * 64 + chk * 8];
        #pragma unroll
        for (int i = 0; i < 4; ++i)
          #pragma unroll
          for (int j = 0; j < 4; ++j)
            acc[i][j] = __builtin_amdgcn_mfma_f32_16x16x32_bf16(a[i], b[j], acc[i][j], 0, 0, 0);
      }
      __syncthreads();
    }
    #pragma unroll
    for (int i = 0; i < 4; ++i) {
      #pragma unroll
      for (int j = 0; j < 4; ++j) {
        floatx4 v = acc[i][j];
        int col = n0 + wn * 64 + j * 16 + (lane & 15);
        int rb = m0 + wm * 64 + i * 16 + ((lane >> 4) << 2);
        #pragma unroll
        for (int qq = 0; qq < 4; ++qq)
          logit_bf[(size_t)(rb + qq) * PHE + col] = f2bf(v[qq]);
      }
    }
  } else {
    if (schunk < 0) return;
    dpc_select(smem, bid - ngemm, dr, schunk, top);
  }
}

// ---------------- GEMM (NT), 2-phase double-buffered, BK=64 ----------------
template<int EPI, int BM, int BN, int NTH, int WR, int WC>
__global__ void __launch_bounds__(NTH, 2) k_gemm2(
    const u16* __restrict__ A, int lda,
    const u16* __restrict__ Bm, int ldb, int K,
    float* __restrict__ outF, u16* __restrict__ outU, int ldc,
    const float* __restrict__ rp, const float* __restrict__ bias, int nepi)
{
  constexpr int BK = 64;
  constexpr int MR = BM / WR / 16;
  constexpr int NR = BN / WC / 16;
  constexpr int LD_A = BM * BK / (NTH * 8);
  constexpr int LD_B = BN * BK / (NTH * 8);
  __shared__ __align__(16) u16 As[2][BM * BK];
  __shared__ __align__(16) u16 Bs[2][BN * BK];
  int tid = threadIdx.x, lane = tid & 63, w = tid >> 6;
  int wm = w / WC, wn = w % WC;
  int m0, n0;
  xcd_block(BM, BN, m0, n0);

  floatx4 acc[MR][NR];
  #pragma unroll
  for (int i = 0; i < MR; ++i)
    #pragma unroll
    for (int j = 0; j < NR; ++j)
      acc[i][j] = (floatx4){0.f, 0.f, 0.f, 0.f};

  auto stage = [&](int buf, int k0) {
    #pragma unroll
    for (int p = 0; p < LD_A; ++p) {
      int c = p * NTH + tid;
      int row = c >> 3;
      int src16 = (c & 7) ^ (row & 7);
      load_lds16(A + (size_t)(m0 + row) * lda + k0 + src16 * 8,
                 &As[buf][p * NTH * 8 + w * 512]);
    }
    #pragma unroll
    for (int p = 0; p < LD_B; ++p) {
      int c = p * NTH + tid;
      int row = c >> 3;
      int src16 = (c & 7) ^ (row & 7);
      load_lds16(Bm + (size_t)(n0 + row) * ldb + k0 + src16 * 8,
                 &Bs[buf][p * NTH * 8 + w * 512]);
    }
  };

  int nt = K / BK;
  stage(0, 0);
  __syncthreads();
  int cur = 0;
  int hi = lane >> 4;
  int rsw = lane & 7;
  for (int kt = 0; kt < nt; ++kt) {
    if (kt + 1 < nt) stage(cur ^ 1, (kt + 1) * BK);
    #pragma unroll
    for (int ks = 0; ks < 2; ++ks) {
      int chk = ((ks << 2) | hi) ^ rsw;
      short8 a[MR], b[NR];
      #pragma unroll
      for (int i = 0; i < MR; ++i)
        a[i] = *(const short8*)&As[cur][(wm * (BM / WR) + i * 16 + (lane & 15)) * BK + chk * 8];
      #pragma unroll
      for (int j = 0; j < NR; ++j)
        b[j] = *(const short8*)&Bs[cur][(wn * (BN / WC) + j * 16 + (lane & 15)) * BK + chk * 8];
      #pragma unroll
      for (int i = 0; i < MR; ++i)
        #pragma unroll
        for (int j = 0; j < NR; ++j)
          acc[i][j] = __builtin_amdgcn_mfma_f32_16x16x32_bf16(a[i], b[j], acc[i][j], 0, 0, 0);
    }
    __syncthreads();
    cur ^= 1;
  }

  #pragma unroll
  for (int i = 0; i < MR; ++i) {
    #pragma unroll
    for (int j = 0; j < NR; ++j) {
      floatx4 v = acc[i][j];
      int col = n0 + wn * (BN / WC) + j * 16 + (lane & 15);
      int rb = m0 + wm * (BM / WR) + i * 16 + ((lane >> 4) << 2);
      #pragma unroll
      for (int qq = 0; qq < 4; ++qq)
        epi_write<EPI>(rb + qq, col, v[qq], outF, outU, ldc, rp, bias, nepi);
    }
  }
}

// ---------------- GEMM (NT), single-buffer, 128x128, 4 blocks/CU -----------
template<int EPI>
__global__ void __launch_bounds__(256, 4) k_gemm2s(
    const u16* __restrict__ A, int lda,
    const u16* __restrict__ Bm, int ldb, int K,
    float* __restrict__ outF, u16* __restrict__ outU, int ldc,
    const float* __restrict__ rp, const float* __restrict__ bias, int nepi)
{
  constexpr int BM = 128, BN = 128, BK = 64, NTH = 256;
  constexpr int MR = 4, NR = 4;
  __shared__ __align__(16) u16 As[BM * BK];
  __shared__ __align__(16) u16 Bs[BN * BK];
  int tid = threadIdx.x, lane = tid & 63, w = tid >> 6;
  int wm = w >> 1, wn = w & 1;
  int m0, n0;
  xcd_block(BM, BN, m0, n0);

  floatx4 acc[MR][NR];
  #pragma unroll
  for (int i = 0; i < MR; ++i)
    #pragma unroll
    for (int j = 0; j < NR; ++j)
      acc[i][j] = (floatx4){0.f, 0.f, 0.f, 0.f};

  int hi = lane >> 4;
  int rsw = lane & 7;
  int nt = K / BK;
  for (int kt = 0; kt < nt; ++kt) {
    int k0 = kt * BK;
    #pragma unroll
    for (int p = 0; p < 4; ++p) {
      int c = p * NTH + tid;
      int row = c >> 3;
      int src16 = (c & 7) ^ (row & 7);
      load_lds16(A + (size_t)(m0 + row) * lda + k0 + src16 * 8,
                 &As[p * NTH * 8 + w * 512]);
    }
    #pragma unroll
    for (int p = 0; p < 4; ++p) {
      int c = p * NTH + tid;
      int row = c >> 3;
      int src16 = (c & 7) ^ (row & 7);
      load_lds16(Bm + (size_t)(n0 + row) * ldb + k0 + src16 * 8,
                 &Bs[p * NTH * 8 + w * 512]);
    }
    __syncthreads();
    #pragma unroll
    for (int ks = 0; ks < 2; ++ks) {
      int chk = ((ks << 2) | hi) ^ rsw;
      short8 a[MR], b[NR];
      #pragma unroll
      for (int i = 0; i < MR; ++i)
        a[i] = *(const short8*)&As[(wm * 64 + i * 16 + (lane & 15)) * BK + chk * 8];
      #pragma unroll
      for (int j = 0; j < NR; ++j)
        b[j] = *(const short8*)&Bs[(wn * 64 + j * 16 + (lane & 15)) * BK + chk * 8];
      #pragma unroll
      for (int i = 0; i < MR; ++i)
        #pragma unroll
        for (int j = 0; j < NR; ++j)
          acc[i][j] = __builtin_amdgcn_mfma_f32_16x16x32_bf16(a[i], b[j], acc[i][j], 0, 0, 0);
    }
    __syncthreads();
  }

  #pragma unroll
  for (int i = 0; i < MR; ++i) {
    #pragma unroll
    for (int j = 0; j < NR; ++j) {
      floatx4 v = acc[i][j];
      int col = n0 + wn * 64 + j * 16 + (lane & 15);
      int rb = m0 + wm * 64 + i * 16 + ((lane >> 4) << 2);
      #pragma unroll
      for (int qq = 0; qq < 4; ++qq)
        epi_write<EPI>(rb + qq, col, v[qq], outF, outU, ldc, rp, bias, nepi);
    }
  }
}

// ---------------- softmax + entropy (bf16 logits in-place) ----------------
__global__ void __launch_bounds__(256) k_softmax(
    u16* __restrict__ probs_bf, const int* __restrict__ mask,
    float* __restrict__ probs, float* __restrict__ entropy)
{
  int row = blockIdx.x;
  int tid = threadIdx.x;
  u16* pb = probs_bf + (size_t)row * PHE;
  float* pp = probs + (size_t)row * PHE;
  if (mask[row] != 0) {
    const float u = 1.0f / (float)PHE;
    const u16 ub = f2bf(u);
    for (int i = tid; i < PHE; i += 256) { pp[i] = u; pb[i] = ub; }
    if (tid == 0) entropy[row] = 0.f;
    return;
  }
  float l[8];
  float mx = -BIGF;
  #pragma unroll
  for (int j = 0; j < 8; ++j) { l[j] = bf2f(pb[tid + j * 256]); mx = fmaxf(mx, l[j]); }
  mx = blockRedMax(mx);
  float s = 0.f;
  #pragma unroll
  for (int j = 0; j < 8; ++j) { l[j] = __expf(l[j] - mx); s += l[j]; }
  s = blockRedSum(s);
  float inv = 1.0f / s;
  float ent = 0.f;
  #pragma unroll
  for (int j = 0; j < 8; ++j) {
    float p = l[j] * inv;
    pp[tid + j * 256] = p;
    pb[tid + j * 256] = f2bf(p);
    ent += p * __logf(p);
  }
  ent = blockRedSum(ent);
  if (tid == 0) entropy[row] = -ent;
}

// ---------------- add + layernorm ----------------
__global__ void __launch_bounds__(256) k_ln(
    const float* __restrict__ xa, const float* __restrict__ xb,
    const float* __restrict__ g, const float* __restrict__ bb,
    float* __restrict__ outF, u16* __restrict__ outBf)
{
  int row = blockIdx.x;
  int tid = threadIdx.x;
  const float* pa = xa + (size_t)row * DIM;
  const float* pb = xb + (size_t)row * DIM;
  float x0 = pa[tid] + pb[tid];
  float x1 = pa[tid + 256] + pb[tid + 256];
  float mu = blockRedSum(x0 + x1) * (1.0f / DIM);
  float d0 = x0 - mu, d1 = x1 - mu;
  float var = blockRedSum(d0 * d0 + d1 * d1) * (1.0f / DIM);
  float rs = 1.0f / sqrtf(var + LNEPS);
  float y0 = d0 * rs * g[tid] + bb[tid];
  float y1 = d1 * rs * g[tid + 256] + bb[tid + 256];
  if (outF) {
    outF[(size_t)row * DIM + tid] = y0;
    outF[(size_t)row * DIM + tid + 256] = y1;
  }
  if (outBf) {
    outBf[(size_t)row * DIM + tid] = f2bf(y0);
    outBf[(size_t)row * DIM + tid + 256] = f2bf(y1);
  }
}

// ---------------- radix smallest-k per row, f32 keys (merge) ---------------
template<int NPER>
__global__ void __launch_bounds__(256) k_rsel(
    const float* __restrict__ in, int ldin, int ncols, int k, int mode,
    float* __restrict__ out)
{
  __shared__ int hist[1024];
  __shared__ int cum[256];
  __shared__ int wsum[4];
  __shared__ int sel_bucket, sel_rank;
  int row = blockIdx.x;
  int tid = threadIdx.x;
  int lane = tid & 63, w = tid >> 6;
  int hbase = w << 8;
  const float* src = in + (size_t)row * ldin;

  unsigned int v[NPER];
  #pragma unroll
  for (int j = 0; j < NPER; ++j) {
    int idx = tid + j * 256;
    v[j] = (idx < ncols) ? f2mono(src[idx]) : 0xFFFFFFFFu;
  }

  unsigned int prefix = 0, pmask = 0;
  int kk = k;
  for (int shift = 24; shift >= 0; shift -= 8) {
    hist[tid] = 0; hist[tid + 256] = 0; hist[tid + 512] = 0; hist[tid + 768] = 0;
    __syncthreads();
    #pragma unroll
    for (int j = 0; j < NPER; ++j)
      hist_add2(hist + hbase, (int)((v[j] >> shift) & 255), (v[j] & pmask) == prefix);
    __syncthreads();
    int x = hist[tid] + hist[tid + 256] + hist[tid + 512] + hist[tid + 768];
    #pragma unroll
    for (int off = 1; off < 64; off <<= 1) {
      int y = __shfl_up(x, off);
      if (lane >= off) x += y;
    }
    if (lane == 63) wsum[w] = x;
    __syncthreads();
    #pragma unroll
    for (int i = 0; i < 4; ++i) if (i < w) x += wsum[i];
    cum[tid] = x;
    __syncthreads();
    int prev = (tid == 0) ? 0 : cum[tid - 1];
    if (prev < kk && kk <= cum[tid]) { sel_bucket = tid; sel_rank = kk - prev; }
    __syncthreads();
    prefix |= ((unsigned int)sel_bucket) << shift;
    pmask |= 255u << shift;
    kk = sel_rank;
    __syncthreads();
  }

  float thr = mono2f(prefix);
  int need = kk;

  float s = 0.f, se = 0.f, sq = 0.f;
  #pragma unroll
  for (int j = 0; j < NPER; ++j) {
    if (v[j] < prefix) {
      float f = mono2f(v[j]);
      s += f; se += __expf(-f); sq += f * f;
    }
  }
  float ts = blockRedSum(s);
  float tse = blockRedSum(se);
  float tsq = blockRedSum(sq);
  if (tid == 0) {
    float fn = (float)need;
    ts += fn * thr;
    if (mode == 1) {
      out[row] = ts;
    } else {
      tse += fn * __expf(-thr);
      tsq += fn * thr * thr;
      out[(size_t)row * 4] = ts;
      out[(size_t)row * 4 + 1] = tse;
      out[(size_t)row * 4 + 2] = tsq;
    }
  }
}

// ---------------- final scalar reductions ----------------
__global__ void __launch_bounds__(256) k_final(
    const float* __restrict__ row_sum50, const float* __restrict__ pp_part,
    float* __restrict__ out_pcd, float* __restrict__ out_inv,
    float* __restrict__ out_mean, float* __restrict__ out_var)
{
  int tid = threadIdx.x;
  double s50 = 0, sn = 0, se = 0, sq = 0;
  for (int i = tid; i < PHE; i += 256) {
    s50 += (double)row_sum50[i];
    sn += (double)pp_part[(size_t)i * 4];
    se += (double)pp_part[(size_t)i * 4 + 1];
    sq += (double)pp_part[(size_t)i * 4 + 2];
  }
  s50 = blockRedSumD(s50);
  sn = blockRedSumD(sn);
  se = blockRedSumD(se);
  sq = blockRedSumD(sq);
  if (tid == 0) {
    *out_pcd = (float)(s50 / (double)(PHE * KC));
    double mean = sn / (double)(PHE * KP);
    *out_inv = (float)(se / (double)(PHE * KP));
    *out_mean = (float)mean;
    *out_var = (float)(sq / (double)(PHE * KP) - mean * mean);
  }
}

// ---------------- host ----------------
extern "C" void kernel_launch(void* const* d_in, const int* in_sizes, int n_in,
                              void* d_out, int out_size, void* d_ws, size_t ws_size,
                              hipStream_t stream)
{
  const float* visit = (const float*)d_in[0];
  const int*   vmask = (const int*)d_in[1];
  const float* emb   = (const float*)d_in[2];
  const float* phe   = (const float*)d_in[3];
  const float* w1    = (const float*)d_in[4];
  const float* b1    = (const float*)d_in[5];
  const float* w2    = (const float*)d_in[6];
  const float* b2    = (const float*)d_in[7];
  const float* ln1g  = (const float*)d_in[8];
  const float* ln1b  = (const float*)d_in[9];
  const float* ln2g  = (const float*)d_in[10];
  const float* ln2b  = (const float*)d_in[11];

  float* out = (float*)d_out;
  float* out2      = out;
  float* probs     = out + (size_t)BT * DIM;
  float* pcd       = probs + (size_t)BT * PHE;
  float* entropy   = pcd + 1;
  float* inv_loss  = entropy + BT;
  float* dist_mean = inv_loss + 1;
  float* dist_var  = dist_mean + 1;

  char* wsb = (char*)d_ws;
  size_t off = 0;
  auto alloc = [&](size_t bytes) -> char* {
    char* p = wsb + off;
    off = (off + bytes + 255) & ~(size_t)255;
    return p;
  };
  u16* phe_bf   = (u16*)alloc((size_t)PHE * DIM * 2);
  u16* pheT_bf  = (u16*)alloc((size_t)DIM * PHE * 2);
  u16* visit_bf = (u16*)alloc((size_t)BT * DIM * 2);
  u16* w1T_bf   = (u16*)alloc((size_t)DFFP2 * DIM * 2);
  u16* w2T_bf   = (u16*)alloc((size_t)DIM * DFFP2 * 2);
  float* r_p    = (float*)alloc((size_t)PHE * 4);
  float* r_c    = (float*)alloc((size_t)VOC * 4);
  char* big1    = alloc((size_t)67108864);            // 2x bf16 d-chunk ping-pong
  char* big2    = alloc((size_t)VOCP * DIM * 2);      // emb_bf padded -> h_bf [BT][DFFP2]
  float* top50c = (float*)alloc((size_t)PHE * NCHUNK * 2 * KC * 4);
  char* big3    = alloc((size_t)PHE * PHE * 4);       // d_pp f32 -> ctx_f [BT][DIM]
  u16* probs_bf = (u16*)alloc((size_t)BT * PHE * 2);  // logits bf16 -> probs (in-place)
  float* out1_f = (float*)alloc((size_t)BT * DIM * 4);
  u16* out1_bf  = (u16*)alloc((size_t)BT * DIM * 2);
  float* ffn_f  = (float*)alloc((size_t)BT * DIM * 4);
  float* row_sum50 = (float*)alloc((size_t)PHE * 4);
  float* pp_part   = (float*)alloc((size_t)PHE * 4 * 4);

  u16* dchunk0  = (u16*)big1;
  u16* dchunk1  = (u16*)(big1 + 33554432);
  u16* emb_bf   = (u16*)big2;
  u16* h_bf     = (u16*)big2;
  float* d_pp   = (float*)big3;
  float* ctx_f  = (float*)big3;

  if (ws_size < off) { k_sentinel<<<1, 1, 0, stream>>>(out); return; }

  // fused prep: row cvt+sumsq (emb, phe), visit cvt, 3 TILED transposes
  int nprep = (VOC + PHE) + PREP_VIS + PREP_PHT + PREP_W1 + PREP_W2;
  k_prep<<<nprep, 256, 0, stream>>>(emb, emb_bf, r_c, phe, phe_bf, r_p,
                                    visit, visit_bf, pheT_bf, w1, w1T_bf, w2, w2T_bf);

  // DPC pipeline with absorbed dpp:
  // L0 = dpc c0 + dpp-gemm(256)        [1280 blocks = 5/CU, fully resident]
  // L1 = dpc c1 + sel c0 + dpp-sel(2048)
  // L2..L4 = dpc c + sel c-1
  // L5 = logits-gemm + sel c4
  k_dpc<256, 0><<<1024 + 256, 256, 0, stream>>>(
      phe_bf, emb_bf, 0, 1024, dchunk0, nullptr, -1, top50c, r_p, r_c, 0,
      d_pp, pp_part);
  k_dpc<0, 2048><<<1024 + 4096 + 2048, 256, 0, stream>>>(
      phe_bf, emb_bf, 1, 1024, dchunk1, dchunk0, 0, top50c, r_p, r_c, 4096,
      d_pp, pp_part);
  for (int c = 2; c < NCHUNK; ++c) {
    int s = c - 1;
    u16* dw = (c & 1) ? dchunk1 : dchunk0;
    const u16* dr = (s & 1) ? dchunk1 : dchunk0;
    k_dpc<0, 0><<<1024 + 4096, 256, 0, stream>>>(
        phe_bf, emb_bf, c, 1024, dw, dr, s, top50c, r_p, r_c, 4096,
        d_pp, pp_part);
  }
  k_dpc_log<<<1024 + PHE * 2, 256, 0, stream>>>(
      visit_bf, phe_bf, 1024, probs_bf,
      (NCHUNK - 1) & 1 ? dchunk1 : dchunk0, NCHUNK - 1, top50c);
  k_rsel<2><<<PHE, 256, 0, stream>>>(top50c, NCHUNK * 2 * KC, NCHUNK * 2 * KC, KC, 1, row_sum50);

  // softmax (in-place bf16 logits) -> ctx
  k_softmax<<<BT, 256, 0, stream>>>(probs_bf, vmask, probs, entropy);
  k_gemm2<EPI_STORE, 64, 128, 256, 2, 2><<<dim3(DIM / 128, BT / 64), 256, 0, stream>>>(
      probs_bf, PHE, pheT_bf, PHE, PHE, ctx_f, nullptr, DIM, nullptr, nullptr, 0);

  // LN1, FFN, LN2
  k_ln<<<BT, 256, 0, stream>>>(visit, ctx_f, ln1g, ln1b, out1_f, out1_bf);
  k_gemm2s<EPI_FFN1><<<dim3(DFFP2 / 128, BT / 128), 256, 0, stream>>>(
      out1_bf, DIM, w1T_bf, DIM, DIM, nullptr, h_bf, DFFP2, nullptr, b1, DFF);
  k_gemm2<EPI_FFN2, 64, 128, 256, 2, 2><<<dim3(DIM / 128, BT / 64), 256, 0, stream>>>(
      h_bf, DFFP2, w2T_bf, DFFP2, DFFP2, ffn_f, nullptr, DIM, nullptr, b2, 0);
  k_ln<<<BT, 256, 0, stream>>>(out1_f, ffn_f, ln2g, ln2b, out2, nullptr);

  // scalars
  k_final<<<1, 256, 0, stream>>>(row_sum50, pp_part, pcd, inv_loss, dist_mean, dist_var);
}

// Round 17
// 559.693 us; speedup vs baseline: 1.0583x; 1.0059x over previous
//
#include <hip/hip_runtime.h>
#include <stdint.h>
#include <stddef.h>

#define BATCH 32
#define TLEN 256
#define DIM 512
#define PHE 2048
#define VOC 40000
#define VOCP 40960
#define DFF 2148
#define DFFP2 2304
#define BT 8192
#define KC 50
#define KP 10
#define CHUNK 8192
#define NCHUNK 5
#define LNEPS 1e-6f
#define BIGF 1e30f

typedef unsigned short u16;
typedef __attribute__((ext_vector_type(8))) short short8;
typedef __attribute__((ext_vector_type(8))) unsigned short ushort8;
typedef __attribute__((ext_vector_type(4))) float floatx4;

__device__ inline u16 f2bf(float f) {
  union { float f; unsigned int u; } v; v.f = f;
  unsigned int u = v.u;
  return (u16)((u + 0x7fffu + ((u >> 16) & 1u)) >> 16);
}
__device__ inline float bf2f(u16 u) {
  union { unsigned int u; float f; } c; c.u = ((unsigned int)u) << 16;
  return c.f;
}

// monotone float<->uint transforms
__device__ inline unsigned int f2mono(float f) {
  union { float f; unsigned int u; } c; c.f = f;
  return (c.u & 0x80000000u) ? ~c.u : (c.u | 0x80000000u);
}
__device__ inline float mono2f(unsigned int u) {
  union { unsigned int u; float f; } c;
  c.u = (u & 0x80000000u) ? (u & 0x7FFFFFFFu) : ~u;
  return c.f;
}
__device__ inline unsigned int mono16(u16 u) {
  return (u & 0x8000u) ? (u16)~u : (u16)(u | 0x8000u);
}
__device__ inline float mono2f16(unsigned int k) {
  unsigned int ub = (k & 0x8000u) ? (k & 0x7FFFu) : ((~k) & 0xFFFFu);
  union { unsigned int u; float f; } c; c.u = ub << 16;
  return c.f;
}

// async global->LDS, 16 bytes per lane; LDS dest is wave-uniform base + lane*16B
__device__ inline void load_lds16(const void* g, void* l) {
  __builtin_amdgcn_global_load_lds(
      (const __attribute__((address_space(1))) unsigned int*)g,
      (__attribute__((address_space(3))) unsigned int*)l, 16, 0, 0);
}

// ---------------- reduction helpers ----------------
__device__ inline float waveRedSum(float v) {
  #pragma unroll
  for (int off = 32; off > 0; off >>= 1) v += __shfl_down(v, off);
  return v;
}
__device__ inline float waveRedMax(float v) {
  #pragma unroll
  for (int off = 32; off > 0; off >>= 1) v = fmaxf(v, __shfl_down(v, off));
  return v;
}
__device__ inline float blockRedSum(float v) {
  __shared__ float sm[8];
  int lane = threadIdx.x & 63, w = threadIdx.x >> 6, nw = blockDim.x >> 6;
  v = waveRedSum(v);
  __syncthreads();
  if (lane == 0) sm[w] = v;
  __syncthreads();
  float r = 0.f;
  for (int i = 0; i < nw; ++i) r += sm[i];
  return r;
}
__device__ inline float blockRedMax(float v) {
  __shared__ float sm2[8];
  int lane = threadIdx.x & 63, w = threadIdx.x >> 6, nw = blockDim.x >> 6;
  v = waveRedMax(v);
  __syncthreads();
  if (lane == 0) sm2[w] = v;
  __syncthreads();
  float r = -BIGF;
  for (int i = 0; i < nw; ++i) r = fmaxf(r, sm2[i]);
  return r;
}
__device__ inline double blockRedSumD(double v) {
  __shared__ double red[256];
  int tid = threadIdx.x;
  __syncthreads();
  red[tid] = v;
  __syncthreads();
  for (int s = 128; s > 0; s >>= 1) {
    if (tid < s) red[tid] += red[tid + s];
    __syncthreads();
  }
  return red[0];
}

// dominance-test histogram add (deterministic integer adds)
__device__ inline void hist_add2(int* hist, int digit, bool pred) {
  int lane = threadIdx.x & 63;
  unsigned long long act = __ballot(pred);
  if (!act) return;
  int src = __ffsll((long long)act) - 1;
  int ld = __shfl(digit, src);
  unsigned long long m = __ballot(pred && digit == ld);
  if (__popcll(m) >= 32) {
    if (lane == src) atomicAdd(&hist[ld], (int)__popcll(m));
    if ((act & ~m) & (1ull << lane)) atomicAdd(&hist[digit], 1);
  } else {
    if (pred) atomicAdd(&hist[digit], 1);
  }
}

// ---------------- small utility kernels ----------------
__global__ void k_sentinel(float* out) { out[0] = -12345.0f; }

// fused prep with LDS-tiled COALESCED transposes.
#define PREP_VIS 2048
#define PREP_PHT 1024
#define PREP_W1  1152
#define PREP_W2  1152
__global__ void __launch_bounds__(256) k_prep(
    const float* __restrict__ emb, u16* __restrict__ emb_bf, float* __restrict__ r_c,
    const float* __restrict__ phe, u16* __restrict__ phe_bf, float* __restrict__ r_p,
    const float* __restrict__ visit, u16* __restrict__ visit_bf,
    u16* __restrict__ pheT_bf,
    const float* __restrict__ w1, u16* __restrict__ w1T_bf,
    const float* __restrict__ w2, u16* __restrict__ w2T_bf)
{
  __shared__ float tile[32][33];
  int bid = (int)blockIdx.x, tid = threadIdx.x;
  if (bid < VOC + PHE) {
    const float* src = (bid < VOC) ? emb + (size_t)bid * DIM
                                   : phe + (size_t)(bid - VOC) * DIM;
    u16* dst = (bid < VOC) ? emb_bf + (size_t)bid * DIM
                           : phe_bf + (size_t)(bid - VOC) * DIM;
    float a = src[tid], b = src[tid + 256];
    dst[tid] = f2bf(a); dst[tid + 256] = f2bf(b);
    float s = blockRedSum(a * a + b * b);
    if (tid == 0) {
      if (bid < VOC) r_c[bid] = s; else r_p[bid - VOC] = s;
    }
    return;
  }
  int b2 = bid - (VOC + PHE);
  int rr = tid >> 5, cc = tid & 31;
  if (b2 < PREP_VIS) {
    int base = b2 * 2048 + tid;
    #pragma unroll
    for (int e = 0; e < 8; ++e) {
      int i = base + e * 256;
      visit_bf[i] = f2bf(visit[i]);
    }
    return;
  }
  b2 -= PREP_VIS;
  if (b2 < PREP_PHT) {
    int i0 = (b2 >> 4) << 5, j0 = (b2 & 15) << 5;
    #pragma unroll
    for (int p = 0; p < 4; ++p)
      tile[p * 8 + rr][cc] = phe[(size_t)(i0 + p * 8 + rr) * DIM + j0 + cc];
    __syncthreads();
    #pragma unroll
    for (int p = 0; p < 4; ++p)
      pheT_bf[(size_t)(j0 + p * 8 + rr) * PHE + i0 + cc] = f2bf(tile[cc][p * 8 + rr]);
    return;
  }
  b2 -= PREP_PHT;
  if (b2 < PREP_W1) {
    int r0 = (b2 >> 4) << 5, c0 = (b2 & 15) << 5;
    #pragma unroll
    for (int p = 0; p < 4; ++p) {
      int i = p * 8 + rr;
      tile[i][cc] = (r0 + cc < DFF) ? w1[(size_t)(c0 + i) * DFF + r0 + cc] : 0.f;
    }
    __syncthreads();
    #pragma unroll
    for (int p = 0; p < 4; ++p) {
      int a = p * 8 + rr;
      w1T_bf[(size_t)(r0 + a) * DIM + c0 + cc] = f2bf(tile[cc][a]);
    }
    return;
  }
  b2 -= PREP_W1;
  {
    int r0 = (b2 / 72) << 5, c0 = (b2 % 72) << 5;
    #pragma unroll
    for (int p = 0; p < 4; ++p) {
      int i = p * 8 + rr;
      tile[i][cc] = (c0 + i < DFF) ? w2[(size_t)(c0 + i) * DIM + r0 + cc] : 0.f;
    }
    __syncthreads();
    #pragma unroll
    for (int p = 0; p < 4; ++p) {
      int a = p * 8 + rr;
      w2T_bf[(size_t)(r0 + a) * DFFP2 + c0 + cc] = f2bf(tile[cc][a]);
    }
    return;
  }
}

#define EPI_STORE 0
#define EPI_DPP   1
#define EPI_FFN1  3
#define EPI_FFN2  4

// XCD-aware bijective block swizzle (m204)
__device__ inline void xcd_block(int BM, int BN, int& m0, int& n0) {
  int nwg = gridDim.x * gridDim.y;
  int orig = blockIdx.y * gridDim.x + blockIdx.x;
  int q = nwg >> 3, r = nwg & 7;
  int xcd = orig & 7, i0 = orig >> 3;
  int wgid = (xcd < r ? xcd * (q + 1) : r * (q + 1) + (xcd - r) * q) + i0;
  m0 = (wgid / gridDim.x) * BM;
  n0 = (wgid % gridDim.x) * BN;
}

template<int EPI>
__device__ inline void epi_write(int rr, int col, float c,
    float* outF, u16* outU, int ldc, const float* rp,
    const float* bias, int nepi) {
  if (EPI == EPI_STORE) {
    outF[(size_t)rr * ldc + col] = c;
  } else if (EPI == EPI_DPP) {
    outF[(size_t)rr * ldc + col] = rp[rr] + rp[col] - 2.f * c;
  } else if (EPI == EPI_FFN1) {
    float h = (col < nepi) ? fmaxf(c + bias[col], 0.f) : 0.f;
    outU[(size_t)rr * ldc + col] = f2bf(h);
  } else if (EPI == EPI_FFN2) {
    outF[(size_t)rr * ldc + col] = c + bias[col];
  }
}

// ---------------- DPC select body (carve-only smem) -----------------------
__device__ __forceinline__ void dpc_select(
    char* smem, int si, const u16* __restrict__ dr, int schunk,
    float* __restrict__ top)
{
  int row = si >> 1, half = si & 1;
  const u16* src = dr + (size_t)row * CHUNK + half * 4096;
  int* hist = (int*)smem;
  int* cum  = hist + 1024;
  int* wred = cum + 256;
  int* selb = wred + 8;
  int tid = threadIdx.x, lane = tid & 63, w4 = tid >> 6;
  int hbase = w4 << 8;

  unsigned int kv[16];
  #pragma unroll
  for (int j2 = 0; j2 < 2; ++j2) {
    ushort8 qv = *(const ushort8*)(src + j2 * 2048 + tid * 8);
    #pragma unroll
    for (int e = 0; e < 8; ++e) kv[j2 * 8 + e] = mono16((u16)qv[e]);
  }

  int hbmin = 255, hbmax = 0;
  #pragma unroll
  for (int j = 0; j < 16; ++j) {
    int hb = (int)(kv[j] >> 8);
    hbmin = min(hbmin, hb); hbmax = max(hbmax, hb);
  }
  #pragma unroll
  for (int off = 32; off > 0; off >>= 1) {
    hbmin = min(hbmin, __shfl_down(hbmin, off));
    hbmax = max(hbmax, __shfl_down(hbmax, off));
  }
  if (lane == 0) { wred[w4] = hbmin; wred[4 + w4] = hbmax; }
  __syncthreads();
  int bmin = min(min(wred[0], wred[1]), min(wred[2], wred[3]));
  int bmax = max(max(wred[4], wred[5]), max(wred[6], wred[7]));
  __syncthreads();

  unsigned int prefix;
  int kk = KC;
  if (bmin == bmax) {
    prefix = (unsigned int)bmin;
  } else {
    hist[tid] = 0; hist[tid + 256] = 0; hist[tid + 512] = 0; hist[tid + 768] = 0;
    __syncthreads();
    #pragma unroll
    for (int j = 0; j < 16; ++j) hist_add2(hist + hbase, (int)(kv[j] >> 8), true);
    __syncthreads();
    int x = hist[tid] + hist[tid + 256] + hist[tid + 512] + hist[tid + 768];
    #pragma unroll
    for (int off = 1; off < 64; off <<= 1) { int y = __shfl_up(x, off); if (lane >= off) x += y; }
    if (lane == 63) wred[w4] = x;
    __syncthreads();
    #pragma unroll
    for (int i = 0; i < 4; ++i) if (i < w4) x += wred[i];
    cum[tid] = x;
    __syncthreads();
    int prev = (tid == 0) ? 0 : cum[tid - 1];
    if (prev < kk && kk <= cum[tid]) { selb[0] = tid; selb[1] = kk - prev; }
    __syncthreads();
    prefix = (unsigned int)selb[0];
    kk = selb[1];
    __syncthreads();
  }

  hist[tid] = 0; hist[tid + 256] = 0; hist[tid + 512] = 0; hist[tid + 768] = 0;
  __syncthreads();
  #pragma unroll
  for (int j = 0; j < 16; ++j)
    hist_add2(hist + hbase, (int)(kv[j] & 255u), (kv[j] >> 8) == prefix);
  __syncthreads();
  int x = hist[tid] + hist[tid + 256] + hist[tid + 512] + hist[tid + 768];
  #pragma unroll
  for (int off = 1; off < 64; off <<= 1) { int y = __shfl_up(x, off); if (lane >= off) x += y; }
  if (lane == 63) wred[w4] = x;
  __syncthreads();
  #pragma unroll
  for (int i = 0; i < 4; ++i) if (i < w4) x += wred[i];
  cum[tid] = x;
  __syncthreads();
  int prev = (tid == 0) ? 0 : cum[tid - 1];
  if (prev < kk && kk <= cum[tid]) { selb[0] = tid; selb[1] = kk - prev; }
  __syncthreads();
  unsigned int key = (prefix << 8) | (unsigned int)selb[0];
  float thr = mono2f16(key);
  float* o50 = top + (size_t)row * (NCHUNK * 2 * KC) + (schunk * 2 + half) * KC;
  __syncthreads();

  int cless = 0;
  #pragma unroll
  for (int j = 0; j < 16; ++j) if (kv[j] < key) cless++;
  int xc = cless;
  #pragma unroll
  for (int off = 1; off < 64; off <<= 1) { int y = __shfl_up(xc, off); if (lane >= off) xc += y; }
  if (lane == 63) wred[w4] = xc;
  __syncthreads();
  #pragma unroll
  for (int i = 0; i < 4; ++i) if (i < w4) xc += wred[i];
  int o = xc - cless;
  #pragma unroll
  for (int j = 0; j < 16; ++j)
    if (kv[j] < key) o50[o++] = mono2f16(kv[j]);
  cum[tid] = xc;
  __syncthreads();
  int total_less = cum[255];
  for (int i = total_less + tid; i < KC; i += 256) o50[i] = thr;
}

// ---------------- fused DPC: GEMM(c) || [dpp-gemm] || select || [dpp-sel] --
// Template params gate branch compilation per instantiation (rule #19);
// dpp-select rows are distributed at runtime (ndpps, dpps_base) so each
// launch's aux load stays within the gemm shadow (r14/r16 lesson).
template<int NDPPG, int DPPS_ON>
__global__ void __launch_bounds__(256, 2) k_dpc(
    const u16* __restrict__ phe_bf, const u16* __restrict__ emb_bf,
    int gchunk, int ngemm, u16* __restrict__ dw,
    const u16* __restrict__ dr, int schunk, float* __restrict__ top,
    const float* __restrict__ rp, const float* __restrict__ rc, int nsel,
    int ndpps, int dpps_base,
    float* __restrict__ d_pp, float* __restrict__ pp_part)
{
  __shared__ __align__(16) char smem[32768];
  int bid = (int)blockIdx.x;
  int tid = threadIdx.x;
  if (bid < ngemm) {
    u16* As = (u16*)smem;
    u16* Bs = (u16*)(smem + 16384);
    int lane = tid & 63, w = tid >> 6;
    int wm = w >> 1, wn = w & 1;
    int nwg = ngemm, orig = bid;
    int q = nwg >> 3, r = nwg & 7;
    int xcd = orig & 7, i0 = orig >> 3;
    int wgid = (xcd < r ? xcd * (q + 1) : r * (q + 1) + (xcd - r) * q) + i0;
    int m0 = (wgid >> 6) << 7;
    int n0 = (wgid & 63) << 7;
    const u16* Bm = emb_bf + (size_t)gchunk * CHUNK * DIM;
    const float* rcc = rc + gchunk * CHUNK;
    int bvalid = VOC - gchunk * CHUNK; if (bvalid > CHUNK) bvalid = CHUNK;

    floatx4 acc[4][4];
    #pragma unroll
    for (int i = 0; i < 4; ++i)
      #pragma unroll
      for (int j = 0; j < 4; ++j)
        acc[i][j] = (floatx4){0.f, 0.f, 0.f, 0.f};

    int hi = lane >> 4, rsw = lane & 7;
    for (int kt = 0; kt < DIM / 64; ++kt) {
      int k0 = kt * 64;
      #pragma unroll
      for (int p = 0; p < 4; ++p) {
        int c = p * 256 + tid;
        int row = c >> 3;
        int src16 = (c & 7) ^ (row & 7);
        load_lds16(phe_bf + (size_t)(m0 + row) * DIM + k0 + src16 * 8,
                   &As[p * 2048 + w * 512]);
      }
      #pragma unroll
      for (int p = 0; p < 4; ++p) {
        int c = p * 256 + tid;
        int row = c >> 3;
        int src16 = (c & 7) ^ (row & 7);
        load_lds16(Bm + (size_t)(n0 + row) * DIM + k0 + src16 * 8,
                   &Bs[p * 2048 + w * 512]);
      }
      __syncthreads();
      #pragma unroll
      for (int ks = 0; ks < 2; ++ks) {
        int chk = ((ks << 2) | hi) ^ rsw;
        short8 a[4], b[4];
        #pragma unroll
        for (int i = 0; i < 4; ++i)
          a[i] = *(const short8*)&As[(wm * 64 + i * 16 + (lane & 15)) * 64 + chk * 8];
        #pragma unroll
        for (int j = 0; j < 4; ++j)
          b[j] = *(const short8*)&Bs[(wn * 64 + j * 16 + (lane & 15)) * 64 + chk * 8];
        #pragma unroll
        for (int i = 0; i < 4; ++i)
          #pragma unroll
          for (int j = 0; j < 4; ++j)
            acc[i][j] = __builtin_amdgcn_mfma_f32_16x16x32_bf16(a[i], b[j], acc[i][j], 0, 0, 0);
      }
      __syncthreads();
    }
    #pragma unroll
    for (int i = 0; i < 4; ++i) {
      #pragma unroll
      for (int j = 0; j < 4; ++j) {
        floatx4 v = acc[i][j];
        int col = n0 + wn * 64 + j * 16 + (lane & 15);
        int rb = m0 + wm * 64 + i * 16 + ((lane >> 4) << 2);
        #pragma unroll
        for (int qq = 0; qq < 4; ++qq) {
          int rr = rb + qq;
          float d = (col < bvalid) ? sqrtf(fmaxf(rp[rr] + rcc[col] - 2.f * v[qq], 0.f)) : BIGF;
          dw[(size_t)rr * CHUNK + col] = f2bf(d);
        }
      }
    }
    return;
  }
  bid -= ngemm;
  if (NDPPG > 0) {
    if (bid < NDPPG) {
      // dpp gemm: d_pp[m][n] = rp[m]+rp[n]-2*phe[m].phe[n], 128x128 tiles
      u16* As = (u16*)smem;
      u16* Bs = (u16*)(smem + 16384);
      int lane = tid & 63, w = tid >> 6;
      int wm = w >> 1, wn = w & 1;
      int m0 = (bid >> 4) << 7;
      int n0 = (bid & 15) << 7;

      floatx4 acc[4][4];
      #pragma unroll
      for (int i = 0; i < 4; ++i)
        #pragma unroll
        for (int j = 0; j < 4; ++j)
          acc[i][j] = (floatx4){0.f, 0.f, 0.f, 0.f};

      int hi = lane >> 4, rsw = lane & 7;
      for (int kt = 0; kt < DIM / 64; ++kt) {
        int k0 = kt * 64;
        #pragma unroll
        for (int p = 0; p < 4; ++p) {
          int c = p * 256 + tid;
          int row = c >> 3;
          int src16 = (c & 7) ^ (row & 7);
          load_lds16(phe_bf + (size_t)(m0 + row) * DIM + k0 + src16 * 8,
                     &As[p * 2048 + w * 512]);
        }
        #pragma unroll
        for (int p = 0; p < 4; ++p) {
          int c = p * 256 + tid;
          int row = c >> 3;
          int src16 = (c & 7) ^ (row & 7);
          load_lds16(phe_bf + (size_t)(n0 + row) * DIM + k0 + src16 * 8,
                     &Bs[p * 2048 + w * 512]);
        }
        __syncthreads();
        #pragma unroll
        for (int ks = 0; ks < 2; ++ks) {
          int chk = ((ks << 2) | hi) ^ rsw;
          short8 a[4], b[4];
          #pragma unroll
          for (int i = 0; i < 4; ++i)
            a[i] = *(const short8*)&As[(wm * 64 + i * 16 + (lane & 15)) * 64 + chk * 8];
          #pragma unroll
          for (int j = 0; j < 4; ++j)
            b[j] = *(const short8*)&Bs[(wn * 64 + j * 16 + (lane & 15)) * 64 + chk * 8];
          #pragma unroll
          for (int i = 0; i < 4; ++i)
            #pragma unroll
            for (int j = 0; j < 4; ++j)
              acc[i][j] = __builtin_amdgcn_mfma_f32_16x16x32_bf16(a[i], b[j], acc[i][j], 0, 0, 0);
        }
        __syncthreads();
      }
      #pragma unroll
      for (int i = 0; i < 4; ++i) {
        #pragma unroll
        for (int j = 0; j < 4; ++j) {
          floatx4 v = acc[i][j];
          int col = n0 + wn * 64 + j * 16 + (lane & 15);
          int rb = m0 + wm * 64 + i * 16 + ((lane >> 4) << 2);
          #pragma unroll
          for (int qq = 0; qq < 4; ++qq) {
            int rr = rb + qq;
            d_pp[(size_t)rr * PHE + col] = rp[rr] + rp[col] - 2.f * v[qq];
          }
        }
      }
      return;
    }
    bid -= NDPPG;
  }
  if (bid < nsel) {
    if (schunk >= 0) dpc_select(smem, bid, dr, schunk, top);
    return;
  }
  bid -= nsel;
  if (DPPS_ON) {
    if (bid >= ndpps) return;
    // dpp select: smallest-10 stats of d_pp row (2048 f32), carve-only smem
    int row = dpps_base + bid;
    const float* src = d_pp + (size_t)row * PHE;
    int* hist = (int*)smem;
    int* cum  = hist + 1024;
    int* wsum = cum + 256;
    int* selb = wsum + 4;
    float* fred = (float*)(selb + 2);   // 12 floats
    int lane = tid & 63, w4 = tid >> 6;
    int hbase = w4 << 8;

    unsigned int v[8];
    #pragma unroll
    for (int j = 0; j < 8; ++j) v[j] = f2mono(src[tid + j * 256]);

    unsigned int prefix = 0, pmask = 0;
    int kk = KP;
    for (int shift = 24; shift >= 0; shift -= 8) {
      hist[tid] = 0; hist[tid + 256] = 0; hist[tid + 512] = 0; hist[tid + 768] = 0;
      __syncthreads();
      #pragma unroll
      for (int j = 0; j < 8; ++j)
        hist_add2(hist + hbase, (int)((v[j] >> shift) & 255), (v[j] & pmask) == prefix);
      __syncthreads();
      int x = hist[tid] + hist[tid + 256] + hist[tid + 512] + hist[tid + 768];
      #pragma unroll
      for (int off = 1; off < 64; off <<= 1) { int y = __shfl_up(x, off); if (lane >= off) x += y; }
      if (lane == 63) wsum[w4] = x;
      __syncthreads();
      #pragma unroll
      for (int i = 0; i < 4; ++i) if (i < w4) x += wsum[i];
      cum[tid] = x;
      __syncthreads();
      int prev = (tid == 0) ? 0 : cum[tid - 1];
      if (prev < kk && kk <= cum[tid]) { selb[0] = tid; selb[1] = kk - prev; }
      __syncthreads();
      prefix |= ((unsigned int)selb[0]) << shift;
      pmask |= 255u << shift;
      kk = selb[1];
      __syncthreads();
    }

    float thr = mono2f(prefix);
    int need = kk;
    float s = 0.f, se = 0.f, sq = 0.f;
    #pragma unroll
    for (int j = 0; j < 8; ++j) {
      if (v[j] < prefix) {
        float f = mono2f(v[j]);
        s += f; se += __expf(-f); sq += f * f;
      }
    }
    s = waveRedSum(s); se = waveRedSum(se); sq = waveRedSum(sq);
    if (lane == 0) { fred[w4] = s; fred[4 + w4] = se; fred[8 + w4] = sq; }
    __syncthreads();
    if (tid == 0) {
      float ts = fred[0] + fred[1] + fred[2] + fred[3];
      float tse = fred[4] + fred[5] + fred[6] + fred[7];
      float tsq = fred[8] + fred[9] + fred[10] + fred[11];
      float fn = (float)need;
      pp_part[(size_t)row * 4] = ts + fn * thr;
      pp_part[(size_t)row * 4 + 1] = tse + fn * __expf(-thr);
      pp_part[(size_t)row * 4 + 2] = tsq + fn * thr * thr;
    }
    return;
  }
}

// ---------------- logits GEMM (bf16 store) || tail select -----------------
__global__ void __launch_bounds__(256, 2) k_dpc_log(
    const u16* __restrict__ visit_bf, const u16* __restrict__ phe_bf,
    int ngemm, u16* __restrict__ logit_bf,
    const u16* __restrict__ dr, int schunk, float* __restrict__ top)
{
  __shared__ __align__(16) char smem[32768];
  int bid = (int)blockIdx.x;
  if (bid < ngemm) {
    u16* As = (u16*)smem;
    u16* Bs = (u16*)(smem + 16384);
    int tid = threadIdx.x, lane = tid & 63, w = tid >> 6;
    int wm = w >> 1, wn = w & 1;
    int nwg = ngemm, orig = bid;
    int q = nwg >> 3, r = nwg & 7;
    int xcd = orig & 7, i0 = orig >> 3;
    int wgid = (xcd < r ? xcd * (q + 1) : r * (q + 1) + (xcd - r) * q) + i0;
    int m0 = (wgid >> 4) << 7;        // gridx = PHE/128 = 16
    int n0 = (wgid & 15) << 7;

    floatx4 acc[4][4];
    #pragma unroll
    for (int i = 0; i < 4; ++i)
      #pragma unroll
      for (int j = 0; j < 4; ++j)
        acc[i][j] = (floatx4){0.f, 0.f, 0.f, 0.f};

    int hi = lane >> 4, rsw = lane & 7;
    for (int kt = 0; kt < DIM / 64; ++kt) {
      int k0 = kt * 64;
      #pragma unroll
      for (int p = 0; p < 4; ++p) {
        int c = p * 256 + tid;
        int row = c >> 3;
        int src16 = (c & 7) ^ (row & 7);
        load_lds16(visit_bf + (size_t)(m0 + row) * DIM + k0 + src16 * 8,
                   &As[p * 2048 + w * 512]);
      }
      #pragma unroll
      for (int p = 0; p < 4; ++p) {
        int c = p * 256 + tid;
        int row = c >> 3;
        int src16 = (c & 7) ^ (row & 7);
        load_lds16(phe_bf + (size_t)(n0 + row) * DIM + k0 + src16 * 8,
                   &Bs[p * 2048 + w * 512]);
      }
      __syncthreads();
      #pragma unroll
      for (int ks = 0; ks < 2; ++ks) {
        int chk = ((ks << 2) | hi) ^ rsw;
        short8 a[4], b[4];
        #pragma unroll
        for (int i = 0; i < 4; ++i)
          a[i] = *(const short8*)&As[(wm * 64 + i * 16 + (lane & 15)) * 64 + chk * 8];
        #pragma unroll
        for (int j = 0; j < 4; ++j)
          b[j] = *(const short8*)&Bs[(wn * 64 + j * 16 + (lane & 15)) * 64 + chk * 8];
        #pragma unroll
        for (int i = 0; i < 4; ++i)
          #pragma unroll
          for (int j = 0; j < 4; ++j)
            acc[i][j] = __builtin_amdgcn_mfma_f32_16x16x32_bf16(a[i], b[j], acc[i][j], 0, 0, 0);
      }
      __syncthreads();
    }
    #pragma unroll
    for (int i = 0; i < 4; ++i) {
      #pragma unroll
      for (int j = 0; j < 4; ++j) {
        floatx4 v = acc[i][j];
        int col = n0 + wn * 64 + j * 16 + (lane & 15);
        int rb = m0 + wm * 64 + i * 16 + ((lane >> 4) << 2);
        #pragma unroll
        for (int qq = 0; qq < 4; ++qq)
          logit_bf[(size_t)(rb + qq) * PHE + col] = f2bf(v[qq]);
      }
    }
  } else {
    if (schunk < 0) return;
    dpc_select(smem, bid - ngemm, dr, schunk, top);
  }
}

// ---------------- GEMM (NT), 2-phase double-buffered, BK=64 ----------------
template<int EPI, int BM, int BN, int NTH, int WR, int WC>
__global__ void __launch_bounds__(NTH, 2) k_gemm2(
    const u16* __restrict__ A, int lda,
    const u16* __restrict__ Bm, int ldb, int K,
    float* __restrict__ outF, u16* __restrict__ outU, int ldc,
    const float* __restrict__ rp, const float* __restrict__ bias, int nepi)
{
  constexpr int BK = 64;
  constexpr int MR = BM / WR / 16;
  constexpr int NR = BN / WC / 16;
  constexpr int LD_A = BM * BK / (NTH * 8);
  constexpr int LD_B = BN * BK / (NTH * 8);
  __shared__ __align__(16) u16 As[2][BM * BK];
  __shared__ __align__(16) u16 Bs[2][BN * BK];
  int tid = threadIdx.x, lane = tid & 63, w = tid >> 6;
  int wm = w / WC, wn = w % WC;
  int m0, n0;
  xcd_block(BM, BN, m0, n0);

  floatx4 acc[MR][NR];
  #pragma unroll
  for (int i = 0; i < MR; ++i)
    #pragma unroll
    for (int j = 0; j < NR; ++j)
      acc[i][j] = (floatx4){0.f, 0.f, 0.f, 0.f};

  auto stage = [&](int buf, int k0) {
    #pragma unroll
    for (int p = 0; p < LD_A; ++p) {
      int c = p * NTH + tid;
      int row = c >> 3;
      int src16 = (c & 7) ^ (row & 7);
      load_lds16(A + (size_t)(m0 + row) * lda + k0 + src16 * 8,
                 &As[buf][p * NTH * 8 + w * 512]);
    }
    #pragma unroll
    for (int p = 0; p < LD_B; ++p) {
      int c = p * NTH + tid;
      int row = c >> 3;
      int src16 = (c & 7) ^ (row & 7);
      load_lds16(Bm + (size_t)(n0 + row) * ldb + k0 + src16 * 8,
                 &Bs[buf][p * NTH * 8 + w * 512]);
    }
  };

  int nt = K / BK;
  stage(0, 0);
  __syncthreads();
  int cur = 0;
  int hi = lane >> 4;
  int rsw = lane & 7;
  for (int kt = 0; kt < nt; ++kt) {
    if (kt + 1 < nt) stage(cur ^ 1, (kt + 1) * BK);
    #pragma unroll
    for (int ks = 0; ks < 2; ++ks) {
      int chk = ((ks << 2) | hi) ^ rsw;
      short8 a[MR], b[NR];
      #pragma unroll
      for (int i = 0; i < MR; ++i)
        a[i] = *(const short8*)&As[cur][(wm * (BM / WR) + i * 16 + (lane & 15)) * BK + chk * 8];
      #pragma unroll
      for (int j = 0; j < NR; ++j)
        b[j] = *(const short8*)&Bs[cur][(wn * (BN / WC) + j * 16 + (lane & 15)) * BK + chk * 8];
      #pragma unroll
      for (int i = 0; i < MR; ++i)
        #pragma unroll
        for (int j = 0; j < NR; ++j)
          acc[i][j] = __builtin_amdgcn_mfma_f32_16x16x32_bf16(a[i], b[j], acc[i][j], 0, 0, 0);
    }
    __syncthreads();
    cur ^= 1;
  }

  #pragma unroll
  for (int i = 0; i < MR; ++i) {
    #pragma unroll
    for (int j = 0; j < NR; ++j) {
      floatx4 v = acc[i][j];
      int col = n0 + wn * (BN / WC) + j * 16 + (lane & 15);
      int rb = m0 + wm * (BM / WR) + i * 16 + ((lane >> 4) << 2);
      #pragma unroll
      for (int qq = 0; qq < 4; ++qq)
        epi_write<EPI>(rb + qq, col, v[qq], outF, outU, ldc, rp, bias, nepi);
    }
  }
}

// ---------------- GEMM (NT), single-buffer, 128x128, 4 blocks/CU -----------
template<int EPI>
__global__ void __launch_bounds__(256, 4) k_gemm2s(
    const u16* __restrict__ A, int lda,
    const u16* __restrict__ Bm, int ldb, int K,
    float* __restrict__ outF, u16* __restrict__ outU, int ldc,
    const float* __restrict__ rp, const float* __restrict__ bias, int nepi)
{
  constexpr int BM = 128, BN = 128, BK = 64, NTH = 256;
  constexpr int MR = 4, NR = 4;
  __shared__ __align__(16) u16 As[BM * BK];
  __shared__ __align__(16) u16 Bs[BN * BK];
  int tid = threadIdx.x, lane = tid & 63, w = tid >> 6;
  int wm = w >> 1, wn = w & 1;
  int m0, n0;
  xcd_block(BM, BN, m0, n0);

  floatx4 acc[MR][NR];
  #pragma unroll
  for (int i = 0; i < MR; ++i)
    #pragma unroll
    for (int j = 0; j < NR; ++j)
      acc[i][j] = (floatx4){0.f, 0.f, 0.f, 0.f};

  int hi = lane >> 4;
  int rsw = lane & 7;
  int nt = K / BK;
  for (int kt = 0; kt < nt; ++kt) {
    int k0 = kt * BK;
    #pragma unroll
    for (int p = 0; p < 4; ++p) {
      int c = p * NTH + tid;
      int row = c >> 3;
      int src16 = (c & 7) ^ (row & 7);
      load_lds16(A + (size_t)(m0 + row) * lda + k0 + src16 * 8,
                 &As[p * NTH * 8 + w * 512]);
    }
    #pragma unroll
    for (int p = 0; p < 4; ++p) {
      int c = p * NTH + tid;
      int row = c >> 3;
      int src16 = (c & 7) ^ (row & 7);
      load_lds16(Bm + (size_t)(n0 + row) * ldb + k0 + src16 * 8,
                 &Bs[p * NTH * 8 + w * 512]);
    }
    __syncthreads();
    #pragma unroll
    for (int ks = 0; ks < 2; ++ks) {
      int chk = ((ks << 2) | hi) ^ rsw;
      short8 a[MR], b[NR];
      #pragma unroll
      for (int i = 0; i < MR; ++i)
        a[i] = *(const short8*)&As[(wm * 64 + i * 16 + (lane & 15)) * BK + chk * 8];
      #pragma unroll
      for (int j = 0; j < NR; ++j)
        b[j] = *(const short8*)&Bs[(wn * 64 + j * 16 + (lane & 15)) * BK + chk * 8];
      #pragma unroll
      for (int i = 0; i < MR; ++i)
        #pragma unroll
        for (int j = 0; j < NR; ++j)
          acc[i][j] = __builtin_amdgcn_mfma_f32_16x16x32_bf16(a[i], b[j], acc[i][j], 0, 0, 0);
    }
    __syncthreads();
  }

  #pragma unroll
  for (int i = 0; i < MR; ++i) {
    #pragma unroll
    for (int j = 0; j < NR; ++j) {
      floatx4 v = acc[i][j];
      int col = n0 + wn * 64 + j * 16 + (lane & 15);
      int rb = m0 + wm * 64 + i * 16 + ((lane >> 4) << 2);
      #pragma unroll
      for (int qq = 0; qq < 4; ++qq)
        epi_write<EPI>(rb + qq, col, v[qq], outF, outU, ldc, rp, bias, nepi);
    }
  }
}

// ---------------- softmax + entropy (bf16 logits in-place) ----------------
__global__ void __launch_bounds__(256) k_softmax(
    u16* __restrict__ probs_bf, const int* __restrict__ mask,
    float* __restrict__ probs, float* __restrict__ entropy)
{
  int row = blockIdx.x;
  int tid = threadIdx.x;
  u16* pb = probs_bf + (size_t)row * PHE;
  float* pp = probs + (size_t)row * PHE;
  if (mask[row] != 0) {
    const float u = 1.0f / (float)PHE;
    const u16 ub = f2bf(u);
    for (int i = tid; i < PHE; i += 256) { pp[i] = u; pb[i] = ub; }
    if (tid == 0) entropy[row] = 0.f;
    return;
  }
  float l[8];
  float mx = -BIGF;
  #pragma unroll
  for (int j = 0; j < 8; ++j) { l[j] = bf2f(pb[tid + j * 256]); mx = fmaxf(mx, l[j]); }
  mx = blockRedMax(mx);
  float s = 0.f;
  #pragma unroll
  for (int j = 0; j < 8; ++j) { l[j] = __expf(l[j] - mx); s += l[j]; }
  s = blockRedSum(s);
  float inv = 1.0f / s;
  float ent = 0.f;
  #pragma unroll
  for (int j = 0; j < 8; ++j) {
    float p = l[j] * inv;
    pp[tid + j * 256] = p;
    pb[tid + j * 256] = f2bf(p);
    ent += p * __logf(p);
  }
  ent = blockRedSum(ent);
  if (tid == 0) entropy[row] = -ent;
}

// ---------------- add + layernorm ----------------
__global__ void __launch_bounds__(256) k_ln(
    const float* __restrict__ xa, const float* __restrict__ xb,
    const float* __restrict__ g, const float* __restrict__ bb,
    float* __restrict__ outF, u16* __restrict__ outBf)
{
  int row = blockIdx.x;
  int tid = threadIdx.x;
  const float* pa = xa + (size_t)row * DIM;
  const float* pb = xb + (size_t)row * DIM;
  float x0 = pa[tid] + pb[tid];
  float x1 = pa[tid + 256] + pb[tid + 256];
  float mu = blockRedSum(x0 + x1) * (1.0f / DIM);
  float d0 = x0 - mu, d1 = x1 - mu;
  float var = blockRedSum(d0 * d0 + d1 * d1) * (1.0f / DIM);
  float rs = 1.0f / sqrtf(var + LNEPS);
  float y0 = d0 * rs * g[tid] + bb[tid];
  float y1 = d1 * rs * g[tid + 256] + bb[tid + 256];
  if (outF) {
    outF[(size_t)row * DIM + tid] = y0;
    outF[(size_t)row * DIM + tid + 256] = y1;
  }
  if (outBf) {
    outBf[(size_t)row * DIM + tid] = f2bf(y0);
    outBf[(size_t)row * DIM + tid + 256] = f2bf(y1);
  }
}

// ---------------- radix smallest-k per row, f32 keys (merge) ---------------
template<int NPER>
__global__ void __launch_bounds__(256) k_rsel(
    const float* __restrict__ in, int ldin, int ncols, int k, int mode,
    float* __restrict__ out)
{
  __shared__ int hist[1024];
  __shared__ int cum[256];
  __shared__ int wsum[4];
  __shared__ int sel_bucket, sel_rank;
  int row = blockIdx.x;
  int tid = threadIdx.x;
  int lane = tid & 63, w = tid >> 6;
  int hbase = w << 8;
  const float* src = in + (size_t)row * ldin;

  unsigned int v[NPER];
  #pragma unroll
  for (int j = 0; j < NPER; ++j) {
    int idx = tid + j * 256;
    v[j] = (idx < ncols) ? f2mono(src[idx]) : 0xFFFFFFFFu;
  }

  unsigned int prefix = 0, pmask = 0;
  int kk = k;
  for (int shift = 24; shift >= 0; shift -= 8) {
    hist[tid] = 0; hist[tid + 256] = 0; hist[tid + 512] = 0; hist[tid + 768] = 0;
    __syncthreads();
    #pragma unroll
    for (int j = 0; j < NPER; ++j)
      hist_add2(hist + hbase, (int)((v[j] >> shift) & 255), (v[j] & pmask) == prefix);
    __syncthreads();
    int x = hist[tid] + hist[tid + 256] + hist[tid + 512] + hist[tid + 768];
    #pragma unroll
    for (int off = 1; off < 64; off <<= 1) {
      int y = __shfl_up(x, off);
      if (lane >= off) x += y;
    }
    if (lane == 63) wsum[w] = x;
    __syncthreads();
    #pragma unroll
    for (int i = 0; i < 4; ++i) if (i < w) x += wsum[i];
    cum[tid] = x;
    __syncthreads();
    int prev = (tid == 0) ? 0 : cum[tid - 1];
    if (prev < kk && kk <= cum[tid]) { sel_bucket = tid; sel_rank = kk - prev; }
    __syncthreads();
    prefix |= ((unsigned int)sel_bucket) << shift;
    pmask |= 255u << shift;
    kk = sel_rank;
    __syncthreads();
  }

  float thr = mono2f(prefix);
  int need = kk;

  float s = 0.f, se = 0.f, sq = 0.f;
  #pragma unroll
  for (int j = 0; j < NPER; ++j) {
    if (v[j] < prefix) {
      float f = mono2f(v[j]);
      s += f; se += __expf(-f); sq += f * f;
    }
  }
  float ts = blockRedSum(s);
  float tse = blockRedSum(se);
  float tsq = blockRedSum(sq);
  if (tid == 0) {
    float fn = (float)need;
    ts += fn * thr;
    if (mode == 1) {
      out[row] = ts;
    } else {
      tse += fn * __expf(-thr);
      tsq += fn * thr * thr;
      out[(size_t)row * 4] = ts;
      out[(size_t)row * 4 + 1] = tse;
      out[(size_t)row * 4 + 2] = tsq;
    }
  }
}

// ---------------- final scalar reductions ----------------
__global__ void __launch_bounds__(256) k_final(
    const float* __restrict__ row_sum50, const float* __restrict__ pp_part,
    float* __restrict__ out_pcd, float* __restrict__ out_inv,
    float* __restrict__ out_mean, float* __restrict__ out_var)
{
  int tid = threadIdx.x;
  double s50 = 0, sn = 0, se = 0, sq = 0;
  for (int i = tid; i < PHE; i += 256) {
    s50 += (double)row_sum50[i];
    sn += (double)pp_part[(size_t)i * 4];
    se += (double)pp_part[(size_t)i * 4 + 1];
    sq += (double)pp_part[(size_t)i * 4 + 2];
  }
  s50 = blockRedSumD(s50);
  sn = blockRedSumD(sn);
  se = blockRedSumD(se);
  sq = blockRedSumD(sq);
  if (tid == 0) {
    *out_pcd = (float)(s50 / (double)(PHE * KC));
    double mean = sn / (double)(PHE * KP);
    *out_inv = (float)(se / (double)(PHE * KP));
    *out_mean = (float)mean;
    *out_var = (float)(sq / (double)(PHE * KP) - mean * mean);
  }
}

// ---------------- host ----------------
extern "C" void kernel_launch(void* const* d_in, const int* in_sizes, int n_in,
                              void* d_out, int out_size, void* d_ws, size_t ws_size,
                              hipStream_t stream)
{
  const float* visit = (const float*)d_in[0];
  const int*   vmask = (const int*)d_in[1];
  const float* emb   = (const float*)d_in[2];
  const float* phe   = (const float*)d_in[3];
  const float* w1    = (const float*)d_in[4];
  const float* b1    = (const float*)d_in[5];
  const float* w2    = (const float*)d_in[6];
  const float* b2    = (const float*)d_in[7];
  const float* ln1g  = (const float*)d_in[8];
  const float* ln1b  = (const float*)d_in[9];
  const float* ln2g  = (const float*)d_in[10];
  const float* ln2b  = (const float*)d_in[11];

  float* out = (float*)d_out;
  float* out2      = out;
  float* probs     = out + (size_t)BT * DIM;
  float* pcd       = probs + (size_t)BT * PHE;
  float* entropy   = pcd + 1;
  float* inv_loss  = entropy + BT;
  float* dist_mean = inv_loss + 1;
  float* dist_var  = dist_mean + 1;

  char* wsb = (char*)d_ws;
  size_t off = 0;
  auto alloc = [&](size_t bytes) -> char* {
    char* p = wsb + off;
    off = (off + bytes + 255) & ~(size_t)255;
    return p;
  };
  u16* phe_bf   = (u16*)alloc((size_t)PHE * DIM * 2);
  u16* pheT_bf  = (u16*)alloc((size_t)DIM * PHE * 2);
  u16* visit_bf = (u16*)alloc((size_t)BT * DIM * 2);
  u16* w1T_bf   = (u16*)alloc((size_t)DFFP2 * DIM * 2);
  u16* w2T_bf   = (u16*)alloc((size_t)DIM * DFFP2 * 2);
  float* r_p    = (float*)alloc((size_t)PHE * 4);
  float* r_c    = (float*)alloc((size_t)VOC * 4);
  char* big1    = alloc((size_t)67108864);            // 2x bf16 d-chunk ping-pong
  char* big2    = alloc((size_t)VOCP * DIM * 2);      // emb_bf padded -> h_bf [BT][DFFP2]
  float* top50c = (float*)alloc((size_t)PHE * NCHUNK * 2 * KC * 4);
  char* big3    = alloc((size_t)PHE * PHE * 4);       // d_pp f32 -> ctx_f [BT][DIM]
  u16* probs_bf = (u16*)alloc((size_t)BT * PHE * 2);  // logits bf16 -> probs (in-place)
  float* out1_f = (float*)alloc((size_t)BT * DIM * 4);
  u16* out1_bf  = (u16*)alloc((size_t)BT * DIM * 2);
  float* ffn_f  = (float*)alloc((size_t)BT * DIM * 4);
  float* row_sum50 = (float*)alloc((size_t)PHE * 4);
  float* pp_part   = (float*)alloc((size_t)PHE * 4 * 4);

  u16* dchunk0  = (u16*)big1;
  u16* dchunk1  = (u16*)(big1 + 33554432);
  u16* emb_bf   = (u16*)big2;
  u16* h_bf     = (u16*)big2;
  float* d_pp   = (float*)big3;
  float* ctx_f  = (float*)big3;

  if (ws_size < off) { k_sentinel<<<1, 1, 0, stream>>>(out); return; }

  // fused prep: row cvt+sumsq (emb, phe), visit cvt, 3 TILED transposes
  int nprep = (VOC + PHE) + PREP_VIS + PREP_PHT + PREP_W1 + PREP_W2;
  k_prep<<<nprep, 256, 0, stream>>>(emb, emb_bf, r_c, phe, phe_bf, r_p,
                                    visit, visit_bf, pheT_bf, w1, w1T_bf, w2, w2T_bf);

  // DPC pipeline with absorbed dpp, dpp-select DISTRIBUTED over L2..L4:
  // L0 = dpc c0 + dpp-gemm(256)        [1280 blocks = 5/CU, fully resident]
  // L1 = dpc c1 + sel c0
  // L2..L4 = dpc c + sel c-1 + dpp-sel(~683 each)
  // L5 = logits-gemm + sel c4
  k_dpc<256, 0><<<1024 + 256, 256, 0, stream>>>(
      phe_bf, emb_bf, 0, 1024, dchunk0, nullptr, -1, top50c, r_p, r_c, 0,
      0, 0, d_pp, pp_part);
  k_dpc<0, 0><<<1024 + 4096, 256, 0, stream>>>(
      phe_bf, emb_bf, 1, 1024, dchunk1, dchunk0, 0, top50c, r_p, r_c, 4096,
      0, 0, d_pp, pp_part);
  int dpps_done = 0;
  for (int c = 2; c < NCHUNK; ++c) {
    int s = c - 1;
    int nd = (PHE - dpps_done) / (NCHUNK - c);   // 683, 683, 682
    u16* dw = (c & 1) ? dchunk1 : dchunk0;
    const u16* dr = (s & 1) ? dchunk1 : dchunk0;
    k_dpc<0, 1><<<1024 + 4096 + nd, 256, 0, stream>>>(
        phe_bf, emb_bf, c, 1024, dw, dr, s, top50c, r_p, r_c, 4096,
        nd, dpps_done, d_pp, pp_part);
    dpps_done += nd;
  }
  k_dpc_log<<<1024 + PHE * 2, 256, 0, stream>>>(
      visit_bf, phe_bf, 1024, probs_bf,
      (NCHUNK - 1) & 1 ? dchunk1 : dchunk0, NCHUNK - 1, top50c);
  k_rsel<2><<<PHE, 256, 0, stream>>>(top50c, NCHUNK * 2 * KC, NCHUNK * 2 * KC, KC, 1, row_sum50);

  // softmax (in-place bf16 logits) -> ctx
  k_softmax<<<BT, 256, 0, stream>>>(probs_bf, vmask, probs, entropy);
  k_gemm2<EPI_STORE, 64, 128, 256, 2, 2><<<dim3(DIM / 128, BT / 64), 256, 0, stream>>>(
      probs_bf, PHE, pheT_bf, PHE, PHE, ctx_f, nullptr, DIM, nullptr, nullptr, 0);

  // LN1, FFN, LN2
  k_ln<<<BT, 256, 0, stream>>>(visit, ctx_f, ln1g, ln1b, out1_f, out1_bf);
  k_gemm2s<EPI_FFN1><<<dim3(DFFP2 / 128, BT / 128), 256, 0, stream>>>(
      out1_bf, DIM, w1T_bf, DIM, DIM, nullptr, h_bf, DFFP2, nullptr, b1, DFF);
  k_gemm2<EPI_FFN2, 64, 128, 256, 2, 2><<<dim3(DIM / 128, BT / 64), 256, 0, stream>>>(
      h_bf, DFFP2, w2T_bf, DFFP2, DFFP2, ffn_f, nullptr, DIM, nullptr, b2, 0);
  k_ln<<<BT, 256, 0, stream>>>(out1_f, ffn_f, ln2g, ln2b, out2, nullptr);

  // scalars
  k_final<<<1, 256, 0, stream>>>(row_sum50, pp_part, pcd, inv_loss, dist_mean, dist_var);
}

// Round 18
// 548.262 us; speedup vs baseline: 1.0804x; 1.0208x over previous
//
#include <hip/hip_runtime.h>
#include <stdint.h>
#include <stddef.h>

#define BATCH 32
#define TLEN 256
#define DIM 512
#define PHE 2048
#define VOC 40000
#define VOCP 40960
#define DFF 2148
#define DFFP2 2176
#define BT 8192
#define KC 50
#define KP 10
#define CHUNK 8192
#define NCHUNK 5
#define LNEPS 1e-6f
#define BIGF 1e30f

typedef unsigned short u16;
typedef __attribute__((ext_vector_type(8))) short short8;
typedef __attribute__((ext_vector_type(8))) unsigned short ushort8;
typedef __attribute__((ext_vector_type(4))) float floatx4;

__device__ inline u16 f2bf(float f) {
  union { float f; unsigned int u; } v; v.f = f;
  unsigned int u = v.u;
  return (u16)((u + 0x7fffu + ((u >> 16) & 1u)) >> 16);
}
__device__ inline float bf2f(u16 u) {
  union { unsigned int u; float f; } c; c.u = ((unsigned int)u) << 16;
  return c.f;
}

// monotone float<->uint transforms
__device__ inline unsigned int f2mono(float f) {
  union { float f; unsigned int u; } c; c.f = f;
  return (c.u & 0x80000000u) ? ~c.u : (c.u | 0x80000000u);
}
__device__ inline float mono2f(unsigned int u) {
  union { unsigned int u; float f; } c;
  c.u = (u & 0x80000000u) ? (u & 0x7FFFFFFFu) : ~u;
  return c.f;
}
__device__ inline unsigned int mono16(u16 u) {
  return (u & 0x8000u) ? (u16)~u : (u16)(u | 0x8000u);
}
__device__ inline float mono2f16(unsigned int k) {
  unsigned int ub = (k & 0x8000u) ? (k & 0x7FFFu) : ((~k) & 0xFFFFu);
  union { unsigned int u; float f; } c; c.u = ub << 16;
  return c.f;
}

// async global->LDS, 16 bytes per lane; LDS dest is wave-uniform base + lane*16B
__device__ inline void load_lds16(const void* g, void* l) {
  __builtin_amdgcn_global_load_lds(
      (const __attribute__((address_space(1))) unsigned int*)g,
      (__attribute__((address_space(3))) unsigned int*)l, 16, 0, 0);
}

// ---------------- reduction helpers ----------------
__device__ inline float waveRedSum(float v) {
  #pragma unroll
  for (int off = 32; off > 0; off >>= 1) v += __shfl_down(v, off);
  return v;
}
__device__ inline float waveRedMax(float v) {
  #pragma unroll
  for (int off = 32; off > 0; off >>= 1) v = fmaxf(v, __shfl_down(v, off));
  return v;
}
__device__ inline float blockRedSum(float v) {
  __shared__ float sm[8];
  int lane = threadIdx.x & 63, w = threadIdx.x >> 6, nw = blockDim.x >> 6;
  v = waveRedSum(v);
  __syncthreads();
  if (lane == 0) sm[w] = v;
  __syncthreads();
  float r = 0.f;
  for (int i = 0; i < nw; ++i) r += sm[i];
  return r;
}
__device__ inline float blockRedMax(float v) {
  __shared__ float sm2[8];
  int lane = threadIdx.x & 63, w = threadIdx.x >> 6, nw = blockDim.x >> 6;
  v = waveRedMax(v);
  __syncthreads();
  if (lane == 0) sm2[w] = v;
  __syncthreads();
  float r = -BIGF;
  for (int i = 0; i < nw; ++i) r = fmaxf(r, sm2[i]);
  return r;
}
__device__ inline double blockRedSumD(double v) {
  __shared__ double red[256];
  int tid = threadIdx.x;
  __syncthreads();
  red[tid] = v;
  __syncthreads();
  for (int s = 128; s > 0; s >>= 1) {
    if (tid < s) red[tid] += red[tid + s];
    __syncthreads();
  }
  return red[0];
}

// dominance-test histogram add (deterministic integer adds)
__device__ inline void hist_add2(int* hist, int digit, bool pred) {
  int lane = threadIdx.x & 63;
  unsigned long long act = __ballot(pred);
  if (!act) return;
  int src = __ffsll((long long)act) - 1;
  int ld = __shfl(digit, src);
  unsigned long long m = __ballot(pred && digit == ld);
  if (__popcll(m) >= 32) {
    if (lane == src) atomicAdd(&hist[ld], (int)__popcll(m));
    if ((act & ~m) & (1ull << lane)) atomicAdd(&hist[digit], 1);
  } else {
    if (pred) atomicAdd(&hist[digit], 1);
  }
}

// ---------------- small utility kernels ----------------
__global__ void k_sentinel(float* out) { out[0] = -12345.0f; }

// fused prep. Row role: 4 rows/block, ONE WAVE PER ROW, float4 loads +
// ushort8 stores, wave-only reduction (no barriers, no LDS). Transposes
// LDS-tiled (coalesced).
#define PREP_ROWB ((VOC + PHE) / 4)          // 10512
#define PREP_VIS 2048
#define PREP_PHT 1024
#define PREP_W1  ((DFFP2 / 32) * (DIM / 32)) // 1088
#define PREP_W2  ((DIM / 32) * (DFFP2 / 32)) // 1088
__global__ void __launch_bounds__(256) k_prep(
    const float* __restrict__ emb, u16* __restrict__ emb_bf, float* __restrict__ r_c,
    const float* __restrict__ phe, u16* __restrict__ phe_bf, float* __restrict__ r_p,
    const float* __restrict__ visit, u16* __restrict__ visit_bf,
    u16* __restrict__ pheT_bf,
    const float* __restrict__ w1, u16* __restrict__ w1T_bf,
    const float* __restrict__ w2, u16* __restrict__ w2T_bf)
{
  __shared__ float tile[32][33];
  int bid = (int)blockIdx.x, tid = threadIdx.x;
  if (bid < PREP_ROWB) {
    int row = bid * 4 + (tid >> 6);          // one wave per row
    int lane = tid & 63;
    const float* src; u16* dst; float* rout;
    if (row < VOC) {
      src = emb + (size_t)row * DIM; dst = emb_bf + (size_t)row * DIM; rout = r_c + row;
    } else {
      int r2 = row - VOC;
      src = phe + (size_t)r2 * DIM; dst = phe_bf + (size_t)r2 * DIM; rout = r_p + r2;
    }
    float4 a = *(const float4*)(src + lane * 8);
    float4 b = *(const float4*)(src + lane * 8 + 4);
    ushort8 o;
    o[0] = f2bf(a.x); o[1] = f2bf(a.y); o[2] = f2bf(a.z); o[3] = f2bf(a.w);
    o[4] = f2bf(b.x); o[5] = f2bf(b.y); o[6] = f2bf(b.z); o[7] = f2bf(b.w);
    *(ushort8*)(dst + lane * 8) = o;
    float s = a.x * a.x + a.y * a.y + a.z * a.z + a.w * a.w
            + b.x * b.x + b.y * b.y + b.z * b.z + b.w * b.w;
    s = waveRedSum(s);
    if (lane == 0) *rout = s;
    return;
  }
  int b2 = bid - PREP_ROWB;
  int rr = tid >> 5, cc = tid & 31;
  if (b2 < PREP_VIS) {
    int base = b2 * 2048 + tid;
    #pragma unroll
    for (int e = 0; e < 8; ++e) {
      int i = base + e * 256;
      visit_bf[i] = f2bf(visit[i]);
    }
    return;
  }
  b2 -= PREP_VIS;
  if (b2 < PREP_PHT) {
    int i0 = (b2 >> 4) << 5, j0 = (b2 & 15) << 5;
    #pragma unroll
    for (int p = 0; p < 4; ++p)
      tile[p * 8 + rr][cc] = phe[(size_t)(i0 + p * 8 + rr) * DIM + j0 + cc];
    __syncthreads();
    #pragma unroll
    for (int p = 0; p < 4; ++p)
      pheT_bf[(size_t)(j0 + p * 8 + rr) * PHE + i0 + cc] = f2bf(tile[cc][p * 8 + rr]);
    return;
  }
  b2 -= PREP_PHT;
  if (b2 < PREP_W1) {
    // w1T[r][c] = (r<DFF) ? w1[c][r] : 0 ; dst [DFFP2][DIM], src [DIM][DFF]
    int r0 = (b2 >> 4) << 5, c0 = (b2 & 15) << 5;
    #pragma unroll
    for (int p = 0; p < 4; ++p) {
      int i = p * 8 + rr;
      tile[i][cc] = (r0 + cc < DFF) ? w1[(size_t)(c0 + i) * DFF + r0 + cc] : 0.f;
    }
    __syncthreads();
    #pragma unroll
    for (int p = 0; p < 4; ++p) {
      int a = p * 8 + rr;
      w1T_bf[(size_t)(r0 + a) * DIM + c0 + cc] = f2bf(tile[cc][a]);
    }
    return;
  }
  b2 -= PREP_W1;
  {
    // w2T[r][c] = (c<DFF) ? w2[c][r] : 0 ; dst [DIM][DFFP2], src [DFF][DIM]
    int r0 = (b2 / (DFFP2 / 32)) << 5, c0 = (b2 % (DFFP2 / 32)) << 5;
    #pragma unroll
    for (int p = 0; p < 4; ++p) {
      int i = p * 8 + rr;
      tile[i][cc] = (c0 + i < DFF) ? w2[(size_t)(c0 + i) * DIM + r0 + cc] : 0.f;
    }
    __syncthreads();
    #pragma unroll
    for (int p = 0; p < 4; ++p) {
      int a = p * 8 + rr;
      w2T_bf[(size_t)(r0 + a) * DFFP2 + c0 + cc] = f2bf(tile[cc][a]);
    }
    return;
  }
}

#define EPI_STORE 0
#define EPI_DPP   1
#define EPI_FFN1  3
#define EPI_FFN2  4

// XCD-aware bijective block swizzle (m204)
__device__ inline void xcd_block(int BM, int BN, int& m0, int& n0) {
  int nwg = gridDim.x * gridDim.y;
  int orig = blockIdx.y * gridDim.x + blockIdx.x;
  int q = nwg >> 3, r = nwg & 7;
  int xcd = orig & 7, i0 = orig >> 3;
  int wgid = (xcd < r ? xcd * (q + 1) : r * (q + 1) + (xcd - r) * q) + i0;
  m0 = (wgid / gridDim.x) * BM;
  n0 = (wgid % gridDim.x) * BN;
}

template<int EPI>
__device__ inline void epi_write(int rr, int col, float c,
    float* outF, u16* outU, int ldc, const float* rp,
    const float* bias, int nepi) {
  if (EPI == EPI_STORE) {
    outF[(size_t)rr * ldc + col] = c;
  } else if (EPI == EPI_DPP) {
    outF[(size_t)rr * ldc + col] = rp[rr] + rp[col] - 2.f * c;
  } else if (EPI == EPI_FFN1) {
    float h = (col < nepi) ? fmaxf(c + bias[col], 0.f) : 0.f;
    outU[(size_t)rr * ldc + col] = f2bf(h);
  } else if (EPI == EPI_FFN2) {
    outF[(size_t)rr * ldc + col] = c + bias[col];
  }
}

// ---------------- DPC select body (carve-only smem) -----------------------
__device__ __forceinline__ void dpc_select(
    char* smem, int si, const u16* __restrict__ dr, int schunk,
    float* __restrict__ top)
{
  int row = si >> 1, half = si & 1;
  const u16* src = dr + (size_t)row * CHUNK + half * 4096;
  int* hist = (int*)smem;
  int* cum  = hist + 1024;
  int* wred = cum + 256;
  int* selb = wred + 8;
  int tid = threadIdx.x, lane = tid & 63, w4 = tid >> 6;
  int hbase = w4 << 8;

  unsigned int kv[16];
  #pragma unroll
  for (int j2 = 0; j2 < 2; ++j2) {
    ushort8 qv = *(const ushort8*)(src + j2 * 2048 + tid * 8);
    #pragma unroll
    for (int e = 0; e < 8; ++e) kv[j2 * 8 + e] = mono16((u16)qv[e]);
  }

  int hbmin = 255, hbmax = 0;
  #pragma unroll
  for (int j = 0; j < 16; ++j) {
    int hb = (int)(kv[j] >> 8);
    hbmin = min(hbmin, hb); hbmax = max(hbmax, hb);
  }
  #pragma unroll
  for (int off = 32; off > 0; off >>= 1) {
    hbmin = min(hbmin, __shfl_down(hbmin, off));
    hbmax = max(hbmax, __shfl_down(hbmax, off));
  }
  if (lane == 0) { wred[w4] = hbmin; wred[4 + w4] = hbmax; }
  __syncthreads();
  int bmin = min(min(wred[0], wred[1]), min(wred[2], wred[3]));
  int bmax = max(max(wred[4], wred[5]), max(wred[6], wred[7]));
  __syncthreads();

  unsigned int prefix;
  int kk = KC;
  if (bmin == bmax) {
    prefix = (unsigned int)bmin;
  } else {
    hist[tid] = 0; hist[tid + 256] = 0; hist[tid + 512] = 0; hist[tid + 768] = 0;
    __syncthreads();
    #pragma unroll
    for (int j = 0; j < 16; ++j) hist_add2(hist + hbase, (int)(kv[j] >> 8), true);
    __syncthreads();
    int x = hist[tid] + hist[tid + 256] + hist[tid + 512] + hist[tid + 768];
    #pragma unroll
    for (int off = 1; off < 64; off <<= 1) { int y = __shfl_up(x, off); if (lane >= off) x += y; }
    if (lane == 63) wred[w4] = x;
    __syncthreads();
    #pragma unroll
    for (int i = 0; i < 4; ++i) if (i < w4) x += wred[i];
    cum[tid] = x;
    __syncthreads();
    int prev = (tid == 0) ? 0 : cum[tid - 1];
    if (prev < kk && kk <= cum[tid]) { selb[0] = tid; selb[1] = kk - prev; }
    __syncthreads();
    prefix = (unsigned int)selb[0];
    kk = selb[1];
    __syncthreads();
  }

  hist[tid] = 0; hist[tid + 256] = 0; hist[tid + 512] = 0; hist[tid + 768] = 0;
  __syncthreads();
  #pragma unroll
  for (int j = 0; j < 16; ++j)
    hist_add2(hist + hbase, (int)(kv[j] & 255u), (kv[j] >> 8) == prefix);
  __syncthreads();
  int x = hist[tid] + hist[tid + 256] + hist[tid + 512] + hist[tid + 768];
  #pragma unroll
  for (int off = 1; off < 64; off <<= 1) { int y = __shfl_up(x, off); if (lane >= off) x += y; }
  if (lane == 63) wred[w4] = x;
  __syncthreads();
  #pragma unroll
  for (int i = 0; i < 4; ++i) if (i < w4) x += wred[i];
  cum[tid] = x;
  __syncthreads();
  int prev = (tid == 0) ? 0 : cum[tid - 1];
  if (prev < kk && kk <= cum[tid]) { selb[0] = tid; selb[1] = kk - prev; }
  __syncthreads();
  unsigned int key = (prefix << 8) | (unsigned int)selb[0];
  float thr = mono2f16(key);
  float* o50 = top + (size_t)row * (NCHUNK * 2 * KC) + (schunk * 2 + half) * KC;
  __syncthreads();

  int cless = 0;
  #pragma unroll
  for (int j = 0; j < 16; ++j) if (kv[j] < key) cless++;
  int xc = cless;
  #pragma unroll
  for (int off = 1; off < 64; off <<= 1) { int y = __shfl_up(xc, off); if (lane >= off) xc += y; }
  if (lane == 63) wred[w4] = xc;
  __syncthreads();
  #pragma unroll
  for (int i = 0; i < 4; ++i) if (i < w4) xc += wred[i];
  int o = xc - cless;
  #pragma unroll
  for (int j = 0; j < 16; ++j)
    if (kv[j] < key) o50[o++] = mono2f16(kv[j]);
  cum[tid] = xc;
  __syncthreads();
  int total_less = cum[255];
  for (int i = total_less + tid; i < KC; i += 256) o50[i] = thr;
}

// ---------------- fused DPC: GEMM(c) || [dpp-gemm] || select || [dpp-sel] --
template<int NDPPG, int DPPS_ON>
__global__ void __launch_bounds__(256, 2) k_dpc(
    const u16* __restrict__ phe_bf, const u16* __restrict__ emb_bf,
    int gchunk, int ngemm, u16* __restrict__ dw,
    const u16* __restrict__ dr, int schunk, float* __restrict__ top,
    const float* __restrict__ rp, const float* __restrict__ rc, int nsel,
    int ndpps, int dpps_base,
    float* __restrict__ d_pp, float* __restrict__ pp_part)
{
  __shared__ __align__(16) char smem[32768];
  int bid = (int)blockIdx.x;
  int tid = threadIdx.x;
  if (bid < ngemm) {
    u16* As = (u16*)smem;
    u16* Bs = (u16*)(smem + 16384);
    int lane = tid & 63, w = tid >> 6;
    int wm = w >> 1, wn = w & 1;
    int nwg = ngemm, orig = bid;
    int q = nwg >> 3, r = nwg & 7;
    int xcd = orig & 7, i0 = orig >> 3;
    int wgid = (xcd < r ? xcd * (q + 1) : r * (q + 1) + (xcd - r) * q) + i0;
    int m0 = (wgid >> 6) << 7;
    int n0 = (wgid & 63) << 7;
    const u16* Bm = emb_bf + (size_t)gchunk * CHUNK * DIM;
    const float* rcc = rc + gchunk * CHUNK;
    int bvalid = VOC - gchunk * CHUNK; if (bvalid > CHUNK) bvalid = CHUNK;

    floatx4 acc[4][4];
    #pragma unroll
    for (int i = 0; i < 4; ++i)
      #pragma unroll
      for (int j = 0; j < 4; ++j)
        acc[i][j] = (floatx4){0.f, 0.f, 0.f, 0.f};

    int hi = lane >> 4, rsw = lane & 7;
    for (int kt = 0; kt < DIM / 64; ++kt) {
      int k0 = kt * 64;
      #pragma unroll
      for (int p = 0; p < 4; ++p) {
        int c = p * 256 + tid;
        int row = c >> 3;
        int src16 = (c & 7) ^ (row & 7);
        load_lds16(phe_bf + (size_t)(m0 + row) * DIM + k0 + src16 * 8,
                   &As[p * 2048 + w * 512]);
      }
      #pragma unroll
      for (int p = 0; p < 4; ++p) {
        int c = p * 256 + tid;
        int row = c >> 3;
        int src16 = (c & 7) ^ (row & 7);
        load_lds16(Bm + (size_t)(n0 + row) * DIM + k0 + src16 * 8,
                   &Bs[p * 2048 + w * 512]);
      }
      __syncthreads();
      #pragma unroll
      for (int ks = 0; ks < 2; ++ks) {
        int chk = ((ks << 2) | hi) ^ rsw;
        short8 a[4], b[4];
        #pragma unroll
        for (int i = 0; i < 4; ++i)
          a[i] = *(const short8*)&As[(wm * 64 + i * 16 + (lane & 15)) * 64 + chk * 8];
        #pragma unroll
        for (int j = 0; j < 4; ++j)
          b[j] = *(const short8*)&Bs[(wn * 64 + j * 16 + (lane & 15)) * 64 + chk * 8];
        #pragma unroll
        for (int i = 0; i < 4; ++i)
          #pragma unroll
          for (int j = 0; j < 4; ++j)
            acc[i][j] = __builtin_amdgcn_mfma_f32_16x16x32_bf16(a[i], b[j], acc[i][j], 0, 0, 0);
      }
      __syncthreads();
    }
    #pragma unroll
    for (int i = 0; i < 4; ++i) {
      #pragma unroll
      for (int j = 0; j < 4; ++j) {
        floatx4 v = acc[i][j];
        int col = n0 + wn * 64 + j * 16 + (lane & 15);
        int rb = m0 + wm * 64 + i * 16 + ((lane >> 4) << 2);
        #pragma unroll
        for (int qq = 0; qq < 4; ++qq) {
          int rr = rb + qq;
          float d = (col < bvalid) ? sqrtf(fmaxf(rp[rr] + rcc[col] - 2.f * v[qq], 0.f)) : BIGF;
          dw[(size_t)rr * CHUNK + col] = f2bf(d);
        }
      }
    }
    return;
  }
  bid -= ngemm;
  if (NDPPG > 0) {
    if (bid < NDPPG) {
      u16* As = (u16*)smem;
      u16* Bs = (u16*)(smem + 16384);
      int lane = tid & 63, w = tid >> 6;
      int wm = w >> 1, wn = w & 1;
      int m0 = (bid >> 4) << 7;
      int n0 = (bid & 15) << 7;

      floatx4 acc[4][4];
      #pragma unroll
      for (int i = 0; i < 4; ++i)
        #pragma unroll
        for (int j = 0; j < 4; ++j)
          acc[i][j] = (floatx4){0.f, 0.f, 0.f, 0.f};

      int hi = lane >> 4, rsw = lane & 7;
      for (int kt = 0; kt < DIM / 64; ++kt) {
        int k0 = kt * 64;
        #pragma unroll
        for (int p = 0; p < 4; ++p) {
          int c = p * 256 + tid;
          int row = c >> 3;
          int src16 = (c & 7) ^ (row & 7);
          load_lds16(phe_bf + (size_t)(m0 + row) * DIM + k0 + src16 * 8,
                     &As[p * 2048 + w * 512]);
        }
        #pragma unroll
        for (int p = 0; p < 4; ++p) {
          int c = p * 256 + tid;
          int row = c >> 3;
          int src16 = (c & 7) ^ (row & 7);
          load_lds16(phe_bf + (size_t)(n0 + row) * DIM + k0 + src16 * 8,
                     &Bs[p * 2048 + w * 512]);
        }
        __syncthreads();
        #pragma unroll
        for (int ks = 0; ks < 2; ++ks) {
          int chk = ((ks << 2) | hi) ^ rsw;
          short8 a[4], b[4];
          #pragma unroll
          for (int i = 0; i < 4; ++i)
            a[i] = *(const short8*)&As[(wm * 64 + i * 16 + (lane & 15)) * 64 + chk * 8];
          #pragma unroll
          for (int j = 0; j < 4; ++j)
            b[j] = *(const short8*)&Bs[(wn * 64 + j * 16 + (lane & 15)) * 64 + chk * 8];
          #pragma unroll
          for (int i = 0; i < 4; ++i)
            #pragma unroll
            for (int j = 0; j < 4; ++j)
              acc[i][j] = __builtin_amdgcn_mfma_f32_16x16x32_bf16(a[i], b[j], acc[i][j], 0, 0, 0);
        }
        __syncthreads();
      }
      #pragma unroll
      for (int i = 0; i < 4; ++i) {
        #pragma unroll
        for (int j = 0; j < 4; ++j) {
          floatx4 v = acc[i][j];
          int col = n0 + wn * 64 + j * 16 + (lane & 15);
          int rb = m0 + wm * 64 + i * 16 + ((lane >> 4) << 2);
          #pragma unroll
          for (int qq = 0; qq < 4; ++qq) {
            int rr = rb + qq;
            d_pp[(size_t)rr * PHE + col] = rp[rr] + rp[col] - 2.f * v[qq];
          }
        }
      }
      return;
    }
    bid -= NDPPG;
  }
  if (bid < nsel) {
    if (schunk >= 0) dpc_select(smem, bid, dr, schunk, top);
    return;
  }
  bid -= nsel;
  if (DPPS_ON) {
    if (bid >= ndpps) return;
    int row = dpps_base + bid;
    const float* src = d_pp + (size_t)row * PHE;
    int* hist = (int*)smem;
    int* cum  = hist + 1024;
    int* wsum = cum + 256;
    int* selb = wsum + 4;
    float* fred = (float*)(selb + 2);
    int lane = tid & 63, w4 = tid >> 6;
    int hbase = w4 << 8;

    unsigned int v[8];
    #pragma unroll
    for (int j = 0; j < 8; ++j) v[j] = f2mono(src[tid + j * 256]);

    unsigned int prefix = 0, pmask = 0;
    int kk = KP;
    for (int shift = 24; shift >= 0; shift -= 8) {
      hist[tid] = 0; hist[tid + 256] = 0; hist[tid + 512] = 0; hist[tid + 768] = 0;
      __syncthreads();
      #pragma unroll
      for (int j = 0; j < 8; ++j)
        hist_add2(hist + hbase, (int)((v[j] >> shift) & 255), (v[j] & pmask) == prefix);
      __syncthreads();
      int x = hist[tid] + hist[tid + 256] + hist[tid + 512] + hist[tid + 768];
      #pragma unroll
      for (int off = 1; off < 64; off <<= 1) { int y = __shfl_up(x, off); if (lane >= off) x += y; }
      if (lane == 63) wsum[w4] = x;
      __syncthreads();
      #pragma unroll
      for (int i = 0; i < 4; ++i) if (i < w4) x += wsum[i];
      cum[tid] = x;
      __syncthreads();
      int prev = (tid == 0) ? 0 : cum[tid - 1];
      if (prev < kk && kk <= cum[tid]) { selb[0] = tid; selb[1] = kk - prev; }
      __syncthreads();
      prefix |= ((unsigned int)selb[0]) << shift;
      pmask |= 255u << shift;
      kk = selb[1];
      __syncthreads();
    }

    float thr = mono2f(prefix);
    int need = kk;
    float s = 0.f, se = 0.f, sq = 0.f;
    #pragma unroll
    for (int j = 0; j < 8; ++j) {
      if (v[j] < prefix) {
        float f = mono2f(v[j]);
        s += f; se += __expf(-f); sq += f * f;
      }
    }
    s = waveRedSum(s); se = waveRedSum(se); sq = waveRedSum(sq);
    if (lane == 0) { fred[w4] = s; fred[4 + w4] = se; fred[8 + w4] = sq; }
    __syncthreads();
    if (tid == 0) {
      float ts = fred[0] + fred[1] + fred[2] + fred[3];
      float tse = fred[4] + fred[5] + fred[6] + fred[7];
      float tsq = fred[8] + fred[9] + fred[10] + fred[11];
      float fn = (float)need;
      pp_part[(size_t)row * 4] = ts + fn * thr;
      pp_part[(size_t)row * 4 + 1] = tse + fn * __expf(-thr);
      pp_part[(size_t)row * 4 + 2] = tsq + fn * thr * thr;
    }
    return;
  }
}

// ---------------- logits GEMM (bf16 store) || tail select -----------------
__global__ void __launch_bounds__(256, 2) k_dpc_log(
    const u16* __restrict__ visit_bf, const u16* __restrict__ phe_bf,
    int ngemm, u16* __restrict__ logit_bf,
    const u16* __restrict__ dr, int schunk, float* __restrict__ top)
{
  __shared__ __align__(16) char smem[32768];
  int bid = (int)blockIdx.x;
  if (bid < ngemm) {
    u16* As = (u16*)smem;
    u16* Bs = (u16*)(smem + 16384);
    int tid = threadIdx.x, lane = tid & 63, w = tid >> 6;
    int wm = w >> 1, wn = w & 1;
    int nwg = ngemm, orig = bid;
    int q = nwg >> 3, r = nwg & 7;
    int xcd = orig & 7, i0 = orig >> 3;
    int wgid = (xcd < r ? xcd * (q + 1) : r * (q + 1) + (xcd - r) * q) + i0;
    int m0 = (wgid >> 4) << 7;
    int n0 = (wgid & 15) << 7;

    floatx4 acc[4][4];
    #pragma unroll
    for (int i = 0; i < 4; ++i)
      #pragma unroll
      for (int j = 0; j < 4; ++j)
        acc[i][j] = (floatx4){0.f, 0.f, 0.f, 0.f};

    int hi = lane >> 4, rsw = lane & 7;
    for (int kt = 0; kt < DIM / 64; ++kt) {
      int k0 = kt * 64;
      #pragma unroll
      for (int p = 0; p < 4; ++p) {
        int c = p * 256 + tid;
        int row = c >> 3;
        int src16 = (c & 7) ^ (row & 7);
        load_lds16(visit_bf + (size_t)(m0 + row) * DIM + k0 + src16 * 8,
                   &As[p * 2048 + w * 512]);
      }
      #pragma unroll
      for (int p = 0; p < 4; ++p) {
        int c = p * 256 + tid;
        int row = c >> 3;
        int src16 = (c & 7) ^ (row & 7);
        load_lds16(phe_bf + (size_t)(n0 + row) * DIM + k0 + src16 * 8,
                   &Bs[p * 2048 + w * 512]);
      }
      __syncthreads();
      #pragma unroll
      for (int ks = 0; ks < 2; ++ks) {
        int chk = ((ks << 2) | hi) ^ rsw;
        short8 a[4], b[4];
        #pragma unroll
        for (int i = 0; i < 4; ++i)
          a[i] = *(const short8*)&As[(wm * 64 + i * 16 + (lane & 15)) * 64 + chk * 8];
        #pragma unroll
        for (int j = 0; j < 4; ++j)
          b[j] = *(const short8*)&Bs[(wn * 64 + j * 16 + (lane & 15)) * 64 + chk * 8];
        #pragma unroll
        for (int i = 0; i < 4; ++i)
          #pragma unroll
          for (int j = 0; j < 4; ++j)
            acc[i][j] = __builtin_amdgcn_mfma_f32_16x16x32_bf16(a[i], b[j], acc[i][j], 0, 0, 0);
      }
      __syncthreads();
    }
    #pragma unroll
    for (int i = 0; i < 4; ++i) {
      #pragma unroll
      for (int j = 0; j < 4; ++j) {
        floatx4 v = acc[i][j];
        int col = n0 + wn * 64 + j * 16 + (lane & 15);
        int rb = m0 + wm * 64 + i * 16 + ((lane >> 4) << 2);
        #pragma unroll
        for (int qq = 0; qq < 4; ++qq)
          logit_bf[(size_t)(rb + qq) * PHE + col] = f2bf(v[qq]);
      }
    }
  } else {
    if (schunk < 0) return;
    dpc_select(smem, bid - ngemm, dr, schunk, top);
  }
}

// ---------------- GEMM (NT), 2-phase double-buffered, BK=64 ----------------
template<int EPI, int BM, int BN, int NTH, int WR, int WC>
__global__ void __launch_bounds__(NTH, 2) k_gemm2(
    const u16* __restrict__ A, int lda,
    const u16* __restrict__ Bm, int ldb, int K,
    float* __restrict__ outF, u16* __restrict__ outU, int ldc,
    const float* __restrict__ rp, const float* __restrict__ bias, int nepi)
{
  constexpr int BK = 64;
  constexpr int MR = BM / WR / 16;
  constexpr int NR = BN / WC / 16;
  constexpr int LD_A = BM * BK / (NTH * 8);
  constexpr int LD_B = BN * BK / (NTH * 8);
  __shared__ __align__(16) u16 As[2][BM * BK];
  __shared__ __align__(16) u16 Bs[2][BN * BK];
  int tid = threadIdx.x, lane = tid & 63, w = tid >> 6;
  int wm = w / WC, wn = w % WC;
  int m0, n0;
  xcd_block(BM, BN, m0, n0);

  floatx4 acc[MR][NR];
  #pragma unroll
  for (int i = 0; i < MR; ++i)
    #pragma unroll
    for (int j = 0; j < NR; ++j)
      acc[i][j] = (floatx4){0.f, 0.f, 0.f, 0.f};

  auto stage = [&](int buf, int k0) {
    #pragma unroll
    for (int p = 0; p < LD_A; ++p) {
      int c = p * NTH + tid;
      int row = c >> 3;
      int src16 = (c & 7) ^ (row & 7);
      load_lds16(A + (size_t)(m0 + row) * lda + k0 + src16 * 8,
                 &As[buf][p * NTH * 8 + w * 512]);
    }
    #pragma unroll
    for (int p = 0; p < LD_B; ++p) {
      int c = p * NTH + tid;
      int row = c >> 3;
      int src16 = (c & 7) ^ (row & 7);
      load_lds16(Bm + (size_t)(n0 + row) * ldb + k0 + src16 * 8,
                 &Bs[buf][p * NTH * 8 + w * 512]);
    }
  };

  int nt = K / BK;
  stage(0, 0);
  __syncthreads();
  int cur = 0;
  int hi = lane >> 4;
  int rsw = lane & 7;
  for (int kt = 0; kt < nt; ++kt) {
    if (kt + 1 < nt) stage(cur ^ 1, (kt + 1) * BK);
    #pragma unroll
    for (int ks = 0; ks < 2; ++ks) {
      int chk = ((ks << 2) | hi) ^ rsw;
      short8 a[MR], b[NR];
      #pragma unroll
      for (int i = 0; i < MR; ++i)
        a[i] = *(const short8*)&As[cur][(wm * (BM / WR) + i * 16 + (lane & 15)) * BK + chk * 8];
      #pragma unroll
      for (int j = 0; j < NR; ++j)
        b[j] = *(const short8*)&Bs[cur][(wn * (BN / WC) + j * 16 + (lane & 15)) * BK + chk * 8];
      #pragma unroll
      for (int i = 0; i < MR; ++i)
        #pragma unroll
        for (int j = 0; j < NR; ++j)
          acc[i][j] = __builtin_amdgcn_mfma_f32_16x16x32_bf16(a[i], b[j], acc[i][j], 0, 0, 0);
    }
    __syncthreads();
    cur ^= 1;
  }

  #pragma unroll
  for (int i = 0; i < MR; ++i) {
    #pragma unroll
    for (int j = 0; j < NR; ++j) {
      floatx4 v = acc[i][j];
      int col = n0 + wn * (BN / WC) + j * 16 + (lane & 15);
      int rb = m0 + wm * (BM / WR) + i * 16 + ((lane >> 4) << 2);
      #pragma unroll
      for (int qq = 0; qq < 4; ++qq)
        epi_write<EPI>(rb + qq, col, v[qq], outF, outU, ldc, rp, bias, nepi);
    }
  }
}

// ---------------- GEMM (NT), single-buffer, 128x128, 4 blocks/CU -----------
template<int EPI>
__global__ void __launch_bounds__(256, 4) k_gemm2s(
    const u16* __restrict__ A, int lda,
    const u16* __restrict__ Bm, int ldb, int K,
    float* __restrict__ outF, u16* __restrict__ outU, int ldc,
    const float* __restrict__ rp, const float* __restrict__ bias, int nepi)
{
  constexpr int BM = 128, BN = 128, BK = 64, NTH = 256;
  constexpr int MR = 4, NR = 4;
  __shared__ __align__(16) u16 As[BM * BK];
  __shared__ __align__(16) u16 Bs[BN * BK];
  int tid = threadIdx.x, lane = tid & 63, w = tid >> 6;
  int wm = w >> 1, wn = w & 1;
  int m0, n0;
  xcd_block(BM, BN, m0, n0);

  floatx4 acc[MR][NR];
  #pragma unroll
  for (int i = 0; i < MR; ++i)
    #pragma unroll
    for (int j = 0; j < NR; ++j)
      acc[i][j] = (floatx4){0.f, 0.f, 0.f, 0.f};

  int hi = lane >> 4;
  int rsw = lane & 7;
  int nt = K / BK;
  for (int kt = 0; kt < nt; ++kt) {
    int k0 = kt * BK;
    #pragma unroll
    for (int p = 0; p < 4; ++p) {
      int c = p * NTH + tid;
      int row = c >> 3;
      int src16 = (c & 7) ^ (row & 7);
      load_lds16(A + (size_t)(m0 + row) * lda + k0 + src16 * 8,
                 &As[p * NTH * 8 + w * 512]);
    }
    #pragma unroll
    for (int p = 0; p < 4; ++p) {
      int c = p * NTH + tid;
      int row = c >> 3;
      int src16 = (c & 7) ^ (row & 7);
      load_lds16(Bm + (size_t)(n0 + row) * ldb + k0 + src16 * 8,
                 &Bs[p * NTH * 8 + w * 512]);
    }
    __syncthreads();
    #pragma unroll
    for (int ks = 0; ks < 2; ++ks) {
      int chk = ((ks << 2) | hi) ^ rsw;
      short8 a[MR], b[NR];
      #pragma unroll
      for (int i = 0; i < MR; ++i)
        a[i] = *(const short8*)&As[(wm * 64 + i * 16 + (lane & 15)) * BK + chk * 8];
      #pragma unroll
      for (int j = 0; j < NR; ++j)
        b[j] = *(const short8*)&Bs[(wn * 64 + j * 16 + (lane & 15)) * BK + chk * 8];
      #pragma unroll
      for (int i = 0; i < MR; ++i)
        #pragma unroll
        for (int j = 0; j < NR; ++j)
          acc[i][j] = __builtin_amdgcn_mfma_f32_16x16x32_bf16(a[i], b[j], acc[i][j], 0, 0, 0);
    }
    __syncthreads();
  }

  #pragma unroll
  for (int i = 0; i < MR; ++i) {
    #pragma unroll
    for (int j = 0; j < NR; ++j) {
      floatx4 v = acc[i][j];
      int col = n0 + wn * 64 + j * 16 + (lane & 15);
      int rb = m0 + wm * 64 + i * 16 + ((lane >> 4) << 2);
      #pragma unroll
      for (int qq = 0; qq < 4; ++qq)
        epi_write<EPI>(rb + qq, col, v[qq], outF, outU, ldc, rp, bias, nepi);
    }
  }
}

// ---------------- softmax + entropy (bf16 logits in-place) ----------------
__global__ void __launch_bounds__(256) k_softmax(
    u16* __restrict__ probs_bf, const int* __restrict__ mask,
    float* __restrict__ probs, float* __restrict__ entropy)
{
  int row = blockIdx.x;
  int tid = threadIdx.x;
  u16* pb = probs_bf + (size_t)row * PHE;
  float* pp = probs + (size_t)row * PHE;
  if (mask[row] != 0) {
    const float u = 1.0f / (float)PHE;
    const u16 ub = f2bf(u);
    for (int i = tid; i < PHE; i += 256) { pp[i] = u; pb[i] = ub; }
    if (tid == 0) entropy[row] = 0.f;
    return;
  }
  float l[8];
  float mx = -BIGF;
  #pragma unroll
  for (int j = 0; j < 8; ++j) { l[j] = bf2f(pb[tid + j * 256]); mx = fmaxf(mx, l[j]); }
  mx = blockRedMax(mx);
  float s = 0.f;
  #pragma unroll
  for (int j = 0; j < 8; ++j) { l[j] = __expf(l[j] - mx); s += l[j]; }
  s = blockRedSum(s);
  float inv = 1.0f / s;
  float ent = 0.f;
  #pragma unroll
  for (int j = 0; j < 8; ++j) {
    float p = l[j] * inv;
    pp[tid + j * 256] = p;
    pb[tid + j * 256] = f2bf(p);
    ent += p * __logf(p);
  }
  ent = blockRedSum(ent);
  if (tid == 0) entropy[row] = -ent;
}

// ---------------- add + layernorm ----------------
__global__ void __launch_bounds__(256) k_ln(
    const float* __restrict__ xa, const float* __restrict__ xb,
    const float* __restrict__ g, const float* __restrict__ bb,
    float* __restrict__ outF, u16* __restrict__ outBf)
{
  int row = blockIdx.x;
  int tid = threadIdx.x;
  const float* pa = xa + (size_t)row * DIM;
  const float* pb = xb + (size_t)row * DIM;
  float x0 = pa[tid] + pb[tid];
  float x1 = pa[tid + 256] + pb[tid + 256];
  float mu = blockRedSum(x0 + x1) * (1.0f / DIM);
  float d0 = x0 - mu, d1 = x1 - mu;
  float var = blockRedSum(d0 * d0 + d1 * d1) * (1.0f / DIM);
  float rs = 1.0f / sqrtf(var + LNEPS);
  float y0 = d0 * rs * g[tid] + bb[tid];
  float y1 = d1 * rs * g[tid + 256] + bb[tid + 256];
  if (outF) {
    outF[(size_t)row * DIM + tid] = y0;
    outF[(size_t)row * DIM + tid + 256] = y1;
  }
  if (outBf) {
    outBf[(size_t)row * DIM + tid] = f2bf(y0);
    outBf[(size_t)row * DIM + tid + 256] = f2bf(y1);
  }
}

// ---------------- radix smallest-k per row, f32 keys (merge) ---------------
template<int NPER>
__global__ void __launch_bounds__(256) k_rsel(
    const float* __restrict__ in, int ldin, int ncols, int k, int mode,
    float* __restrict__ out)
{
  __shared__ int hist[1024];
  __shared__ int cum[256];
  __shared__ int wsum[4];
  __shared__ int sel_bucket, sel_rank;
  int row = blockIdx.x;
  int tid = threadIdx.x;
  int lane = tid & 63, w = tid >> 6;
  int hbase = w << 8;
  const float* src = in + (size_t)row * ldin;

  unsigned int v[NPER];
  #pragma unroll
  for (int j = 0; j < NPER; ++j) {
    int idx = tid + j * 256;
    v[j] = (idx < ncols) ? f2mono(src[idx]) : 0xFFFFFFFFu;
  }

  unsigned int prefix = 0, pmask = 0;
  int kk = k;
  for (int shift = 24; shift >= 0; shift -= 8) {
    hist[tid] = 0; hist[tid + 256] = 0; hist[tid + 512] = 0; hist[tid + 768] = 0;
    __syncthreads();
    #pragma unroll
    for (int j = 0; j < NPER; ++j)
      hist_add2(hist + hbase, (int)((v[j] >> shift) & 255), (v[j] & pmask) == prefix);
    __syncthreads();
    int x = hist[tid] + hist[tid + 256] + hist[tid + 512] + hist[tid + 768];
    #pragma unroll
    for (int off = 1; off < 64; off <<= 1) {
      int y = __shfl_up(x, off);
      if (lane >= off) x += y;
    }
    if (lane == 63) wsum[w] = x;
    __syncthreads();
    #pragma unroll
    for (int i = 0; i < 4; ++i) if (i < w) x += wsum[i];
    cum[tid] = x;
    __syncthreads();
    int prev = (tid == 0) ? 0 : cum[tid - 1];
    if (prev < kk && kk <= cum[tid]) { sel_bucket = tid; sel_rank = kk - prev; }
    __syncthreads();
    prefix |= ((unsigned int)sel_bucket) << shift;
    pmask |= 255u << shift;
    kk = sel_rank;
    __syncthreads();
  }

  float thr = mono2f(prefix);
  int need = kk;

  float s = 0.f, se = 0.f, sq = 0.f;
  #pragma unroll
  for (int j = 0; j < NPER; ++j) {
    if (v[j] < prefix) {
      float f = mono2f(v[j]);
      s += f; se += __expf(-f); sq += f * f;
    }
  }
  float ts = blockRedSum(s);
  float tse = blockRedSum(se);
  float tsq = blockRedSum(sq);
  if (tid == 0) {
    float fn = (float)need;
    ts += fn * thr;
    if (mode == 1) {
      out[row] = ts;
    } else {
      tse += fn * __expf(-thr);
      tsq += fn * thr * thr;
      out[(size_t)row * 4] = ts;
      out[(size_t)row * 4 + 1] = tse;
      out[(size_t)row * 4 + 2] = tsq;
    }
  }
}

// ---------------- final scalar reductions ----------------
__global__ void __launch_bounds__(256) k_final(
    const float* __restrict__ row_sum50, const float* __restrict__ pp_part,
    float* __restrict__ out_pcd, float* __restrict__ out_inv,
    float* __restrict__ out_mean, float* __restrict__ out_var)
{
  int tid = threadIdx.x;
  double s50 = 0, sn = 0, se = 0, sq = 0;
  for (int i = tid; i < PHE; i += 256) {
    s50 += (double)row_sum50[i];
    sn += (double)pp_part[(size_t)i * 4];
    se += (double)pp_part[(size_t)i * 4 + 1];
    sq += (double)pp_part[(size_t)i * 4 + 2];
  }
  s50 = blockRedSumD(s50);
  sn = blockRedSumD(sn);
  se = blockRedSumD(se);
  sq = blockRedSumD(sq);
  if (tid == 0) {
    *out_pcd = (float)(s50 / (double)(PHE * KC));
    double mean = sn / (double)(PHE * KP);
    *out_inv = (float)(se / (double)(PHE * KP));
    *out_mean = (float)mean;
    *out_var = (float)(sq / (double)(PHE * KP) - mean * mean);
  }
}

// ---------------- host ----------------
extern "C" void kernel_launch(void* const* d_in, const int* in_sizes, int n_in,
                              void* d_out, int out_size, void* d_ws, size_t ws_size,
                              hipStream_t stream)
{
  const float* visit = (const float*)d_in[0];
  const int*   vmask = (const int*)d_in[1];
  const float* emb   = (const float*)d_in[2];
  const float* phe   = (const float*)d_in[3];
  const float* w1    = (const float*)d_in[4];
  const float* b1    = (const float*)d_in[5];
  const float* w2    = (const float*)d_in[6];
  const float* b2    = (const float*)d_in[7];
  const float* ln1g  = (const float*)d_in[8];
  const float* ln1b  = (const float*)d_in[9];
  const float* ln2g  = (const float*)d_in[10];
  const float* ln2b  = (const float*)d_in[11];

  float* out = (float*)d_out;
  float* out2      = out;
  float* probs     = out + (size_t)BT * DIM;
  float* pcd       = probs + (size_t)BT * PHE;
  float* entropy   = pcd + 1;
  float* inv_loss  = entropy + BT;
  float* dist_mean = inv_loss + 1;
  float* dist_var  = dist_mean + 1;

  char* wsb = (char*)d_ws;
  size_t off = 0;
  auto alloc = [&](size_t bytes) -> char* {
    char* p = wsb + off;
    off = (off + bytes + 255) & ~(size_t)255;
    return p;
  };
  u16* phe_bf   = (u16*)alloc((size_t)PHE * DIM * 2);
  u16* pheT_bf  = (u16*)alloc((size_t)DIM * PHE * 2);
  u16* visit_bf = (u16*)alloc((size_t)BT * DIM * 2);
  u16* w1T_bf   = (u16*)alloc((size_t)DFFP2 * DIM * 2);
  u16* w2T_bf   = (u16*)alloc((size_t)DIM * DFFP2 * 2);
  float* r_p    = (float*)alloc((size_t)PHE * 4);
  float* r_c    = (float*)alloc((size_t)VOC * 4);
  char* big1    = alloc((size_t)67108864);            // 2x bf16 d-chunk ping-pong
  char* big2    = alloc((size_t)VOCP * DIM * 2);      // emb_bf padded -> h_bf [BT][DFFP2]
  float* top50c = (float*)alloc((size_t)PHE * NCHUNK * 2 * KC * 4);
  char* big3    = alloc((size_t)PHE * PHE * 4);       // d_pp f32 -> ctx_f [BT][DIM]
  u16* probs_bf = (u16*)alloc((size_t)BT * PHE * 2);  // logits bf16 -> probs (in-place)
  float* out1_f = (float*)alloc((size_t)BT * DIM * 4);
  u16* out1_bf  = (u16*)alloc((size_t)BT * DIM * 2);
  float* ffn_f  = (float*)alloc((size_t)BT * DIM * 4);
  float* row_sum50 = (float*)alloc((size_t)PHE * 4);
  float* pp_part   = (float*)alloc((size_t)PHE * 4 * 4);

  u16* dchunk0  = (u16*)big1;
  u16* dchunk1  = (u16*)(big1 + 33554432);
  u16* emb_bf   = (u16*)big2;
  u16* h_bf     = (u16*)big2;
  float* d_pp   = (float*)big3;
  float* ctx_f  = (float*)big3;

  if (ws_size < off) { k_sentinel<<<1, 1, 0, stream>>>(out); return; }

  // fused prep: wave-per-row cvt+sumsq (emb, phe), visit cvt, 3 TILED transposes
  int nprep = PREP_ROWB + PREP_VIS + PREP_PHT + PREP_W1 + PREP_W2;
  k_prep<<<nprep, 256, 0, stream>>>(emb, emb_bf, r_c, phe, phe_bf, r_p,
                                    visit, visit_bf, pheT_bf, w1, w1T_bf, w2, w2T_bf);

  // DPC pipeline with absorbed dpp, dpp-select distributed over L2..L4
  k_dpc<256, 0><<<1024 + 256, 256, 0, stream>>>(
      phe_bf, emb_bf, 0, 1024, dchunk0, nullptr, -1, top50c, r_p, r_c, 0,
      0, 0, d_pp, pp_part);
  k_dpc<0, 0><<<1024 + 4096, 256, 0, stream>>>(
      phe_bf, emb_bf, 1, 1024, dchunk1, dchunk0, 0, top50c, r_p, r_c, 4096,
      0, 0, d_pp, pp_part);
  int dpps_done = 0;
  for (int c = 2; c < NCHUNK; ++c) {
    int s = c - 1;
    int nd = (PHE - dpps_done) / (NCHUNK - c);   // 683, 683, 682
    u16* dw = (c & 1) ? dchunk1 : dchunk0;
    const u16* dr = (s & 1) ? dchunk1 : dchunk0;
    k_dpc<0, 1><<<1024 + 4096 + nd, 256, 0, stream>>>(
        phe_bf, emb_bf, c, 1024, dw, dr, s, top50c, r_p, r_c, 4096,
        nd, dpps_done, d_pp, pp_part);
    dpps_done += nd;
  }
  k_dpc_log<<<1024 + PHE * 2, 256, 0, stream>>>(
      visit_bf, phe_bf, 1024, probs_bf,
      (NCHUNK - 1) & 1 ? dchunk1 : dchunk0, NCHUNK - 1, top50c);
  k_rsel<2><<<PHE, 256, 0, stream>>>(top50c, NCHUNK * 2 * KC, NCHUNK * 2 * KC, KC, 1, row_sum50);

  // softmax (in-place bf16 logits) -> ctx
  k_softmax<<<BT, 256, 0, stream>>>(probs_bf, vmask, probs, entropy);
  k_gemm2<EPI_STORE, 64, 128, 256, 2, 2><<<dim3(DIM / 128, BT / 64), 256, 0, stream>>>(
      probs_bf, PHE, pheT_bf, PHE, PHE, ctx_f, nullptr, DIM, nullptr, nullptr, 0);

  // LN1, FFN, LN2
  k_ln<<<BT, 256, 0, stream>>>(visit, ctx_f, ln1g, ln1b, out1_f, out1_bf);
  k_gemm2s<EPI_FFN1><<<dim3(DFFP2 / 128, BT / 128), 256, 0, stream>>>(
      out1_bf, DIM, w1T_bf, DIM, DIM, nullptr, h_bf, DFFP2, nullptr, b1, DFF);
  k_gemm2<EPI_FFN2, 64, 128, 256, 2, 2><<<dim3(DIM / 128, BT / 64), 256, 0, stream>>>(
      h_bf, DFFP2, w2T_bf, DFFP2, DFFP2, ffn_f, nullptr, DIM, nullptr, b2, 0);
  k_ln<<<BT, 256, 0, stream>>>(out1_f, ffn_f, ln2g, ln2b, out2, nullptr);

  // scalars
  k_final<<<1, 256, 0, stream>>>(row_sum50, pp_part, pcd, inv_loss, dist_mean, dist_var);
}